// Round 4
// baseline (2004.589 us; speedup 1.0000x reference)
//
#include <hip/hip_runtime.h>
#include <hip/hip_bf16.h>
#include <math.h>

typedef __hip_bfloat16 bf16;

// flags[0..15]: 1 if float-array slot is bf16, 0 if fp32.
//   slot 0:x | per layer L(0..2): 1+5L:w_up 2+5L:w_down 3+5L:w_bias 4+5L:ew_up 5+5L:ew_down
// flags[16]: 1 if edge_index is int64 (little-endian, values < 2^31), else int32.
__device__ __forceinline__ float ldf(const void* p, long i, int isbf) {
    return isbf ? __bfloat162float(((const bf16*)p)[i]) : ((const float*)p)[i];
}
__device__ __forceinline__ int lde(const int* ei, int half, long e, long E, int is64) {
    long idx = half ? (E + e) : e;
    return is64 ? ei[idx * 2] : ei[idx];
}

// ---------------------------------------------------------------- dtype detection
struct DetectArgs {
    const void* p[16];
    long n[16];
    const int* ei;
    long E;
    int* flags;
};

__global__ void k_detect(DetectArgs a) {
    __shared__ int cnt;
    if (threadIdx.x == 0) cnt = 0;
    __syncthreads();
    int b = blockIdx.x;
    int bad = 0;
    if (b < 16) {
        const bf16* p = (const bf16*)a.p[b];
        long m = a.n[b] < 4096 ? a.n[b] : 4096;
        for (long i = threadIdx.x; i < m; i += 256) {
            float v = __bfloat162float(p[i]);
            if (!(fabsf(v) < 100.0f)) bad++;   // NaN/Inf/huge counted bad
        }
        atomicAdd(&cnt, bad);
        __syncthreads();
        if (threadIdx.x == 0) a.flags[b] = ((long)cnt * 16 < m) ? 1 : 0;
    } else {
        long m = a.E / 2 < 4096 ? a.E / 2 : 4096;
        for (long i = threadIdx.x; i < m; i += 256) {
            if (a.ei[2 * i + 1] != 0) bad++;   // high words: 0 under int64 truth
        }
        atomicAdd(&cnt, bad);
        __syncthreads();
        if (threadIdx.x == 0) a.flags[16] = (cnt < (int)(m / 16) + 1) ? 1 : 0;
    }
}

// ---------------------------------------------------------------- degrees
__global__ void k_deg(const int* __restrict__ ei, long E, const int* __restrict__ flags,
                      float* __restrict__ degc, float* __restrict__ degr) {
    long e = (long)blockIdx.x * blockDim.x + threadIdx.x;
    if (e < E) {
        int is64 = flags[16];
        atomicAdd(&degc[lde(ei, 1, e, E, is64)], 1.0f);
        atomicAdd(&degr[lde(ei, 0, e, E, is64)], 1.0f);
    }
}

__global__ void k_inv(float* __restrict__ a, long n) {
    long i = (long)blockIdx.x * blockDim.x + threadIdx.x;
    if (i < n) { float v = a[i]; a[i] = (v > 0.0f) ? 1.0f / v : 0.0f; }
}

// ---------------------------------------------------------------- linear: A=x@Wu^T, B=x@Wd^T, C=x@Wb^T
// Generic dims. One thread per (node, out-feature). Weights staged transposed
// in LDS (s[i*dout+o]) when they fit so lanes hit consecutive banks.
__global__ void k_linear(const void* __restrict__ xin, int xfi, int din, int dout, long N,
                         const void* __restrict__ wu, const void* __restrict__ wd,
                         const void* __restrict__ wb, int wfi,
                         const int* __restrict__ flags, int uselds,
                         float* __restrict__ A, float* __restrict__ B, float* __restrict__ C) {
    __shared__ float smem[12288];   // 48 KB: 3*din*dout must fit when uselds
    int xbf = (xfi >= 0) ? flags[xfi] : 0;
    int ubf = flags[wfi], dbf = flags[wfi + 1], bbf = flags[wfi + 2];
    float* su = smem;
    float* sd = smem + (long)din * dout;
    float* sb = smem + 2l * din * dout;
    if (uselds) {
        for (int j = threadIdx.x; j < din * dout; j += 256) {
            int o = j % dout, i = j / dout;
            su[j] = ldf(wu, (long)o * din + i, ubf);
            sd[j] = ldf(wd, (long)o * din + i, dbf);
            sb[j] = ldf(wb, (long)o * din + i, bbf);
        }
        __syncthreads();
    }
    long idx = (long)blockIdx.x * blockDim.x + threadIdx.x;
    long node = idx / dout;
    int o = (int)(idx % dout);
    if (node >= N) return;
    float au = 0.f, ad = 0.f, ab = 0.f;
    long xb = node * din;
    if (uselds) {
        for (int i = 0; i < din; i++) {
            float xv = ldf(xin, xb + i, xbf);
            au += xv * su[i * dout + o];
            ad += xv * sd[i * dout + o];
            ab += xv * sb[i * dout + o];
        }
    } else {
        for (int i = 0; i < din; i++) {
            float xv = ldf(xin, xb + i, xbf);
            au += xv * ldf(wu, (long)o * din + i, ubf);
            ad += xv * ldf(wd, (long)o * din + i, dbf);
            ab += xv * ldf(wb, (long)o * din + i, bbf);
        }
    }
    A[node * dout + o] = au;
    B[node * dout + o] = ad;
    C[node * dout + o] = ab;
}

// ---------------------------------------------------------------- scatter propagate
// One thread per (edge, direction, feature). dir 0: src=row -> dst=col (up);
// dir 1: src=col -> dst=row (down). Gather + fp32 atomic scatter.
__global__ void k_scatter(const int* __restrict__ ei, long E, int F,
                          const void* __restrict__ ewu, const void* __restrict__ ewd,
                          int fu, int fd, const int* __restrict__ flags,
                          const float* __restrict__ degci, const float* __restrict__ degri,
                          const float* __restrict__ A, const float* __restrict__ B,
                          float* __restrict__ U, float* __restrict__ D) {
    long idx = (long)blockIdx.x * blockDim.x + threadIdx.x;
    long tot = E * 2 * F;
    if (idx >= tot) return;
    int is64 = flags[16];
    long e = idx / (2 * F);
    int rem = (int)(idx - e * 2 * F);
    int dir = rem >= F;
    int f = rem - dir * F;
    int r = lde(ei, 0, e, E, is64), c = lde(ei, 1, e, E, is64);
    if (!dir) {
        float w = degci[c] * ldf(ewu, e, flags[fu]);
        atomicAdd(&U[(long)c * F + f], w * A[(long)r * F + f]);
    } else {
        float w = degri[r] * ldf(ewd, e, flags[fd]);
        atomicAdd(&D[(long)r * F + f], w * B[(long)c * F + f]);
    }
}

// ---------------------------------------------------------------- normalize + leaky relu
// One 64-lane wave per node; cat = 3F elems strided by 64 across the wave.
// Output is fp32 (the reference returns float32; d_out is float*).
__global__ void k_finalize(const float* __restrict__ U, const float* __restrict__ D,
                           const float* __restrict__ C, int F, long N,
                           float* __restrict__ out) {
    long t = (long)blockIdx.x * blockDim.x + threadIdx.x;
    long n = t >> 6;
    if (n >= N) return;
    int lane = (int)(t & 63);
    int cat = 3 * F;
    float ss = 0.f;
    for (int j = lane; j < cat; j += 64) {
        float v = (j < F) ? U[n * F + j] : (j < 2 * F) ? D[n * F + j - F] : C[n * F + j - 2 * F];
        ss += v * v;
    }
#pragma unroll
    for (int m = 1; m < 64; m <<= 1) ss += __shfl_xor(ss, m, 64);
    float inv = 1.0f / fmaxf(sqrtf(ss), 1e-12f);
    for (int j = lane; j < cat; j += 64) {
        float v = (j < F) ? U[n * F + j] : (j < 2 * F) ? D[n * F + j - F] : C[n * F + j - 2 * F];
        float a = v * inv;
        a = (a >= 0.0f) ? a : 0.1f * a;
        out[n * cat + j] = a;
    }
}

// ---------------------------------------------------------------- edge-weight means (fp32 out)
__global__ void k_mean(const void* e1u, const void* e2u, const void* e3u,
                       const void* e1d, const void* e2d, const void* e3d,
                       const int* __restrict__ flags, long E,
                       float* __restrict__ mu, float* __restrict__ md) {
    long e = (long)blockIdx.x * blockDim.x + threadIdx.x;
    if (e >= E) return;
    float su = ldf(e1u, e, flags[4]) + ldf(e2u, e, flags[9]) + ldf(e3u, e, flags[14]);
    float sd = ldf(e1d, e, flags[5]) + ldf(e2d, e, flags[10]) + ldf(e3d, e, flags[15]);
    mu[e] = su / 3.0f;
    md[e] = sd / 3.0f;
}

extern "C" void kernel_launch(void* const* d_in, const int* in_sizes, int n_in,
                              void* d_out, int out_size, void* d_ws, size_t ws_size,
                              hipStream_t stream) {
    const int* ei = (const int*)d_in[1];
    const void* w_up[3]   = {d_in[2], d_in[7],  d_in[12]};
    const void* w_down[3] = {d_in[3], d_in[8],  d_in[13]};
    const void* w_bias[3] = {d_in[4], d_in[9],  d_in[14]};
    const void* ew_up[3]  = {d_in[5], d_in[10], d_in[15]};
    const void* ew_down[3]= {d_in[6], d_in[11], d_in[16]};

    // ---- derive true sizes from in_sizes
    long E = in_sizes[5];                                   // ew1_up: [E]
    if (E <= 0) E = 1600000;
    int HID = (int)(sqrt((double)in_sizes[7] / 3.0) + 0.5); // w2_up: [HID, 3*HID]
    if (HID <= 0 || (long)3 * HID * HID != (long)in_sizes[7]) HID = 32;
    int DIN = in_sizes[2] / HID;                            // w1_up: [HID, DIN]
    if (DIN <= 0) DIN = 8;
    long N = (long)in_sizes[0] / DIN;                       // x: [N, DIN]
    if (N <= 0) N = 50000;
    int EMB = in_sizes[12] / (3 * HID);                     // w3_up: [EMB, 3*HID]
    if (EMB <= 0) EMB = 32;
    int Fm = HID > EMB ? HID : EMB;

    // ---- workspace layout (all fp32)
    int* flags = (int*)d_ws;              // 17 ints, padded to 64 floats
    float* base = (float*)d_ws + 64;
    float* degci = base;                  // N
    float* degri = degci + N;             // N
    float* A = degri + N;                 // N*Fm
    float* B = A + N * Fm;                // N*Fm
    float* C = B + N * Fm;                // N*Fm
    float* U = C + N * Fm;                // N*Fm  (U,D contiguous for one memset)
    float* D = U + N * Fm;                // N*Fm
    float* H = D + N * Fm;                // N*3*HID

    // ---- outputs: fp32, concatenated flat in return order (h, mean_up, mean_down)
    float* out_h  = (float*)d_out;
    float* out_mu = out_h + N * 3l * EMB;
    float* out_md = out_mu + E;

    const int TB = 256;
    int lds12 = (3l * (3 * HID) * HID <= 12288) ? 1 : 0;
    int lds1  = (3l * DIN * HID <= 12288) ? 1 : 0;
    int lds3  = (3l * (3 * HID) * EMB <= 12288) ? 1 : 0;
    dim3 linG1((unsigned)((N * HID + TB - 1) / TB));
    dim3 linG3((unsigned)((N * EMB + TB - 1) / TB));
    dim3 scatG12((unsigned)((E * 2 * HID + TB - 1) / TB));
    dim3 scatG3((unsigned)((E * 2 * EMB + TB - 1) / TB));
    dim3 finG((unsigned)((N * 64 + TB - 1) / TB));
    dim3 edgeG((unsigned)((E + TB - 1) / TB));

    // ---- dtype detection
    DetectArgs da;
    da.p[0] = d_in[0]; da.n[0] = in_sizes[0];
    for (int L = 0; L < 3; L++) {
        da.p[1 + 5 * L] = w_up[L];    da.n[1 + 5 * L] = in_sizes[2 + 5 * L];
        da.p[2 + 5 * L] = w_down[L];  da.n[2 + 5 * L] = in_sizes[3 + 5 * L];
        da.p[3 + 5 * L] = w_bias[L];  da.n[3 + 5 * L] = in_sizes[4 + 5 * L];
        da.p[4 + 5 * L] = ew_up[L];   da.n[4 + 5 * L] = in_sizes[5 + 5 * L];
        da.p[5 + 5 * L] = ew_down[L]; da.n[5 + 5 * L] = in_sizes[6 + 5 * L];
    }
    da.ei = ei; da.E = E; da.flags = flags;
    k_detect<<<17, TB, 0, stream>>>(da);

    // ---- degrees (edge_index constant across layers)
    hipMemsetAsync(degci, 0, 2 * N * sizeof(float), stream);
    k_deg<<<edgeG, TB, 0, stream>>>(ei, E, flags, degci, degri);
    k_inv<<<dim3((unsigned)((2 * N + TB - 1) / TB)), TB, 0, stream>>>(degci, 2 * N);

    // ---- layer 1: din=DIN -> HID
    k_linear<<<linG1, TB, 0, stream>>>(d_in[0], 0, DIN, HID, N,
                                       w_up[0], w_down[0], w_bias[0], 1, flags, lds1, A, B, C);
    hipMemsetAsync(U, 0, 2l * N * Fm * sizeof(float), stream);
    k_scatter<<<scatG12, TB, 0, stream>>>(ei, E, HID, ew_up[0], ew_down[0], 4, 5, flags,
                                          degci, degri, A, B, U, D);
    k_finalize<<<finG, TB, 0, stream>>>(U, D, C, HID, N, H);

    // ---- layer 2: din=3*HID -> HID
    k_linear<<<linG1, TB, 0, stream>>>(H, -1, 3 * HID, HID, N,
                                       w_up[1], w_down[1], w_bias[1], 6, flags, lds12, A, B, C);
    hipMemsetAsync(U, 0, 2l * N * Fm * sizeof(float), stream);
    k_scatter<<<scatG12, TB, 0, stream>>>(ei, E, HID, ew_up[1], ew_down[1], 9, 10, flags,
                                          degci, degri, A, B, U, D);
    k_finalize<<<finG, TB, 0, stream>>>(U, D, C, HID, N, H);

    // ---- layer 3: din=3*HID -> EMB, fp32 output
    k_linear<<<linG3, TB, 0, stream>>>(H, -1, 3 * HID, EMB, N,
                                       w_up[2], w_down[2], w_bias[2], 11, flags, lds3, A, B, C);
    hipMemsetAsync(U, 0, 2l * N * Fm * sizeof(float), stream);
    k_scatter<<<scatG3, TB, 0, stream>>>(ei, E, EMB, ew_up[2], ew_down[2], 14, 15, flags,
                                         degci, degri, A, B, U, D);
    k_finalize<<<finG, TB, 0, stream>>>(U, D, C, EMB, N, out_h);

    // ---- edge-weight means
    k_mean<<<edgeG, TB, 0, stream>>>(ew_up[0], ew_up[1], ew_up[2],
                                     ew_down[0], ew_down[1], ew_down[2],
                                     flags, E, out_mu, out_md);
}

// Round 5
// 1351.101 us; speedup vs baseline: 1.4837x; 1.4837x over previous
//
#include <hip/hip_runtime.h>
#include <hip/hip_bf16.h>
#include <math.h>

typedef __hip_bfloat16 bf16;

// flags[0..15]: 1 if float-array slot is bf16, 0 if fp32.
//   slot 0:x | per layer L(0..2): 1+5L:w_up 2+5L:w_down 3+5L:w_bias 4+5L:ew_up 5+5L:ew_down
// flags[16]: 1 if edge_index is int64 (little-endian, values < 2^31), else int32.
__device__ __forceinline__ float ldf(const void* p, long i, int isbf) {
    return isbf ? __bfloat162float(((const bf16*)p)[i]) : ((const float*)p)[i];
}
__device__ __forceinline__ int lde(const int* ei, int half, long e, long E, int is64) {
    long idx = half ? (E + e) : e;
    return is64 ? ei[idx * 2] : ei[idx];
}

// ---------------------------------------------------------------- dtype detection
struct DetectArgs {
    const void* p[16];
    long n[16];
    const int* ei;
    long E;
    int* flags;
};

__global__ void k_detect(DetectArgs a) {
    __shared__ int cnt;
    if (threadIdx.x == 0) cnt = 0;
    __syncthreads();
    int b = blockIdx.x;
    int bad = 0;
    if (b < 16) {
        const bf16* p = (const bf16*)a.p[b];
        long m = a.n[b] < 4096 ? a.n[b] : 4096;
        for (long i = threadIdx.x; i < m; i += 256) {
            float v = __bfloat162float(p[i]);
            if (!(fabsf(v) < 100.0f)) bad++;   // NaN/Inf/huge counted bad
        }
        atomicAdd(&cnt, bad);
        __syncthreads();
        if (threadIdx.x == 0) a.flags[b] = ((long)cnt * 16 < m) ? 1 : 0;
    } else {
        long m = a.E / 2 < 4096 ? a.E / 2 : 4096;
        for (long i = threadIdx.x; i < m; i += 256) {
            if (a.ei[2 * i + 1] != 0) bad++;   // high words: 0 under int64 truth
        }
        atomicAdd(&cnt, bad);
        __syncthreads();
        if (threadIdx.x == 0) a.flags[16] = (cnt < (int)(m / 16) + 1) ? 1 : 0;
    }
}

// ================================================================ CSR build
__global__ void k_count(const int* __restrict__ ei, long E, const int* __restrict__ flags,
                        int* __restrict__ cnt_c, int* __restrict__ cnt_r) {
    long e = (long)blockIdx.x * blockDim.x + threadIdx.x;
    if (e < E) {
        int is64 = flags[16];
        atomicAdd(&cnt_c[lde(ei, 1, e, E, is64)], 1);
        atomicAdd(&cnt_r[lde(ei, 0, e, E, is64)], 1);
    }
}

// Exclusive scan, one block per array (blockIdx 0: cnt_c->off_c, 1: cnt_r->off_r).
__global__ void k_scan(const int* __restrict__ cnt, int* __restrict__ off, long N) {
    __shared__ int s[1024];
    const int* c = cnt + (long)blockIdx.x * N;
    int* o = off + (long)blockIdx.x * (N + 1);
    int base = 0;
    for (long start = 0; start < N; start += 1024) {
        long i = start + threadIdx.x;
        int v = (i < N) ? c[i] : 0;
        s[threadIdx.x] = v;
        __syncthreads();
        for (int d = 1; d < 1024; d <<= 1) {
            int t = (threadIdx.x >= d) ? s[threadIdx.x - d] : 0;
            __syncthreads();
            s[threadIdx.x] += t;
            __syncthreads();
        }
        if (i < N) o[i] = base + s[threadIdx.x] - v;   // exclusive
        base += s[1023];
        __syncthreads();
    }
    if (threadIdx.x == 0) o[N] = base;
}

__global__ void k_fill(const int* __restrict__ ei, long E, const int* __restrict__ flags,
                       const int* __restrict__ off_c, const int* __restrict__ off_r,
                       int* __restrict__ cur_c, int* __restrict__ cur_r,
                       int2* __restrict__ list_c, int2* __restrict__ list_r) {
    long e = (long)blockIdx.x * blockDim.x + threadIdx.x;
    if (e >= E) return;
    int is64 = flags[16];
    int r = lde(ei, 0, e, E, is64), c = lde(ei, 1, e, E, is64);
    int p = atomicAdd(&cur_c[c], 1);
    list_c[(long)off_c[c] + p] = make_int2(r, (int)e);   // up:   dst=col, src=row
    int q = atomicAdd(&cur_r[r], 1);
    list_r[(long)off_r[r] + q] = make_int2(c, (int)e);   // down: dst=row, src=col
}

// ================================================================ fused gather + normalize
// One 64-lane wave per node (F<=32): lanes 0-31 accumulate up (col-CSR over A),
// lanes 32-63 accumulate down (row-CSR over B). deg_inv = 1/list_len. Then
// wave-reduce ||[up,down,bias]||, leaky-relu, write cat row. No atomics.
__global__ void k_gather_fin(const int* __restrict__ off_c, const int2* __restrict__ list_c,
                             const int* __restrict__ off_r, const int2* __restrict__ list_r,
                             const void* __restrict__ ewu, const void* __restrict__ ewd,
                             int fu, int fd, const int* __restrict__ flags,
                             const float* __restrict__ A, const float* __restrict__ B,
                             const float* __restrict__ C, int F, long N,
                             float* __restrict__ out) {
    long t = (long)blockIdx.x * blockDim.x + threadIdx.x;
    long n = t >> 6;
    if (n >= N) return;
    int lane = (int)(t & 63);
    int up = lane < 32;
    int f = lane & 31;
    const int* off = up ? off_c : off_r;
    const int2* list = up ? list_c : list_r;
    const void* ew = up ? ewu : ewd;
    int ebf = flags[up ? fu : fd];
    const float* S = up ? A : B;
    int j0 = off[n], j1 = off[n + 1];
    float acc = 0.f;
    if (f < F) {
        int j = j0;
        for (; j + 4 <= j1; j += 4) {                 // 4 independent gathers in flight
            int2 p0 = list[j], p1 = list[j + 1], p2 = list[j + 2], p3 = list[j + 3];
            float w0 = ldf(ew, p0.y, ebf), w1 = ldf(ew, p1.y, ebf);
            float w2 = ldf(ew, p2.y, ebf), w3 = ldf(ew, p3.y, ebf);
            float s0 = S[(long)p0.x * F + f], s1 = S[(long)p1.x * F + f];
            float s2 = S[(long)p2.x * F + f], s3 = S[(long)p3.x * F + f];
            acc += w0 * s0 + w1 * s1 + w2 * s2 + w3 * s3;
        }
        for (; j < j1; j++) {
            int2 p = list[j];
            acc += ldf(ew, p.y, ebf) * S[(long)p.x * F + f];
        }
    }
    int deg = j1 - j0;
    float val = (f < F && deg > 0) ? acc / (float)deg : 0.f;
    float cv = (up && f < F) ? C[n * F + f] : 0.f;
    float ss = val * val + cv * cv;
#pragma unroll
    for (int m = 1; m < 64; m <<= 1) ss += __shfl_xor(ss, m, 64);
    float inv = 1.0f / fmaxf(sqrtf(ss), 1e-12f);
    if (f < F) {
        float a = val * inv;
        a = (a >= 0.0f) ? a : 0.1f * a;
        out[n * 3 * F + (up ? 0 : F) + f] = a;        // up block / down block
        if (up) {
            float b = cv * inv;
            b = (b >= 0.0f) ? b : 0.1f * b;
            out[n * 3 * F + 2 * F + f] = b;           // bias block
        }
    }
}

// ================================================================ linear: A=x@Wu^T, B=x@Wd^T, C=x@Wb^T
__global__ void k_linear(const void* __restrict__ xin, int xfi, int din, int dout, long N,
                         const void* __restrict__ wu, const void* __restrict__ wd,
                         const void* __restrict__ wb, int wfi,
                         const int* __restrict__ flags, int uselds,
                         float* __restrict__ A, float* __restrict__ B, float* __restrict__ C) {
    __shared__ float smem[12288];   // 48 KB: 3*din*dout must fit when uselds
    int xbf = (xfi >= 0) ? flags[xfi] : 0;
    int ubf = flags[wfi], dbf = flags[wfi + 1], bbf = flags[wfi + 2];
    float* su = smem;
    float* sd = smem + (long)din * dout;
    float* sb = smem + 2l * din * dout;
    if (uselds) {
        for (int j = threadIdx.x; j < din * dout; j += 256) {
            int o = j % dout, i = j / dout;
            su[j] = ldf(wu, (long)o * din + i, ubf);
            sd[j] = ldf(wd, (long)o * din + i, dbf);
            sb[j] = ldf(wb, (long)o * din + i, bbf);
        }
        __syncthreads();
    }
    long idx = (long)blockIdx.x * blockDim.x + threadIdx.x;
    long node = idx / dout;
    int o = (int)(idx % dout);
    if (node >= N) return;
    float au = 0.f, ad = 0.f, ab = 0.f;
    long xb = node * din;
    if (uselds) {
        for (int i = 0; i < din; i++) {
            float xv = ldf(xin, xb + i, xbf);
            au += xv * su[i * dout + o];
            ad += xv * sd[i * dout + o];
            ab += xv * sb[i * dout + o];
        }
    } else {
        for (int i = 0; i < din; i++) {
            float xv = ldf(xin, xb + i, xbf);
            au += xv * ldf(wu, (long)o * din + i, ubf);
            ad += xv * ldf(wd, (long)o * din + i, dbf);
            ab += xv * ldf(wb, (long)o * din + i, bbf);
        }
    }
    A[node * dout + o] = au;
    B[node * dout + o] = ad;
    C[node * dout + o] = ab;
}

// ================================================================ fallback (round-4 proven) kernels
__global__ void k_deg(const int* __restrict__ ei, long E, const int* __restrict__ flags,
                      float* __restrict__ degc, float* __restrict__ degr) {
    long e = (long)blockIdx.x * blockDim.x + threadIdx.x;
    if (e < E) {
        int is64 = flags[16];
        atomicAdd(&degc[lde(ei, 1, e, E, is64)], 1.0f);
        atomicAdd(&degr[lde(ei, 0, e, E, is64)], 1.0f);
    }
}

__global__ void k_inv(float* __restrict__ a, long n) {
    long i = (long)blockIdx.x * blockDim.x + threadIdx.x;
    if (i < n) { float v = a[i]; a[i] = (v > 0.0f) ? 1.0f / v : 0.0f; }
}

__global__ void k_scatter(const int* __restrict__ ei, long E, int F,
                          const void* __restrict__ ewu, const void* __restrict__ ewd,
                          int fu, int fd, const int* __restrict__ flags,
                          const float* __restrict__ degci, const float* __restrict__ degri,
                          const float* __restrict__ A, const float* __restrict__ B,
                          float* __restrict__ U, float* __restrict__ D) {
    long idx = (long)blockIdx.x * blockDim.x + threadIdx.x;
    long tot = E * 2 * F;
    if (idx >= tot) return;
    int is64 = flags[16];
    long e = idx / (2 * F);
    int rem = (int)(idx - e * 2 * F);
    int dir = rem >= F;
    int f = rem - dir * F;
    int r = lde(ei, 0, e, E, is64), c = lde(ei, 1, e, E, is64);
    if (!dir) {
        float w = degci[c] * ldf(ewu, e, flags[fu]);
        atomicAdd(&U[(long)c * F + f], w * A[(long)r * F + f]);
    } else {
        float w = degri[r] * ldf(ewd, e, flags[fd]);
        atomicAdd(&D[(long)r * F + f], w * B[(long)c * F + f]);
    }
}

__global__ void k_finalize(const float* __restrict__ U, const float* __restrict__ D,
                           const float* __restrict__ C, int F, long N,
                           float* __restrict__ out) {
    long t = (long)blockIdx.x * blockDim.x + threadIdx.x;
    long n = t >> 6;
    if (n >= N) return;
    int lane = (int)(t & 63);
    int cat = 3 * F;
    float ss = 0.f;
    for (int j = lane; j < cat; j += 64) {
        float v = (j < F) ? U[n * F + j] : (j < 2 * F) ? D[n * F + j - F] : C[n * F + j - 2 * F];
        ss += v * v;
    }
#pragma unroll
    for (int m = 1; m < 64; m <<= 1) ss += __shfl_xor(ss, m, 64);
    float inv = 1.0f / fmaxf(sqrtf(ss), 1e-12f);
    for (int j = lane; j < cat; j += 64) {
        float v = (j < F) ? U[n * F + j] : (j < 2 * F) ? D[n * F + j - F] : C[n * F + j - 2 * F];
        float a = v * inv;
        a = (a >= 0.0f) ? a : 0.1f * a;
        out[n * cat + j] = a;
    }
}

// ---------------------------------------------------------------- edge-weight means (fp32 out)
__global__ void k_mean(const void* e1u, const void* e2u, const void* e3u,
                       const void* e1d, const void* e2d, const void* e3d,
                       const int* __restrict__ flags, long E,
                       float* __restrict__ mu, float* __restrict__ md) {
    long e = (long)blockIdx.x * blockDim.x + threadIdx.x;
    if (e >= E) return;
    float su = ldf(e1u, e, flags[4]) + ldf(e2u, e, flags[9]) + ldf(e3u, e, flags[14]);
    float sd = ldf(e1d, e, flags[5]) + ldf(e2d, e, flags[10]) + ldf(e3d, e, flags[15]);
    mu[e] = su / 3.0f;
    md[e] = sd / 3.0f;
}

extern "C" void kernel_launch(void* const* d_in, const int* in_sizes, int n_in,
                              void* d_out, int out_size, void* d_ws, size_t ws_size,
                              hipStream_t stream) {
    const int* ei = (const int*)d_in[1];
    const void* w_up[3]   = {d_in[2], d_in[7],  d_in[12]};
    const void* w_down[3] = {d_in[3], d_in[8],  d_in[13]};
    const void* w_bias[3] = {d_in[4], d_in[9],  d_in[14]};
    const void* ew_up[3]  = {d_in[5], d_in[10], d_in[15]};
    const void* ew_down[3]= {d_in[6], d_in[11], d_in[16]};

    // ---- derive true sizes from in_sizes
    long E = in_sizes[5];
    if (E <= 0) E = 1600000;
    int HID = (int)(sqrt((double)in_sizes[7] / 3.0) + 0.5);
    if (HID <= 0 || (long)3 * HID * HID != (long)in_sizes[7]) HID = 32;
    int DIN = in_sizes[2] / HID;
    if (DIN <= 0) DIN = 8;
    long N = (long)in_sizes[0] / DIN;
    if (N <= 0) N = 50000;
    int EMB = in_sizes[12] / (3 * HID);
    if (EMB <= 0) EMB = 32;
    int Fm = HID > EMB ? HID : EMB;

    // ---- outputs: fp32, concatenated (h, mean_up, mean_down)
    float* out_h  = (float*)d_out;
    float* out_mu = out_h + N * 3l * EMB;
    float* out_md = out_mu + E;

    const int TB = 256;
    int lds12 = (3l * (3 * HID) * HID <= 12288) ? 1 : 0;
    int lds1  = (3l * DIN * HID <= 12288) ? 1 : 0;
    int lds3  = (3l * (3 * HID) * EMB <= 12288) ? 1 : 0;
    dim3 linG1((unsigned)((N * HID + TB - 1) / TB));
    dim3 linG3((unsigned)((N * EMB + TB - 1) / TB));
    dim3 finG((unsigned)((N * 64 + TB - 1) / TB));
    dim3 edgeG((unsigned)((E + TB - 1) / TB));

    // ---- fast-path workspace layout
    int* flags = (int*)d_ws;                       // 64 ints
    int* cnt_c = flags + 64;                       // N    (cnt_c,cnt_r,cur_c,cur_r contiguous)
    int* cnt_r = cnt_c + N;                        // N
    int* cur_c = cnt_r + N;                        // N
    int* cur_r = cur_c + N;                        // N
    int* off_c = cur_r + N;                        // N+1  (off_c,off_r contiguous)
    int* off_r = off_c + (N + 1);                  // N+1
    int2* list_c = (int2*)(off_r + (N + 1));       // E
    int2* list_r = list_c + E;                     // E
    float* A = (float*)(list_r + E);               // N*Fm
    float* B = A + N * Fm;                         // N*Fm
    float* C = B + N * Fm;                         // N*Fm
    float* H = C + N * Fm;                         // N*3*HID
    size_t need = (size_t)((char*)(H + N * 3l * HID) - (char*)d_ws);

    bool fast = (HID <= 32 && EMB <= 32) && (ws_size == 0 || ws_size >= need);

    // ---- dtype detection (both paths)
    DetectArgs da;
    da.p[0] = d_in[0]; da.n[0] = in_sizes[0];
    for (int L = 0; L < 3; L++) {
        da.p[1 + 5 * L] = w_up[L];    da.n[1 + 5 * L] = in_sizes[2 + 5 * L];
        da.p[2 + 5 * L] = w_down[L];  da.n[2 + 5 * L] = in_sizes[3 + 5 * L];
        da.p[3 + 5 * L] = w_bias[L];  da.n[3 + 5 * L] = in_sizes[4 + 5 * L];
        da.p[4 + 5 * L] = ew_up[L];   da.n[4 + 5 * L] = in_sizes[5 + 5 * L];
        da.p[5 + 5 * L] = ew_down[L]; da.n[5 + 5 * L] = in_sizes[6 + 5 * L];
    }
    da.ei = ei; da.E = E; da.flags = flags;
    k_detect<<<17, TB, 0, stream>>>(da);

    if (fast) {
        // ---- CSR build (once; reused for 3 layers x 2 directions)
        hipMemsetAsync(cnt_c, 0, 4 * N * sizeof(int), stream);
        k_count<<<edgeG, TB, 0, stream>>>(ei, E, flags, cnt_c, cnt_r);
        k_scan<<<2, 1024, 0, stream>>>(cnt_c, off_c, N);
        k_fill<<<edgeG, TB, 0, stream>>>(ei, E, flags, off_c, off_r, cur_c, cur_r, list_c, list_r);

        // ---- layer 1
        k_linear<<<linG1, TB, 0, stream>>>(d_in[0], 0, DIN, HID, N,
                                           w_up[0], w_down[0], w_bias[0], 1, flags, lds1, A, B, C);
        k_gather_fin<<<finG, TB, 0, stream>>>(off_c, list_c, off_r, list_r,
                                              ew_up[0], ew_down[0], 4, 5, flags,
                                              A, B, C, HID, N, H);
        // ---- layer 2
        k_linear<<<linG1, TB, 0, stream>>>(H, -1, 3 * HID, HID, N,
                                           w_up[1], w_down[1], w_bias[1], 6, flags, lds12, A, B, C);
        k_gather_fin<<<finG, TB, 0, stream>>>(off_c, list_c, off_r, list_r,
                                              ew_up[1], ew_down[1], 9, 10, flags,
                                              A, B, C, HID, N, H);
        // ---- layer 3 -> fp32 output
        k_linear<<<linG3, TB, 0, stream>>>(H, -1, 3 * HID, EMB, N,
                                           w_up[2], w_down[2], w_bias[2], 11, flags, lds3, A, B, C);
        k_gather_fin<<<finG, TB, 0, stream>>>(off_c, list_c, off_r, list_r,
                                              ew_up[2], ew_down[2], 14, 15, flags,
                                              A, B, C, EMB, N, out_h);
    } else {
        // ---- fallback: round-4 proven atomic-scatter path
        float* degci = (float*)(flags + 64);
        float* degri = degci + N;
        float* fA = degri + N;
        float* fB = fA + N * Fm;
        float* fC = fB + N * Fm;
        float* fU = fC + N * Fm;
        float* fD = fU + N * Fm;
        float* fH = fD + N * Fm;
        dim3 scatG12((unsigned)((E * 2 * HID + TB - 1) / TB));
        dim3 scatG3((unsigned)((E * 2 * EMB + TB - 1) / TB));

        hipMemsetAsync(degci, 0, 2 * N * sizeof(float), stream);
        k_deg<<<edgeG, TB, 0, stream>>>(ei, E, flags, degci, degri);
        k_inv<<<dim3((unsigned)((2 * N + TB - 1) / TB)), TB, 0, stream>>>(degci, 2 * N);

        k_linear<<<linG1, TB, 0, stream>>>(d_in[0], 0, DIN, HID, N,
                                           w_up[0], w_down[0], w_bias[0], 1, flags, lds1, fA, fB, fC);
        hipMemsetAsync(fU, 0, 2l * N * Fm * sizeof(float), stream);
        k_scatter<<<scatG12, TB, 0, stream>>>(ei, E, HID, ew_up[0], ew_down[0], 4, 5, flags,
                                              degci, degri, fA, fB, fU, fD);
        k_finalize<<<finG, TB, 0, stream>>>(fU, fD, fC, HID, N, fH);

        k_linear<<<linG1, TB, 0, stream>>>(fH, -1, 3 * HID, HID, N,
                                           w_up[1], w_down[1], w_bias[1], 6, flags, lds12, fA, fB, fC);
        hipMemsetAsync(fU, 0, 2l * N * Fm * sizeof(float), stream);
        k_scatter<<<scatG12, TB, 0, stream>>>(ei, E, HID, ew_up[1], ew_down[1], 9, 10, flags,
                                              degci, degri, fA, fB, fU, fD);
        k_finalize<<<finG, TB, 0, stream>>>(fU, fD, fC, HID, N, fH);

        k_linear<<<linG3, TB, 0, stream>>>(fH, -1, 3 * HID, EMB, N,
                                           w_up[2], w_down[2], w_bias[2], 11, flags, lds3, fA, fB, fC);
        hipMemsetAsync(fU, 0, 2l * N * Fm * sizeof(float), stream);
        k_scatter<<<scatG3, TB, 0, stream>>>(ei, E, EMB, ew_up[2], ew_down[2], 14, 15, flags,
                                             degci, degri, fA, fB, fU, fD);
        k_finalize<<<finG, TB, 0, stream>>>(fU, fD, fC, EMB, N, out_h);
    }

    // ---- edge-weight means
    k_mean<<<edgeG, TB, 0, stream>>>(ew_up[0], ew_up[1], ew_up[2],
                                     ew_down[0], ew_down[1], ew_down[2],
                                     flags, E, out_mu, out_md);
}

// Round 6
// 1094.022 us; speedup vs baseline: 1.8323x; 1.2350x over previous
//
#include <hip/hip_runtime.h>
#include <hip/hip_bf16.h>
#include <math.h>

typedef __hip_bfloat16 bf16;

#define NBMAX 1024   // max buckets (N <= 262144 for fast path)
#define BSH 8        // 256 nodes per bucket

// flags[0..15]: 1 if float-array slot is bf16, 0 if fp32.
//   slot 0:x | per layer L(0..2): 1+5L:w_up 2+5L:w_down 3+5L:w_bias 4+5L:ew_up 5+5L:ew_down
// flags[16]: 1 if edge_index is int64 (little-endian, values < 2^31), else int32.
__device__ __forceinline__ float ldf(const void* p, long i, int isbf) {
    return isbf ? __bfloat162float(((const bf16*)p)[i]) : ((const float*)p)[i];
}
__device__ __forceinline__ int lde(const int* ei, int half, long e, long E, int is64) {
    long idx = half ? (E + e) : e;
    return is64 ? ei[idx * 2] : ei[idx];
}

// ---------------------------------------------------------------- dtype detection
struct DetectArgs {
    const void* p[16];
    long n[16];
    const int* ei;
    long E;
    int* flags;
};

__global__ void k_detect(DetectArgs a) {
    __shared__ int cnt;
    if (threadIdx.x == 0) cnt = 0;
    __syncthreads();
    int b = blockIdx.x;
    int bad = 0;
    if (b < 16) {
        const bf16* p = (const bf16*)a.p[b];
        long m = a.n[b] < 4096 ? a.n[b] : 4096;
        for (long i = threadIdx.x; i < m; i += 256) {
            float v = __bfloat162float(p[i]);
            if (!(fabsf(v) < 100.0f)) bad++;
        }
        atomicAdd(&cnt, bad);
        __syncthreads();
        if (threadIdx.x == 0) a.flags[b] = ((long)cnt * 16 < m) ? 1 : 0;
    } else {
        long m = a.E / 2 < 4096 ? a.E / 2 : 4096;
        for (long i = threadIdx.x; i < m; i += 256) {
            if (a.ei[2 * i + 1] != 0) bad++;
        }
        atomicAdd(&cnt, bad);
        __syncthreads();
        if (threadIdx.x == 0) a.flags[16] = (cnt < (int)(m / 16) + 1) ? 1 : 0;
    }
}

// ================================================================ bucketed CSR build
// dir 0: dst=col (up-list), dir 1: dst=row (down-list). bucket = dst>>8.

__global__ void kb_count(const int* __restrict__ ei, long E, const int* __restrict__ flags,
                         int NB, int* __restrict__ bc) {
    __shared__ int h[NBMAX];
    for (int i = threadIdx.x; i < NB; i += 256) h[i] = 0;
    __syncthreads();
    int dir = blockIdx.y;
    int is64 = flags[16];
    long base = (long)blockIdx.x * 2048;
#pragma unroll
    for (int i = 0; i < 8; i++) {
        long e = base + i * 256 + threadIdx.x;
        if (e < E) {
            int d = lde(ei, dir ? 0 : 1, e, E, is64);
            atomicAdd(&h[d >> BSH], 1);
        }
    }
    __syncthreads();
    for (int i = threadIdx.x; i < NB; i += 256)
        if (h[i]) atomicAdd(&bc[dir * NBMAX + i], h[i]);
}

__global__ void kb_scan(const int* __restrict__ bc, int* __restrict__ bb,
                        int* __restrict__ gcur, int NB) {
    if (threadIdx.x < 2) {
        int dir = threadIdx.x;
        int acc = 0;
        for (int i = 0; i < NB; i++) { bb[dir * (NBMAX + 1) + i] = acc; acc += bc[dir * NBMAX + i]; }
        bb[dir * (NBMAX + 1) + NB] = acc;
    }
    __syncthreads();
    for (int i = threadIdx.x; i < 2 * NBMAX; i += blockDim.x) {
        int d = i / NBMAX, b = i - d * NBMAX;
        gcur[i] = bb[d * (NBMAX + 1) + (b < NB ? b : NB)];
    }
}

// Per-block counting-sort of a 2048-edge chunk by bucket, then bucket-contiguous
// global append (mostly full 64B lines instead of 8B random scatter).
__global__ void kb_fill(const int* __restrict__ ei, long E, const int* __restrict__ flags,
                        int NB, int* __restrict__ gcur,
                        int* __restrict__ bdst, int2* __restrict__ bse) {
    __shared__ int sdst[2048], ssrc[2048], seid[2048];
    __shared__ int h[NBMAX], lofs[NBMAX], cur[NBMAX], gb[NBMAX];
    __shared__ int sc[256];
    int tid = threadIdx.x;
    int dir = blockIdx.y;
    int is64 = flags[16];
    for (int i = tid; i < NBMAX; i += 256) { h[i] = 0; cur[i] = 0; }
    __syncthreads();
    long base = (long)blockIdx.x * 2048;
    int myd[8], mys[8], mye[8];
#pragma unroll
    for (int i = 0; i < 8; i++) {
        long e = base + i * 256 + tid;
        myd[i] = -1;
        if (e < E) {
            myd[i] = lde(ei, dir ? 0 : 1, e, E, is64);
            mys[i] = lde(ei, dir ? 1 : 0, e, E, is64);
            mye[i] = (int)e;
            atomicAdd(&h[myd[i] >> BSH], 1);
        }
    }
    __syncthreads();
    // exclusive scan over h[0..1024): 4 buckets/thread + Hillis-Steele on sums
    int i0 = tid * 4;
    int a0 = h[i0], a1 = h[i0 + 1], a2 = h[i0 + 2], a3 = h[i0 + 3];
    int ts = a0 + a1 + a2 + a3;
    sc[tid] = ts;
    __syncthreads();
    for (int d = 1; d < 256; d <<= 1) {
        int t = (tid >= d) ? sc[tid - d] : 0;
        __syncthreads();
        sc[tid] += t;
        __syncthreads();
    }
    int eb = sc[tid] - ts;
    lofs[i0] = eb; lofs[i0 + 1] = eb + a0; lofs[i0 + 2] = eb + a0 + a1; lofs[i0 + 3] = eb + a0 + a1 + a2;
    __syncthreads();
#pragma unroll
    for (int i = 0; i < 8; i++) {
        if (myd[i] >= 0) {
            int b = myd[i] >> BSH;
            int r = atomicAdd(&cur[b], 1);
            int p = lofs[b] + r;
            sdst[p] = myd[i]; ssrc[p] = mys[i]; seid[p] = mye[i];
        }
    }
    __syncthreads();
    for (int b = tid; b < NB; b += 256) {
        int c = h[b];
        gb[b] = c ? atomicAdd(&gcur[dir * NBMAX + b], c) : 0;
    }
    __syncthreads();
    long rem = E - base;
    int nvalid = rem >= 2048 ? 2048 : (rem > 0 ? (int)rem : 0);
    int* od = bdst + (long)dir * E;
    int2* os = bse + (long)dir * E;
    for (int s = tid; s < nvalid; s += 256) {
        int b = sdst[s] >> BSH;
        long p = (long)gb[b] + (s - lofs[b]);
        od[p] = sdst[s];
        os[p] = make_int2(ssrc[s], seid[s]);
    }
}

// Per-(bucket,dir) counting sort into final per-node CSR. All random writes land
// in the bucket's ~65KB segment -> L2-resident, full-line evictions.
__global__ void kb_csr(const int* __restrict__ bb, const int* __restrict__ bdst,
                       const int2* __restrict__ bse, long E, int NB, long N,
                       int* __restrict__ off_c, int* __restrict__ off_r,
                       int2* __restrict__ list_c, int2* __restrict__ list_r) {
    __shared__ int h[256], lofs[256], cur[256], sc[256];
    int tid = threadIdx.x;
    int b = blockIdx.x, dir = blockIdx.y;
    int base = bb[dir * (NBMAX + 1) + b];
    int cnt  = bb[dir * (NBMAX + 1) + b + 1] - base;
    const int* bd = bdst + (long)dir * E;
    const int2* bs = bse + (long)dir * E;
    int* off = dir ? off_r : off_c;
    int2* list = dir ? list_r : list_c;
    h[tid] = 0; cur[tid] = 0;
    __syncthreads();
    int nb0 = b << BSH;
    for (int s = tid; s < cnt; s += 256)
        atomicAdd(&h[bd[base + s] - nb0], 1);
    __syncthreads();
    int v = h[tid];
    sc[tid] = v;
    __syncthreads();
    for (int d = 1; d < 256; d <<= 1) {
        int t = (tid >= d) ? sc[tid - d] : 0;
        __syncthreads();
        sc[tid] += t;
        __syncthreads();
    }
    lofs[tid] = sc[tid] - v;
    __syncthreads();
    long n = (long)nb0 + tid;
    if (n < N) off[n] = base + lofs[tid];
    if (b == 0 && tid == 0) off[N] = (int)E;
    for (int s = tid; s < cnt; s += 256) {
        int local = bd[base + s] - nb0;
        int r = atomicAdd(&cur[local], 1);
        list[(long)base + lofs[local] + r] = bs[base + s];
    }
}

// ================================================================ fused gather + normalize
// One 64-lane wave per node (F<=32): lanes 0-31 accumulate up (col-CSR over A),
// lanes 32-63 accumulate down (row-CSR over B). deg = list_len. No atomics.
__global__ void k_gather_fin(const int* __restrict__ off_c, const int2* __restrict__ list_c,
                             const int* __restrict__ off_r, const int2* __restrict__ list_r,
                             const void* __restrict__ ewu, const void* __restrict__ ewd,
                             int fu, int fd, const int* __restrict__ flags,
                             const float* __restrict__ A, const float* __restrict__ B,
                             const float* __restrict__ C, int F, long N,
                             float* __restrict__ out) {
    long t = (long)blockIdx.x * blockDim.x + threadIdx.x;
    long n = t >> 6;
    if (n >= N) return;
    int lane = (int)(t & 63);
    int up = lane < 32;
    int f = lane & 31;
    const int* off = up ? off_c : off_r;
    const int2* list = up ? list_c : list_r;
    const void* ew = up ? ewu : ewd;
    int ebf = flags[up ? fu : fd];
    const float* S = up ? A : B;
    int j0 = off[n], j1 = off[n + 1];
    float acc = 0.f;
    if (f < F) {
        int j = j0;
        for (; j + 4 <= j1; j += 4) {
            int2 p0 = list[j], p1 = list[j + 1], p2 = list[j + 2], p3 = list[j + 3];
            float w0 = ldf(ew, p0.y, ebf), w1 = ldf(ew, p1.y, ebf);
            float w2 = ldf(ew, p2.y, ebf), w3 = ldf(ew, p3.y, ebf);
            float s0 = S[(long)p0.x * F + f], s1 = S[(long)p1.x * F + f];
            float s2 = S[(long)p2.x * F + f], s3 = S[(long)p3.x * F + f];
            acc += w0 * s0 + w1 * s1 + w2 * s2 + w3 * s3;
        }
        for (; j < j1; j++) {
            int2 p = list[j];
            acc += ldf(ew, p.y, ebf) * S[(long)p.x * F + f];
        }
    }
    int deg = j1 - j0;
    float val = (f < F && deg > 0) ? acc / (float)deg : 0.f;
    float cv = (up && f < F) ? C[n * F + f] : 0.f;
    float ss = val * val + cv * cv;
#pragma unroll
    for (int m = 1; m < 64; m <<= 1) ss += __shfl_xor(ss, m, 64);
    float inv = 1.0f / fmaxf(sqrtf(ss), 1e-12f);
    if (f < F) {
        float a = val * inv;
        a = (a >= 0.0f) ? a : 0.1f * a;
        out[n * 3 * F + (up ? 0 : F) + f] = a;
        if (up) {
            float bv = cv * inv;
            bv = (bv >= 0.0f) ? bv : 0.1f * bv;
            out[n * 3 * F + 2 * F + f] = bv;
        }
    }
}

// ================================================================ linear: A=x@Wu^T, B=x@Wd^T, C=x@Wb^T
__global__ void k_linear(const void* __restrict__ xin, int xfi, int din, int dout, long N,
                         const void* __restrict__ wu, const void* __restrict__ wd,
                         const void* __restrict__ wb, int wfi,
                         const int* __restrict__ flags, int uselds,
                         float* __restrict__ A, float* __restrict__ B, float* __restrict__ C) {
    __shared__ float smem[12288];
    int xbf = (xfi >= 0) ? flags[xfi] : 0;
    int ubf = flags[wfi], dbf = flags[wfi + 1], bbf = flags[wfi + 2];
    float* su = smem;
    float* sd = smem + (long)din * dout;
    float* sb = smem + 2l * din * dout;
    if (uselds) {
        for (int j = threadIdx.x; j < din * dout; j += 256) {
            int o = j % dout, i = j / dout;
            su[j] = ldf(wu, (long)o * din + i, ubf);
            sd[j] = ldf(wd, (long)o * din + i, dbf);
            sb[j] = ldf(wb, (long)o * din + i, bbf);
        }
        __syncthreads();
    }
    long idx = (long)blockIdx.x * blockDim.x + threadIdx.x;
    long node = idx / dout;
    int o = (int)(idx % dout);
    if (node >= N) return;
    float au = 0.f, ad = 0.f, ab = 0.f;
    long xb = node * din;
    if (uselds) {
        for (int i = 0; i < din; i++) {
            float xv = ldf(xin, xb + i, xbf);
            au += xv * su[i * dout + o];
            ad += xv * sd[i * dout + o];
            ab += xv * sb[i * dout + o];
        }
    } else {
        for (int i = 0; i < din; i++) {
            float xv = ldf(xin, xb + i, xbf);
            au += xv * ldf(wu, (long)o * din + i, ubf);
            ad += xv * ldf(wd, (long)o * din + i, dbf);
            ab += xv * ldf(wb, (long)o * din + i, bbf);
        }
    }
    A[node * dout + o] = au;
    B[node * dout + o] = ad;
    C[node * dout + o] = ab;
}

// ================================================================ fallback (round-4 proven) kernels
__global__ void k_deg(const int* __restrict__ ei, long E, const int* __restrict__ flags,
                      float* __restrict__ degc, float* __restrict__ degr) {
    long e = (long)blockIdx.x * blockDim.x + threadIdx.x;
    if (e < E) {
        int is64 = flags[16];
        atomicAdd(&degc[lde(ei, 1, e, E, is64)], 1.0f);
        atomicAdd(&degr[lde(ei, 0, e, E, is64)], 1.0f);
    }
}

__global__ void k_inv(float* __restrict__ a, long n) {
    long i = (long)blockIdx.x * blockDim.x + threadIdx.x;
    if (i < n) { float v = a[i]; a[i] = (v > 0.0f) ? 1.0f / v : 0.0f; }
}

__global__ void k_scatter(const int* __restrict__ ei, long E, int F,
                          const void* __restrict__ ewu, const void* __restrict__ ewd,
                          int fu, int fd, const int* __restrict__ flags,
                          const float* __restrict__ degci, const float* __restrict__ degri,
                          const float* __restrict__ A, const float* __restrict__ B,
                          float* __restrict__ U, float* __restrict__ D) {
    long idx = (long)blockIdx.x * blockDim.x + threadIdx.x;
    long tot = E * 2 * F;
    if (idx >= tot) return;
    int is64 = flags[16];
    long e = idx / (2 * F);
    int rem = (int)(idx - e * 2 * F);
    int dir = rem >= F;
    int f = rem - dir * F;
    int r = lde(ei, 0, e, E, is64), c = lde(ei, 1, e, E, is64);
    if (!dir) {
        float w = degci[c] * ldf(ewu, e, flags[fu]);
        atomicAdd(&U[(long)c * F + f], w * A[(long)r * F + f]);
    } else {
        float w = degri[r] * ldf(ewd, e, flags[fd]);
        atomicAdd(&D[(long)r * F + f], w * B[(long)c * F + f]);
    }
}

__global__ void k_finalize(const float* __restrict__ U, const float* __restrict__ D,
                           const float* __restrict__ C, int F, long N,
                           float* __restrict__ out) {
    long t = (long)blockIdx.x * blockDim.x + threadIdx.x;
    long n = t >> 6;
    if (n >= N) return;
    int lane = (int)(t & 63);
    int cat = 3 * F;
    float ss = 0.f;
    for (int j = lane; j < cat; j += 64) {
        float v = (j < F) ? U[n * F + j] : (j < 2 * F) ? D[n * F + j - F] : C[n * F + j - 2 * F];
        ss += v * v;
    }
#pragma unroll
    for (int m = 1; m < 64; m <<= 1) ss += __shfl_xor(ss, m, 64);
    float inv = 1.0f / fmaxf(sqrtf(ss), 1e-12f);
    for (int j = lane; j < cat; j += 64) {
        float v = (j < F) ? U[n * F + j] : (j < 2 * F) ? D[n * F + j - F] : C[n * F + j - 2 * F];
        float a = v * inv;
        a = (a >= 0.0f) ? a : 0.1f * a;
        out[n * cat + j] = a;
    }
}

// ---------------------------------------------------------------- edge-weight means (fp32 out)
__global__ void k_mean(const void* e1u, const void* e2u, const void* e3u,
                       const void* e1d, const void* e2d, const void* e3d,
                       const int* __restrict__ flags, long E,
                       float* __restrict__ mu, float* __restrict__ md) {
    long e = (long)blockIdx.x * blockDim.x + threadIdx.x;
    if (e >= E) return;
    float su = ldf(e1u, e, flags[4]) + ldf(e2u, e, flags[9]) + ldf(e3u, e, flags[14]);
    float sd = ldf(e1d, e, flags[5]) + ldf(e2d, e, flags[10]) + ldf(e3d, e, flags[15]);
    mu[e] = su / 3.0f;
    md[e] = sd / 3.0f;
}

extern "C" void kernel_launch(void* const* d_in, const int* in_sizes, int n_in,
                              void* d_out, int out_size, void* d_ws, size_t ws_size,
                              hipStream_t stream) {
    const int* ei = (const int*)d_in[1];
    const void* w_up[3]   = {d_in[2], d_in[7],  d_in[12]};
    const void* w_down[3] = {d_in[3], d_in[8],  d_in[13]};
    const void* w_bias[3] = {d_in[4], d_in[9],  d_in[14]};
    const void* ew_up[3]  = {d_in[5], d_in[10], d_in[15]};
    const void* ew_down[3]= {d_in[6], d_in[11], d_in[16]};

    // ---- derive true sizes from in_sizes
    long E = in_sizes[5];
    if (E <= 0) E = 1600000;
    int HID = (int)(sqrt((double)in_sizes[7] / 3.0) + 0.5);
    if (HID <= 0 || (long)3 * HID * HID != (long)in_sizes[7]) HID = 32;
    int DIN = in_sizes[2] / HID;
    if (DIN <= 0) DIN = 8;
    long N = (long)in_sizes[0] / DIN;
    if (N <= 0) N = 50000;
    int EMB = in_sizes[12] / (3 * HID);
    if (EMB <= 0) EMB = 32;
    int Fm = HID > EMB ? HID : EMB;
    int NB = (int)((N + 255) >> BSH);

    // ---- outputs: fp32, concatenated (h, mean_up, mean_down)
    float* out_h  = (float*)d_out;
    float* out_mu = out_h + N * 3l * EMB;
    float* out_md = out_mu + E;

    const int TB = 256;
    int lds12 = (3l * (3 * HID) * HID <= 12288) ? 1 : 0;
    int lds1  = (3l * DIN * HID <= 12288) ? 1 : 0;
    int lds3  = (3l * (3 * HID) * EMB <= 12288) ? 1 : 0;
    dim3 linG1((unsigned)((N * HID + TB - 1) / TB));
    dim3 linG3((unsigned)((N * EMB + TB - 1) / TB));
    dim3 finG((unsigned)((N * 64 + TB - 1) / TB));
    dim3 edgeG((unsigned)((E + TB - 1) / TB));
    dim3 chunkG((unsigned)((E + 2047) / 2048), 2);

    // ---- fast-path workspace layout
    int* flags = (int*)d_ws;                       // 64
    int* bc    = flags + 64;                       // 2*NBMAX
    int* bb    = bc + 2 * NBMAX;                   // 2*(NBMAX+1)
    int* gcur  = bb + 2 * (NBMAX + 1);             // 2*NBMAX
    int* off_c = gcur + 2 * NBMAX;                 // N+1
    int* off_r = off_c + (N + 1);                  // N+1
    long li = (long)(off_r + (N + 1) - (int*)d_ws);
    li = (li + 1) & ~1l;                           // 8B-align lists
    int2* list_c = (int2*)((int*)d_ws + li);       // E
    int2* list_r = list_c + E;                     // E
    int* scratch = (int*)(list_r + E);
    // bucket phase overlay:
    int* bdst = scratch;                           // 2E ints (dir-major)
    int2* bse = (int2*)(scratch + 2 * E);          // 2E int2
    // linear phase overlay (after kb_csr, bucket lists dead):
    float* A = (float*)scratch;                    // N*Fm
    float* B = A + N * Fm;                         // N*Fm
    float* C = B + N * Fm;                         // N*Fm
    float* H = C + N * Fm;                         // N*3*HID
    long scrInts = 6 * E;
    long linInts = N * (3l * Fm + 3l * HID);
    if (linInts > scrInts) scrInts = linInts;
    size_t need = (size_t)((li + 4 * E + scrInts) * 4l + 256);

    bool fast = (HID <= 32 && EMB <= 32) && (NB <= NBMAX) &&
                (ws_size == 0 || ws_size >= need);

    // ---- dtype detection (both paths)
    DetectArgs da;
    da.p[0] = d_in[0]; da.n[0] = in_sizes[0];
    for (int L = 0; L < 3; L++) {
        da.p[1 + 5 * L] = w_up[L];    da.n[1 + 5 * L] = in_sizes[2 + 5 * L];
        da.p[2 + 5 * L] = w_down[L];  da.n[2 + 5 * L] = in_sizes[3 + 5 * L];
        da.p[3 + 5 * L] = w_bias[L];  da.n[3 + 5 * L] = in_sizes[4 + 5 * L];
        da.p[4 + 5 * L] = ew_up[L];   da.n[4 + 5 * L] = in_sizes[5 + 5 * L];
        da.p[5 + 5 * L] = ew_down[L]; da.n[5 + 5 * L] = in_sizes[6 + 5 * L];
    }
    da.ei = ei; da.E = E; da.flags = flags;
    k_detect<<<17, TB, 0, stream>>>(da);

    if (fast) {
        // ---- bucketed CSR build (once; reused 3 layers x 2 directions)
        hipMemsetAsync(bc, 0, 2 * NBMAX * sizeof(int), stream);
        kb_count<<<chunkG, TB, 0, stream>>>(ei, E, flags, NB, bc);
        kb_scan<<<1, 512, 0, stream>>>(bc, bb, gcur, NB);
        kb_fill<<<chunkG, TB, 0, stream>>>(ei, E, flags, NB, gcur, bdst, bse);
        kb_csr<<<dim3((unsigned)NB, 2), TB, 0, stream>>>(bb, bdst, bse, E, NB, N,
                                                         off_c, off_r, list_c, list_r);

        // ---- layer 1
        k_linear<<<linG1, TB, 0, stream>>>(d_in[0], 0, DIN, HID, N,
                                           w_up[0], w_down[0], w_bias[0], 1, flags, lds1, A, B, C);
        k_gather_fin<<<finG, TB, 0, stream>>>(off_c, list_c, off_r, list_r,
                                              ew_up[0], ew_down[0], 4, 5, flags,
                                              A, B, C, HID, N, H);
        // ---- layer 2
        k_linear<<<linG1, TB, 0, stream>>>(H, -1, 3 * HID, HID, N,
                                           w_up[1], w_down[1], w_bias[1], 6, flags, lds12, A, B, C);
        k_gather_fin<<<finG, TB, 0, stream>>>(off_c, list_c, off_r, list_r,
                                              ew_up[1], ew_down[1], 9, 10, flags,
                                              A, B, C, HID, N, H);
        // ---- layer 3 -> fp32 output
        k_linear<<<linG3, TB, 0, stream>>>(H, -1, 3 * HID, EMB, N,
                                           w_up[2], w_down[2], w_bias[2], 11, flags, lds3, A, B, C);
        k_gather_fin<<<finG, TB, 0, stream>>>(off_c, list_c, off_r, list_r,
                                              ew_up[2], ew_down[2], 14, 15, flags,
                                              A, B, C, EMB, N, out_h);
    } else {
        // ---- fallback: round-4 proven atomic-scatter path
        float* degci = (float*)(flags + 64);
        float* degri = degci + N;
        float* fA = degri + N;
        float* fB = fA + N * Fm;
        float* fC = fB + N * Fm;
        float* fU = fC + N * Fm;
        float* fD = fU + N * Fm;
        float* fH = fD + N * Fm;
        dim3 scatG12((unsigned)((E * 2 * HID + TB - 1) / TB));
        dim3 scatG3((unsigned)((E * 2 * EMB + TB - 1) / TB));

        hipMemsetAsync(degci, 0, 2 * N * sizeof(float), stream);
        k_deg<<<edgeG, TB, 0, stream>>>(ei, E, flags, degci, degri);
        k_inv<<<dim3((unsigned)((2 * N + TB - 1) / TB)), TB, 0, stream>>>(degci, 2 * N);

        k_linear<<<linG1, TB, 0, stream>>>(d_in[0], 0, DIN, HID, N,
                                           w_up[0], w_down[0], w_bias[0], 1, flags, lds1, fA, fB, fC);
        hipMemsetAsync(fU, 0, 2l * N * Fm * sizeof(float), stream);
        k_scatter<<<scatG12, TB, 0, stream>>>(ei, E, HID, ew_up[0], ew_down[0], 4, 5, flags,
                                              degci, degri, fA, fB, fU, fD);
        k_finalize<<<finG, TB, 0, stream>>>(fU, fD, fC, HID, N, fH);

        k_linear<<<linG1, TB, 0, stream>>>(fH, -1, 3 * HID, HID, N,
                                           w_up[1], w_down[1], w_bias[1], 6, flags, lds12, fA, fB, fC);
        hipMemsetAsync(fU, 0, 2l * N * Fm * sizeof(float), stream);
        k_scatter<<<scatG12, TB, 0, stream>>>(ei, E, HID, ew_up[1], ew_down[1], 9, 10, flags,
                                              degci, degri, fA, fB, fU, fD);
        k_finalize<<<finG, TB, 0, stream>>>(fU, fD, fC, HID, N, fH);

        k_linear<<<linG3, TB, 0, stream>>>(fH, -1, 3 * HID, EMB, N,
                                           w_up[2], w_down[2], w_bias[2], 11, flags, lds3, fA, fB, fC);
        hipMemsetAsync(fU, 0, 2l * N * Fm * sizeof(float), stream);
        k_scatter<<<scatG3, TB, 0, stream>>>(ei, E, EMB, ew_up[2], ew_down[2], 14, 15, flags,
                                             degci, degri, fA, fB, fU, fD);
        k_finalize<<<finG, TB, 0, stream>>>(fU, fD, fC, EMB, N, out_h);
    }

    // ---- edge-weight means
    k_mean<<<edgeG, TB, 0, stream>>>(ew_up[0], ew_up[1], ew_up[2],
                                     ew_down[0], ew_down[1], ew_down[2],
                                     flags, E, out_mu, out_md);
}

// Round 7
// 884.849 us; speedup vs baseline: 2.2655x; 1.2364x over previous
//
#include <hip/hip_runtime.h>
#include <hip/hip_bf16.h>
#include <math.h>

typedef __hip_bfloat16 bf16;

#define NBMAX 1024   // max buckets (N <= 262144 for fast path)
#define BSH 8        // 256 nodes per bucket

// flags[0..15]: 1 if float-array slot is bf16, 0 if fp32.
//   slot 0:x | per layer L(0..2): 1+5L:w_up 2+5L:w_down 3+5L:w_bias 4+5L:ew_up 5+5L:ew_down
// flags[16]: 1 if edge_index is int64 (little-endian, values < 2^31), else int32.
__device__ __forceinline__ float ldf(const void* p, long i, int isbf) {
    return isbf ? __bfloat162float(((const bf16*)p)[i]) : ((const float*)p)[i];
}
__device__ __forceinline__ int lde(const int* ei, int half, long e, long E, int is64) {
    long idx = half ? (E + e) : e;
    return is64 ? ei[idx * 2] : ei[idx];
}

// ---------------------------------------------------------------- dtype detection
struct DetectArgs {
    const void* p[16];
    long n[16];
    const int* ei;
    long E;
    int* flags;
};

__global__ void k_detect(DetectArgs a) {
    __shared__ int cnt;
    if (threadIdx.x == 0) cnt = 0;
    __syncthreads();
    int b = blockIdx.x;
    int bad = 0;
    if (b < 16) {
        const bf16* p = (const bf16*)a.p[b];
        long m = a.n[b] < 4096 ? a.n[b] : 4096;
        for (long i = threadIdx.x; i < m; i += 256) {
            float v = __bfloat162float(p[i]);
            if (!(fabsf(v) < 100.0f)) bad++;
        }
        atomicAdd(&cnt, bad);
        __syncthreads();
        if (threadIdx.x == 0) a.flags[b] = ((long)cnt * 16 < m) ? 1 : 0;
    } else {
        long m = a.E / 2 < 4096 ? a.E / 2 : 4096;
        for (long i = threadIdx.x; i < m; i += 256) {
            if (a.ei[2 * i + 1] != 0) bad++;
        }
        atomicAdd(&cnt, bad);
        __syncthreads();
        if (threadIdx.x == 0) a.flags[16] = (cnt < (int)(m / 16) + 1) ? 1 : 0;
    }
}

// ================================================================ bucketed CSR build
// dir 0: dst=col (up-list), dir 1: dst=row (down-list). bucket = dst>>8.

__global__ void kb_count(const int* __restrict__ ei, long E, const int* __restrict__ flags,
                         int NB, int* __restrict__ bc) {
    __shared__ int h[NBMAX];
    for (int i = threadIdx.x; i < NB; i += 256) h[i] = 0;
    __syncthreads();
    int dir = blockIdx.y;
    int is64 = flags[16];
    long base = (long)blockIdx.x * 2048;
#pragma unroll
    for (int i = 0; i < 8; i++) {
        long e = base + i * 256 + threadIdx.x;
        if (e < E) {
            int d = lde(ei, dir ? 0 : 1, e, E, is64);
            atomicAdd(&h[d >> BSH], 1);
        }
    }
    __syncthreads();
    for (int i = threadIdx.x; i < NB; i += 256)
        if (h[i]) atomicAdd(&bc[dir * NBMAX + i], h[i]);
}

__global__ void kb_scan(const int* __restrict__ bc, int* __restrict__ bb,
                        int* __restrict__ gcur, int NB) {
    if (threadIdx.x < 2) {
        int dir = threadIdx.x;
        int acc = 0;
        for (int i = 0; i < NB; i++) { bb[dir * (NBMAX + 1) + i] = acc; acc += bc[dir * NBMAX + i]; }
        bb[dir * (NBMAX + 1) + NB] = acc;
    }
    __syncthreads();
    for (int i = threadIdx.x; i < 2 * NBMAX; i += blockDim.x) {
        int d = i / NBMAX, b = i - d * NBMAX;
        gcur[i] = bb[d * (NBMAX + 1) + (b < NB ? b : NB)];
    }
}

// Per-block counting-sort of a 2048-edge chunk by bucket, then bucket-contiguous
// global append (mostly full 64B lines instead of 8B random scatter).
__global__ void kb_fill(const int* __restrict__ ei, long E, const int* __restrict__ flags,
                        int NB, int* __restrict__ gcur,
                        int* __restrict__ bdst, int2* __restrict__ bse) {
    __shared__ int sdst[2048], ssrc[2048], seid[2048];
    __shared__ int h[NBMAX], lofs[NBMAX], cur[NBMAX], gb[NBMAX];
    __shared__ int sc[256];
    int tid = threadIdx.x;
    int dir = blockIdx.y;
    int is64 = flags[16];
    for (int i = tid; i < NBMAX; i += 256) { h[i] = 0; cur[i] = 0; }
    __syncthreads();
    long base = (long)blockIdx.x * 2048;
    int myd[8], mys[8], mye[8];
#pragma unroll
    for (int i = 0; i < 8; i++) {
        long e = base + i * 256 + tid;
        myd[i] = -1;
        if (e < E) {
            myd[i] = lde(ei, dir ? 0 : 1, e, E, is64);
            mys[i] = lde(ei, dir ? 1 : 0, e, E, is64);
            mye[i] = (int)e;
            atomicAdd(&h[myd[i] >> BSH], 1);
        }
    }
    __syncthreads();
    int i0 = tid * 4;
    int a0 = h[i0], a1 = h[i0 + 1], a2 = h[i0 + 2], a3 = h[i0 + 3];
    int ts = a0 + a1 + a2 + a3;
    sc[tid] = ts;
    __syncthreads();
    for (int d = 1; d < 256; d <<= 1) {
        int t = (tid >= d) ? sc[tid - d] : 0;
        __syncthreads();
        sc[tid] += t;
        __syncthreads();
    }
    int eb = sc[tid] - ts;
    lofs[i0] = eb; lofs[i0 + 1] = eb + a0; lofs[i0 + 2] = eb + a0 + a1; lofs[i0 + 3] = eb + a0 + a1 + a2;
    __syncthreads();
#pragma unroll
    for (int i = 0; i < 8; i++) {
        if (myd[i] >= 0) {
            int b = myd[i] >> BSH;
            int r = atomicAdd(&cur[b], 1);
            int p = lofs[b] + r;
            sdst[p] = myd[i]; ssrc[p] = mys[i]; seid[p] = mye[i];
        }
    }
    __syncthreads();
    for (int b = tid; b < NB; b += 256) {
        int c = h[b];
        gb[b] = c ? atomicAdd(&gcur[dir * NBMAX + b], c) : 0;
    }
    __syncthreads();
    long rem = E - base;
    int nvalid = rem >= 2048 ? 2048 : (rem > 0 ? (int)rem : 0);
    int* od = bdst + (long)dir * E;
    int2* os = bse + (long)dir * E;
    for (int s = tid; s < nvalid; s += 256) {
        int b = sdst[s] >> BSH;
        long p = (long)gb[b] + (s - lofs[b]);
        od[p] = sdst[s];
        os[p] = make_int2(ssrc[s], seid[s]);
    }
}

// Per-(bucket,dir) counting sort into final per-node CSR (L2-resident window).
__global__ void kb_csr(const int* __restrict__ bb, const int* __restrict__ bdst,
                       const int2* __restrict__ bse, long E, int NB, long N,
                       int* __restrict__ off_c, int* __restrict__ off_r,
                       int2* __restrict__ list_c, int2* __restrict__ list_r) {
    __shared__ int h[256], lofs[256], cur[256], sc[256];
    int tid = threadIdx.x;
    int b = blockIdx.x, dir = blockIdx.y;
    int base = bb[dir * (NBMAX + 1) + b];
    int cnt  = bb[dir * (NBMAX + 1) + b + 1] - base;
    const int* bd = bdst + (long)dir * E;
    const int2* bs = bse + (long)dir * E;
    int* off = dir ? off_r : off_c;
    int2* list = dir ? list_r : list_c;
    h[tid] = 0; cur[tid] = 0;
    __syncthreads();
    int nb0 = b << BSH;
    for (int s = tid; s < cnt; s += 256)
        atomicAdd(&h[bd[base + s] - nb0], 1);
    __syncthreads();
    int v = h[tid];
    sc[tid] = v;
    __syncthreads();
    for (int d = 1; d < 256; d <<= 1) {
        int t = (tid >= d) ? sc[tid - d] : 0;
        __syncthreads();
        sc[tid] += t;
        __syncthreads();
    }
    lofs[tid] = sc[tid] - v;
    __syncthreads();
    long n = (long)nb0 + tid;
    if (n < N) off[n] = base + lofs[tid];
    if (b == 0 && tid == 0) off[N] = (int)E;
    for (int s = tid; s < cnt; s += 256) {
        int local = bd[base + s] - nb0;
        int r = atomicAdd(&cur[local], 1);
        list[(long)base + lofs[local] + r] = bs[base + s];
    }
}

// ================================================================ fused gather + normalize
// X3 layout: [node][3F] = up-src block | down-src block | bias block.
// One 64-lane wave per node (F<=32): lanes 0-31 up (col-CSR, X3 block 0),
// lanes 32-63 down (row-CSR, X3 block 1). No atomics.
__global__ void k_gather_fin(const int* __restrict__ off_c, const int2* __restrict__ list_c,
                             const int* __restrict__ off_r, const int2* __restrict__ list_r,
                             const void* __restrict__ ewu, const void* __restrict__ ewd,
                             int fu, int fd, const int* __restrict__ flags,
                             const float* __restrict__ X3, int F, long N,
                             float* __restrict__ out) {
    long t = (long)blockIdx.x * blockDim.x + threadIdx.x;
    long n = t >> 6;
    if (n >= N) return;
    int lane = (int)(t & 63);
    int up = lane < 32;
    int f = lane & 31;
    const int* off = up ? off_c : off_r;
    const int2* list = up ? list_c : list_r;
    const void* ew = up ? ewu : ewd;
    int ebf = flags[up ? fu : fd];
    const float* S = X3 + (up ? 0 : F);   // stride 3F rows
    int F3 = 3 * F;
    int j0 = off[n], j1 = off[n + 1];
    float acc = 0.f;
    if (f < F) {
        int j = j0;
        for (; j + 4 <= j1; j += 4) {
            int2 p0 = list[j], p1 = list[j + 1], p2 = list[j + 2], p3 = list[j + 3];
            float w0 = ldf(ew, p0.y, ebf), w1 = ldf(ew, p1.y, ebf);
            float w2 = ldf(ew, p2.y, ebf), w3 = ldf(ew, p3.y, ebf);
            float s0 = S[(long)p0.x * F3 + f], s1 = S[(long)p1.x * F3 + f];
            float s2 = S[(long)p2.x * F3 + f], s3 = S[(long)p3.x * F3 + f];
            acc += w0 * s0 + w1 * s1 + w2 * s2 + w3 * s3;
        }
        for (; j < j1; j++) {
            int2 p = list[j];
            acc += ldf(ew, p.y, ebf) * S[(long)p.x * F3 + f];
        }
    }
    int deg = j1 - j0;
    float val = (f < F && deg > 0) ? acc / (float)deg : 0.f;
    float cv = (up && f < F) ? X3[n * F3 + 2 * F + f] : 0.f;
    float ss = val * val + cv * cv;
#pragma unroll
    for (int m = 1; m < 64; m <<= 1) ss += __shfl_xor(ss, m, 64);
    float inv = 1.0f / fmaxf(sqrtf(ss), 1e-12f);
    if (f < F) {
        float a = val * inv;
        a = (a >= 0.0f) ? a : 0.1f * a;
        out[n * F3 + (up ? 0 : F) + f] = a;
        if (up) {
            float bv = cv * inv;
            bv = (bv >= 0.0f) ? bv : 0.1f * bv;
            out[n * F3 + 2 * F + f] = bv;
        }
    }
}

// ================================================================ specialized linear, din=96, dout=32x3 fused
// 32 nodes/block. x-tile in LDS (padded stride 100 -> distinct bank groups per
// node), weights transposed+fused wt[i][o3]. Thread = (node, 12 consecutive o3),
// K-loop unrolled x4, all LDS reads b128. Output: fused X3[node][96].
__global__ void k_lin96(const float* __restrict__ xin, long N,
                        const void* __restrict__ wu, const void* __restrict__ wd,
                        const void* __restrict__ wb, int wfi,
                        const int* __restrict__ flags,
                        float* __restrict__ X3) {
    __shared__ float xs[32 * 100];   // 12.8 KB
    __shared__ float wt[96 * 96];    // 36.9 KB
    int tid = threadIdx.x;
    int ubf = flags[wfi], dbf = flags[wfi + 1], bbf = flags[wfi + 2];
    for (int j = tid; j < 96 * 96; j += 256) {
        int o3 = j % 96, i = j / 96;
        float v;
        if (o3 < 32)      v = ldf(wu, (long)o3 * 96 + i, ubf);
        else if (o3 < 64) v = ldf(wd, (long)(o3 - 32) * 96 + i, dbf);
        else              v = ldf(wb, (long)(o3 - 64) * 96 + i, bbf);
        wt[j] = v;
    }
    long nb = (long)blockIdx.x * 32;
    for (int j = tid; j < 32 * 24; j += 256) {   // 768 float4, coalesced
        int node = j / 24, c = j % 24;
        long gn = nb + node;
        float4 v = make_float4(0.f, 0.f, 0.f, 0.f);
        if (gn < N) v = ((const float4*)(xin + gn * 96))[c];
        *(float4*)&xs[node * 100 + c * 4] = v;
    }
    __syncthreads();
    int node = tid >> 3;
    int o0 = (tid & 7) * 12;
    long gn = nb + node;
    float acc[12];
#pragma unroll
    for (int s = 0; s < 12; s++) acc[s] = 0.f;
    const float* xrow = &xs[node * 100];
#pragma unroll 4
    for (int c = 0; c < 24; c++) {
        float4 xv = *(const float4*)&xrow[c * 4];
        const float* w0 = &wt[(c * 4) * 96 + o0];
#pragma unroll
        for (int k = 0; k < 4; k++) {
            float xk = (k == 0) ? xv.x : (k == 1) ? xv.y : (k == 2) ? xv.z : xv.w;
            const float* wr = w0 + k * 96;
            float4 wa = *(const float4*)(wr);
            float4 wb4 = *(const float4*)(wr + 4);
            float4 wc = *(const float4*)(wr + 8);
            acc[0] += xk * wa.x;  acc[1] += xk * wa.y;  acc[2]  += xk * wa.z;  acc[3]  += xk * wa.w;
            acc[4] += xk * wb4.x; acc[5] += xk * wb4.y; acc[6]  += xk * wb4.z; acc[7]  += xk * wb4.w;
            acc[8] += xk * wc.x;  acc[9] += xk * wc.y;  acc[10] += xk * wc.z;  acc[11] += xk * wc.w;
        }
    }
    if (gn < N) {
        float* orow = X3 + gn * 96 + o0;
        *(float4*)(orow)     = make_float4(acc[0], acc[1], acc[2], acc[3]);
        *(float4*)(orow + 4) = make_float4(acc[4], acc[5], acc[6], acc[7]);
        *(float4*)(orow + 8) = make_float4(acc[8], acc[9], acc[10], acc[11]);
    }
}

// ================================================================ generic linear (layer 1 + fallback)
// Writes A[node*rs+o], B[node*rs+o], C[node*rs+o] (rs = row stride).
__global__ void k_linear(const void* __restrict__ xin, int xfi, int din, int dout, int rs, long N,
                         const void* __restrict__ wu, const void* __restrict__ wd,
                         const void* __restrict__ wb, int wfi,
                         const int* __restrict__ flags, int uselds,
                         float* __restrict__ A, float* __restrict__ B, float* __restrict__ C) {
    __shared__ float smem[12288];
    int xbf = (xfi >= 0) ? flags[xfi] : 0;
    int ubf = flags[wfi], dbf = flags[wfi + 1], bbf = flags[wfi + 2];
    float* su = smem;
    float* sd = smem + (long)din * dout;
    float* sb = smem + 2l * din * dout;
    if (uselds) {
        for (int j = threadIdx.x; j < din * dout; j += 256) {
            int o = j % dout, i = j / dout;
            su[j] = ldf(wu, (long)o * din + i, ubf);
            sd[j] = ldf(wd, (long)o * din + i, dbf);
            sb[j] = ldf(wb, (long)o * din + i, bbf);
        }
        __syncthreads();
    }
    long idx = (long)blockIdx.x * blockDim.x + threadIdx.x;
    long node = idx / dout;
    int o = (int)(idx % dout);
    if (node >= N) return;
    float au = 0.f, ad = 0.f, ab = 0.f;
    long xb = node * din;
    if (uselds) {
        for (int i = 0; i < din; i++) {
            float xv = ldf(xin, xb + i, xbf);
            au += xv * su[i * dout + o];
            ad += xv * sd[i * dout + o];
            ab += xv * sb[i * dout + o];
        }
    } else {
        for (int i = 0; i < din; i++) {
            float xv = ldf(xin, xb + i, xbf);
            au += xv * ldf(wu, (long)o * din + i, ubf);
            ad += xv * ldf(wd, (long)o * din + i, dbf);
            ab += xv * ldf(wb, (long)o * din + i, bbf);
        }
    }
    A[node * rs + o] = au;
    B[node * rs + o] = ad;
    C[node * rs + o] = ab;
}

// ================================================================ fallback (round-4 proven) kernels
__global__ void k_deg(const int* __restrict__ ei, long E, const int* __restrict__ flags,
                      float* __restrict__ degc, float* __restrict__ degr) {
    long e = (long)blockIdx.x * blockDim.x + threadIdx.x;
    if (e < E) {
        int is64 = flags[16];
        atomicAdd(&degc[lde(ei, 1, e, E, is64)], 1.0f);
        atomicAdd(&degr[lde(ei, 0, e, E, is64)], 1.0f);
    }
}

__global__ void k_inv(float* __restrict__ a, long n) {
    long i = (long)blockIdx.x * blockDim.x + threadIdx.x;
    if (i < n) { float v = a[i]; a[i] = (v > 0.0f) ? 1.0f / v : 0.0f; }
}

__global__ void k_scatter(const int* __restrict__ ei, long E, int F,
                          const void* __restrict__ ewu, const void* __restrict__ ewd,
                          int fu, int fd, const int* __restrict__ flags,
                          const float* __restrict__ degci, const float* __restrict__ degri,
                          const float* __restrict__ A, const float* __restrict__ B,
                          float* __restrict__ U, float* __restrict__ D) {
    long idx = (long)blockIdx.x * blockDim.x + threadIdx.x;
    long tot = E * 2 * F;
    if (idx >= tot) return;
    int is64 = flags[16];
    long e = idx / (2 * F);
    int rem = (int)(idx - e * 2 * F);
    int dir = rem >= F;
    int f = rem - dir * F;
    int r = lde(ei, 0, e, E, is64), c = lde(ei, 1, e, E, is64);
    if (!dir) {
        float w = degci[c] * ldf(ewu, e, flags[fu]);
        atomicAdd(&U[(long)c * F + f], w * A[(long)r * F + f]);
    } else {
        float w = degri[r] * ldf(ewd, e, flags[fd]);
        atomicAdd(&D[(long)r * F + f], w * B[(long)c * F + f]);
    }
}

__global__ void k_finalize(const float* __restrict__ U, const float* __restrict__ D,
                           const float* __restrict__ C, int F, long N,
                           float* __restrict__ out) {
    long t = (long)blockIdx.x * blockDim.x + threadIdx.x;
    long n = t >> 6;
    if (n >= N) return;
    int lane = (int)(t & 63);
    int cat = 3 * F;
    float ss = 0.f;
    for (int j = lane; j < cat; j += 64) {
        float v = (j < F) ? U[n * F + j] : (j < 2 * F) ? D[n * F + j - F] : C[n * F + j - 2 * F];
        ss += v * v;
    }
#pragma unroll
    for (int m = 1; m < 64; m <<= 1) ss += __shfl_xor(ss, m, 64);
    float inv = 1.0f / fmaxf(sqrtf(ss), 1e-12f);
    for (int j = lane; j < cat; j += 64) {
        float v = (j < F) ? U[n * F + j] : (j < 2 * F) ? D[n * F + j - F] : C[n * F + j - 2 * F];
        float a = v * inv;
        a = (a >= 0.0f) ? a : 0.1f * a;
        out[n * cat + j] = a;
    }
}

// ---------------------------------------------------------------- edge-weight means (fp32 out)
__global__ void k_mean(const void* e1u, const void* e2u, const void* e3u,
                       const void* e1d, const void* e2d, const void* e3d,
                       const int* __restrict__ flags, long E,
                       float* __restrict__ mu, float* __restrict__ md) {
    long e = (long)blockIdx.x * blockDim.x + threadIdx.x;
    if (e >= E) return;
    float su = ldf(e1u, e, flags[4]) + ldf(e2u, e, flags[9]) + ldf(e3u, e, flags[14]);
    float sd = ldf(e1d, e, flags[5]) + ldf(e2d, e, flags[10]) + ldf(e3d, e, flags[15]);
    mu[e] = su / 3.0f;
    md[e] = sd / 3.0f;
}

extern "C" void kernel_launch(void* const* d_in, const int* in_sizes, int n_in,
                              void* d_out, int out_size, void* d_ws, size_t ws_size,
                              hipStream_t stream) {
    const int* ei = (const int*)d_in[1];
    const void* w_up[3]   = {d_in[2], d_in[7],  d_in[12]};
    const void* w_down[3] = {d_in[3], d_in[8],  d_in[13]};
    const void* w_bias[3] = {d_in[4], d_in[9],  d_in[14]};
    const void* ew_up[3]  = {d_in[5], d_in[10], d_in[15]};
    const void* ew_down[3]= {d_in[6], d_in[11], d_in[16]};

    // ---- derive true sizes from in_sizes
    long E = in_sizes[5];
    if (E <= 0) E = 1600000;
    int HID = (int)(sqrt((double)in_sizes[7] / 3.0) + 0.5);
    if (HID <= 0 || (long)3 * HID * HID != (long)in_sizes[7]) HID = 32;
    int DIN = in_sizes[2] / HID;
    if (DIN <= 0) DIN = 8;
    long N = (long)in_sizes[0] / DIN;
    if (N <= 0) N = 50000;
    int EMB = in_sizes[12] / (3 * HID);
    if (EMB <= 0) EMB = 32;
    int Fm = HID > EMB ? HID : EMB;
    int NB = (int)((N + 255) >> BSH);

    // ---- outputs: fp32, concatenated (h, mean_up, mean_down)
    float* out_h  = (float*)d_out;
    float* out_mu = out_h + N * 3l * EMB;
    float* out_md = out_mu + E;

    const int TB = 256;
    int lds12 = (3l * (3 * HID) * HID <= 12288) ? 1 : 0;
    int lds1  = (3l * DIN * HID <= 12288) ? 1 : 0;
    int lds3  = (3l * (3 * HID) * EMB <= 12288) ? 1 : 0;
    dim3 linG1((unsigned)((N * HID + TB - 1) / TB));
    dim3 linG3((unsigned)((N * EMB + TB - 1) / TB));
    dim3 lin96G((unsigned)((N + 31) / 32));
    dim3 finG((unsigned)((N * 64 + TB - 1) / TB));
    dim3 edgeG((unsigned)((E + TB - 1) / TB));
    dim3 chunkG((unsigned)((E + 2047) / 2048), 2);

    // ---- fast-path workspace layout
    int* flags = (int*)d_ws;                       // 64
    int* bc    = flags + 64;                       // 2*NBMAX
    int* bb    = bc + 2 * NBMAX;                   // 2*(NBMAX+1)
    int* gcur  = bb + 2 * (NBMAX + 1);             // 2*NBMAX
    int* off_c = gcur + 2 * NBMAX;                 // N+1
    int* off_r = off_c + (N + 1);                  // N+1
    long li = (long)(off_r + (N + 1) - (int*)d_ws);
    li = (li + 3) & ~3l;                           // 16B-align lists
    int2* list_c = (int2*)((int*)d_ws + li);       // E
    int2* list_r = list_c + E;                     // E
    int* scratch = (int*)(list_r + E);
    // bucket phase overlay:
    int* bdst = scratch;                           // 2E ints (dir-major)
    int2* bse = (int2*)(scratch + 2 * E);          // 2E int2
    // linear phase overlay (after kb_csr, bucket arrays dead):
    float* X3 = (float*)scratch;                   // N*3*Fm fused activations
    float* H  = X3 + N * 3l * Fm;                  // N*3*HID
    long scrInts = 6 * E;
    long linInts = N * (3l * Fm + 3l * HID);
    if (linInts > scrInts) scrInts = linInts;
    size_t need = (size_t)((li + 4 * E + scrInts) * 4l + 256);

    bool fast = (HID <= 32 && EMB <= 32) && (NB <= NBMAX) &&
                (ws_size == 0 || ws_size >= need);
    bool use96_2 = fast && (HID == 32);            // layer2: din=96, fused dout=96
    bool use96_3 = fast && (HID == 32 && EMB == 32);

    // ---- dtype detection (both paths)
    DetectArgs da;
    da.p[0] = d_in[0]; da.n[0] = in_sizes[0];
    for (int L = 0; L < 3; L++) {
        da.p[1 + 5 * L] = w_up[L];    da.n[1 + 5 * L] = in_sizes[2 + 5 * L];
        da.p[2 + 5 * L] = w_down[L];  da.n[2 + 5 * L] = in_sizes[3 + 5 * L];
        da.p[3 + 5 * L] = w_bias[L];  da.n[3 + 5 * L] = in_sizes[4 + 5 * L];
        da.p[4 + 5 * L] = ew_up[L];   da.n[4 + 5 * L] = in_sizes[5 + 5 * L];
        da.p[5 + 5 * L] = ew_down[L]; da.n[5 + 5 * L] = in_sizes[6 + 5 * L];
    }
    da.ei = ei; da.E = E; da.flags = flags;
    k_detect<<<17, TB, 0, stream>>>(da);

    if (fast) {
        // ---- bucketed CSR build (once; reused 3 layers x 2 directions)
        hipMemsetAsync(bc, 0, 2 * NBMAX * sizeof(int), stream);
        kb_count<<<chunkG, TB, 0, stream>>>(ei, E, flags, NB, bc);
        kb_scan<<<1, 512, 0, stream>>>(bc, bb, gcur, NB);
        kb_fill<<<chunkG, TB, 0, stream>>>(ei, E, flags, NB, gcur, bdst, bse);
        kb_csr<<<dim3((unsigned)NB, 2), TB, 0, stream>>>(bb, bdst, bse, E, NB, N,
                                                         off_c, off_r, list_c, list_r);

        // ---- layer 1 (din=DIN, generic, fused X3 output)
        k_linear<<<linG1, TB, 0, stream>>>(d_in[0], 0, DIN, HID, 3 * HID, N,
                                           w_up[0], w_down[0], w_bias[0], 1, flags, lds1,
                                           X3, X3 + HID, X3 + 2 * HID);
        k_gather_fin<<<finG, TB, 0, stream>>>(off_c, list_c, off_r, list_r,
                                              ew_up[0], ew_down[0], 4, 5, flags,
                                              X3, HID, N, H);
        // ---- layer 2 (din=96 specialized)
        if (use96_2)
            k_lin96<<<lin96G, TB, 0, stream>>>(H, N, w_up[1], w_down[1], w_bias[1], 6, flags, X3);
        else
            k_linear<<<linG1, TB, 0, stream>>>(H, -1, 3 * HID, HID, 3 * HID, N,
                                               w_up[1], w_down[1], w_bias[1], 6, flags, lds12,
                                               X3, X3 + HID, X3 + 2 * HID);
        k_gather_fin<<<finG, TB, 0, stream>>>(off_c, list_c, off_r, list_r,
                                              ew_up[1], ew_down[1], 9, 10, flags,
                                              X3, HID, N, H);
        // ---- layer 3 -> fp32 output
        if (use96_3)
            k_lin96<<<lin96G, TB, 0, stream>>>(H, N, w_up[2], w_down[2], w_bias[2], 11, flags, X3);
        else
            k_linear<<<linG3, TB, 0, stream>>>(H, -1, 3 * HID, EMB, 3 * EMB, N,
                                               w_up[2], w_down[2], w_bias[2], 11, flags, lds3,
                                               X3, X3 + EMB, X3 + 2 * EMB);
        k_gather_fin<<<finG, TB, 0, stream>>>(off_c, list_c, off_r, list_r,
                                              ew_up[2], ew_down[2], 14, 15, flags,
                                              X3, EMB, N, out_h);
    } else {
        // ---- fallback: round-4 proven atomic-scatter path
        float* degci = (float*)(flags + 64);
        float* degri = degci + N;
        float* fA = degri + N;
        float* fB = fA + N * Fm;
        float* fC = fB + N * Fm;
        float* fU = fC + N * Fm;
        float* fD = fU + N * Fm;
        float* fH = fD + N * Fm;
        dim3 scatG12((unsigned)((E * 2 * HID + TB - 1) / TB));
        dim3 scatG3((unsigned)((E * 2 * EMB + TB - 1) / TB));

        hipMemsetAsync(degci, 0, 2 * N * sizeof(float), stream);
        k_deg<<<edgeG, TB, 0, stream>>>(ei, E, flags, degci, degri);
        k_inv<<<dim3((unsigned)((2 * N + TB - 1) / TB)), TB, 0, stream>>>(degci, 2 * N);

        k_linear<<<linG1, TB, 0, stream>>>(d_in[0], 0, DIN, HID, HID, N,
                                           w_up[0], w_down[0], w_bias[0], 1, flags, lds1, fA, fB, fC);
        hipMemsetAsync(fU, 0, 2l * N * Fm * sizeof(float), stream);
        k_scatter<<<scatG12, TB, 0, stream>>>(ei, E, HID, ew_up[0], ew_down[0], 4, 5, flags,
                                              degci, degri, fA, fB, fU, fD);
        k_finalize<<<finG, TB, 0, stream>>>(fU, fD, fC, HID, N, fH);

        k_linear<<<linG1, TB, 0, stream>>>(fH, -1, 3 * HID, HID, HID, N,
                                           w_up[1], w_down[1], w_bias[1], 6, flags, lds12, fA, fB, fC);
        hipMemsetAsync(fU, 0, 2l * N * Fm * sizeof(float), stream);
        k_scatter<<<scatG12, TB, 0, stream>>>(ei, E, HID, ew_up[1], ew_down[1], 9, 10, flags,
                                              degci, degri, fA, fB, fU, fD);
        k_finalize<<<finG, TB, 0, stream>>>(fU, fD, fC, HID, N, fH);

        k_linear<<<linG3, TB, 0, stream>>>(fH, -1, 3 * HID, EMB, EMB, N,
                                           w_up[2], w_down[2], w_bias[2], 11, flags, lds3, fA, fB, fC);
        hipMemsetAsync(fU, 0, 2l * N * Fm * sizeof(float), stream);
        k_scatter<<<scatG3, TB, 0, stream>>>(ei, E, EMB, ew_up[2], ew_down[2], 14, 15, flags,
                                             degci, degri, fA, fB, fU, fD);
        k_finalize<<<finG, TB, 0, stream>>>(fU, fD, fC, EMB, N, out_h);
    }

    // ---- edge-weight means
    k_mean<<<edgeG, TB, 0, stream>>>(ew_up[0], ew_up[1], ew_up[2],
                                     ew_down[0], ew_down[1], ew_down[2],
                                     flags, E, out_mu, out_md);
}

// Round 8
// 777.921 us; speedup vs baseline: 2.5769x; 1.1375x over previous
//
#include <hip/hip_runtime.h>
#include <hip/hip_bf16.h>
#include <math.h>

typedef __hip_bfloat16 bf16;
typedef unsigned short ushort_t;

#define NBMAX 1024   // max buckets (N <= 262144 for fast path)
#define BSH 8        // 256 nodes per bucket

// flags[0..15]: 1 if float-array slot is bf16, 0 if fp32.
//   slot 0:x | per layer L(0..2): 1+5L:w_up 2+5L:w_down 3+5L:w_bias 4+5L:ew_up 5+5L:ew_down
// flags[16]: 1 if edge_index is int64 (little-endian, values < 2^31), else int32.
__device__ __forceinline__ float ldf(const void* p, long i, int isbf) {
    return isbf ? __bfloat162float(((const bf16*)p)[i]) : ((const float*)p)[i];
}
__device__ __forceinline__ int lde(const int* ei, int half, long e, long E, int is64) {
    long idx = half ? (E + e) : e;
    return is64 ? ei[idx * 2] : ei[idx];
}
__device__ __forceinline__ float u2f(ushort_t u) {
    union { unsigned int i; float f; } v; v.i = ((unsigned)u) << 16; return v.f;
}
__device__ __forceinline__ ushort_t f2u(float f) {
    bf16 h = __float2bfloat16(f);
    return *reinterpret_cast<ushort_t*>(&h);
}

// ---------------------------------------------------------------- dtype detection
struct DetectArgs {
    const void* p[16];
    long n[16];
    const int* ei;
    long E;
    int* flags;
};

__global__ void k_detect(DetectArgs a) {
    __shared__ int cnt;
    if (threadIdx.x == 0) cnt = 0;
    __syncthreads();
    int b = blockIdx.x;
    int bad = 0;
    if (b < 16) {
        const bf16* p = (const bf16*)a.p[b];
        long m = a.n[b] < 4096 ? a.n[b] : 4096;
        for (long i = threadIdx.x; i < m; i += 256) {
            float v = __bfloat162float(p[i]);
            if (!(fabsf(v) < 100.0f)) bad++;
        }
        atomicAdd(&cnt, bad);
        __syncthreads();
        if (threadIdx.x == 0) a.flags[b] = ((long)cnt * 16 < m) ? 1 : 0;
    } else {
        long m = a.E / 2 < 4096 ? a.E / 2 : 4096;
        for (long i = threadIdx.x; i < m; i += 256) {
            if (a.ei[2 * i + 1] != 0) bad++;
        }
        atomicAdd(&cnt, bad);
        __syncthreads();
        if (threadIdx.x == 0) a.flags[16] = (cnt < (int)(m / 16) + 1) ? 1 : 0;
    }
}

// ================================================================ bucketed CSR build
// dir 0: dst=col (up-list), dir 1: dst=row (down-list). bucket = dst>>8.

__global__ void kb_count(const int* __restrict__ ei, long E, const int* __restrict__ flags,
                         int NB, int* __restrict__ bc) {
    __shared__ int h[NBMAX];
    for (int i = threadIdx.x; i < NB; i += 256) h[i] = 0;
    __syncthreads();
    int dir = blockIdx.y;
    int is64 = flags[16];
    long base = (long)blockIdx.x * 2048;
#pragma unroll
    for (int i = 0; i < 8; i++) {
        long e = base + i * 256 + threadIdx.x;
        if (e < E) {
            int d = lde(ei, dir ? 0 : 1, e, E, is64);
            atomicAdd(&h[d >> BSH], 1);
        }
    }
    __syncthreads();
    for (int i = threadIdx.x; i < NB; i += 256)
        if (h[i]) atomicAdd(&bc[dir * NBMAX + i], h[i]);
}

__global__ void kb_scan(const int* __restrict__ bc, int* __restrict__ bb,
                        int* __restrict__ gcur, int NB) {
    if (threadIdx.x < 2) {
        int dir = threadIdx.x;
        int acc = 0;
        for (int i = 0; i < NB; i++) { bb[dir * (NBMAX + 1) + i] = acc; acc += bc[dir * NBMAX + i]; }
        bb[dir * (NBMAX + 1) + NB] = acc;
    }
    __syncthreads();
    for (int i = threadIdx.x; i < 2 * NBMAX; i += blockDim.x) {
        int d = i / NBMAX, b = i - d * NBMAX;
        gcur[i] = bb[d * (NBMAX + 1) + (b < NB ? b : NB)];
    }
}

// Per-block counting-sort of a 2048-edge chunk by bucket, then bucket-contiguous
// global append (mostly full 64B lines instead of 8B random scatter).
__global__ void kb_fill(const int* __restrict__ ei, long E, const int* __restrict__ flags,
                        int NB, int* __restrict__ gcur,
                        int* __restrict__ bdst, int2* __restrict__ bse) {
    __shared__ int sdst[2048], ssrc[2048], seid[2048];
    __shared__ int h[NBMAX], lofs[NBMAX], cur[NBMAX], gb[NBMAX];
    __shared__ int sc[256];
    int tid = threadIdx.x;
    int dir = blockIdx.y;
    int is64 = flags[16];
    for (int i = tid; i < NBMAX; i += 256) { h[i] = 0; cur[i] = 0; }
    __syncthreads();
    long base = (long)blockIdx.x * 2048;
    int myd[8], mys[8], mye[8];
#pragma unroll
    for (int i = 0; i < 8; i++) {
        long e = base + i * 256 + tid;
        myd[i] = -1;
        if (e < E) {
            myd[i] = lde(ei, dir ? 0 : 1, e, E, is64);
            mys[i] = lde(ei, dir ? 1 : 0, e, E, is64);
            mye[i] = (int)e;
            atomicAdd(&h[myd[i] >> BSH], 1);
        }
    }
    __syncthreads();
    int i0 = tid * 4;
    int a0 = h[i0], a1 = h[i0 + 1], a2 = h[i0 + 2], a3 = h[i0 + 3];
    int ts = a0 + a1 + a2 + a3;
    sc[tid] = ts;
    __syncthreads();
    for (int d = 1; d < 256; d <<= 1) {
        int t = (tid >= d) ? sc[tid - d] : 0;
        __syncthreads();
        sc[tid] += t;
        __syncthreads();
    }
    int eb = sc[tid] - ts;
    lofs[i0] = eb; lofs[i0 + 1] = eb + a0; lofs[i0 + 2] = eb + a0 + a1; lofs[i0 + 3] = eb + a0 + a1 + a2;
    __syncthreads();
#pragma unroll
    for (int i = 0; i < 8; i++) {
        if (myd[i] >= 0) {
            int b = myd[i] >> BSH;
            int r = atomicAdd(&cur[b], 1);
            int p = lofs[b] + r;
            sdst[p] = myd[i]; ssrc[p] = mys[i]; seid[p] = mye[i];
        }
    }
    __syncthreads();
    for (int b = tid; b < NB; b += 256) {
        int c = h[b];
        gb[b] = c ? atomicAdd(&gcur[dir * NBMAX + b], c) : 0;
    }
    __syncthreads();
    long rem = E - base;
    int nvalid = rem >= 2048 ? 2048 : (rem > 0 ? (int)rem : 0);
    int* od = bdst + (long)dir * E;
    int2* os = bse + (long)dir * E;
    for (int s = tid; s < nvalid; s += 256) {
        int b = sdst[s] >> BSH;
        long p = (long)gb[b] + (s - lofs[b]);
        od[p] = sdst[s];
        os[p] = make_int2(ssrc[s], seid[s]);
    }
}

// Per-(bucket,dir) counting sort into final per-node CSR (L2-resident window).
__global__ void kb_csr(const int* __restrict__ bb, const int* __restrict__ bdst,
                       const int2* __restrict__ bse, long E, int NB, long N,
                       int* __restrict__ off_c, int* __restrict__ off_r,
                       int2* __restrict__ list_c, int2* __restrict__ list_r) {
    __shared__ int h[256], lofs[256], cur[256], sc[256];
    int tid = threadIdx.x;
    int b = blockIdx.x, dir = blockIdx.y;
    int base = bb[dir * (NBMAX + 1) + b];
    int cnt  = bb[dir * (NBMAX + 1) + b + 1] - base;
    const int* bd = bdst + (long)dir * E;
    const int2* bs = bse + (long)dir * E;
    int* off = dir ? off_r : off_c;
    int2* list = dir ? list_r : list_c;
    h[tid] = 0; cur[tid] = 0;
    __syncthreads();
    int nb0 = b << BSH;
    for (int s = tid; s < cnt; s += 256)
        atomicAdd(&h[bd[base + s] - nb0], 1);
    __syncthreads();
    int v = h[tid];
    sc[tid] = v;
    __syncthreads();
    for (int d = 1; d < 256; d <<= 1) {
        int t = (tid >= d) ? sc[tid - d] : 0;
        __syncthreads();
        sc[tid] += t;
        __syncthreads();
    }
    lofs[tid] = sc[tid] - v;
    __syncthreads();
    long n = (long)nb0 + tid;
    if (n < N) off[n] = base + lofs[tid];
    if (b == 0 && tid == 0) off[N] = (int)E;
    for (int s = tid; s < cnt; s += 256) {
        int local = bd[base + s] - nb0;
        int r = atomicAdd(&cur[local], 1);
        list[(long)base + lofs[local] + r] = bs[base + s];
    }
}

// ================================================================ per-layer bf16 edge-weight cast
__global__ void k_ewcast(const void* __restrict__ ewu, const void* __restrict__ ewd,
                         int fu, int fd, const int* __restrict__ flags, long E,
                         ushort_t* __restrict__ ebu, ushort_t* __restrict__ ebd) {
    long e = (long)blockIdx.x * blockDim.x + threadIdx.x;
    if (e >= E) return;
    ebu[e] = f2u(ldf(ewu, e, flags[fu]));
    ebd[e] = f2u(ldf(ewd, e, flags[fd]));
}

// ================================================================ fused gather + normalize (bf16 sources)
// Su/Sd/Sb: [N][F] bf16. One 64-lane wave per node: lanes 0-31 up (col-CSR over
// Su), lanes 32-63 down (row-CSR over Sd). 64B row per edge, unroll x8.
__global__ void k_gather_fin(const int* __restrict__ off_c, const int2* __restrict__ list_c,
                             const int* __restrict__ off_r, const int2* __restrict__ list_r,
                             const ushort_t* __restrict__ ebu, const ushort_t* __restrict__ ebd,
                             const ushort_t* __restrict__ Su, const ushort_t* __restrict__ Sd,
                             const ushort_t* __restrict__ Sb, int F, long N,
                             float* __restrict__ out) {
    long t = (long)blockIdx.x * blockDim.x + threadIdx.x;
    long n = t >> 6;
    if (n >= N) return;
    int lane = (int)(t & 63);
    int up = lane < 32;
    int f = lane & 31;
    const int* off = up ? off_c : off_r;
    const int2* list = up ? list_c : list_r;
    const ushort_t* ewb = up ? ebu : ebd;
    const ushort_t* S = up ? Su : Sd;
    int j0 = off[n], j1 = off[n + 1];
    float acc = 0.f;
    if (f < F) {
        int j = j0;
        for (; j + 8 <= j1; j += 8) {
            int2 p[8];
#pragma unroll
            for (int k = 0; k < 8; k++) p[k] = list[j + k];
            float w[8], s[8];
#pragma unroll
            for (int k = 0; k < 8; k++) {
                w[k] = u2f(ewb[p[k].y]);
                s[k] = u2f(S[(long)p[k].x * F + f]);
            }
#pragma unroll
            for (int k = 0; k < 8; k++) acc += w[k] * s[k];
        }
        for (; j < j1; j++) {
            int2 p = list[j];
            acc += u2f(ewb[p.y]) * u2f(S[(long)p.x * F + f]);
        }
    }
    int deg = j1 - j0;
    float val = (f < F && deg > 0) ? acc / (float)deg : 0.f;
    float cv = (up && f < F) ? u2f(Sb[n * F + f]) : 0.f;
    float ss = val * val + cv * cv;
#pragma unroll
    for (int m = 1; m < 64; m <<= 1) ss += __shfl_xor(ss, m, 64);
    float inv = 1.0f / fmaxf(sqrtf(ss), 1e-12f);
    int F3 = 3 * F;
    if (f < F) {
        float a = val * inv;
        a = (a >= 0.0f) ? a : 0.1f * a;
        out[n * F3 + (up ? 0 : F) + f] = a;
        if (up) {
            float bv = cv * inv;
            bv = (bv >= 0.0f) ? bv : 0.1f * bv;
            out[n * F3 + 2 * F + f] = bv;
        }
    }
}

// ================================================================ specialized linear, din=96, dout=3x32 fused, bf16 out
// 32 nodes/block. x-tile in LDS (padded stride 100), weights transposed+fused
// wt[i][o3]. Thread = (node, 12 consecutive o3), K-loop x4, LDS reads b128.
// Output staged in LDS (reusing xs) then written coalesced to Su/Sd/Sb bf16.
__global__ void k_lin96(const float* __restrict__ xin, long N,
                        const void* __restrict__ wu, const void* __restrict__ wd,
                        const void* __restrict__ wb, int wfi,
                        const int* __restrict__ flags,
                        ushort_t* __restrict__ Su, ushort_t* __restrict__ Sd,
                        ushort_t* __restrict__ Sb) {
    __shared__ float xs[32 * 100];   // 12.8 KB (reused as bf16 staging after compute)
    __shared__ float wt[96 * 96];    // 36.9 KB
    int tid = threadIdx.x;
    int ubf = flags[wfi], dbf = flags[wfi + 1], bbf = flags[wfi + 2];
    for (int j = tid; j < 96 * 96; j += 256) {
        int o3 = j % 96, i = j / 96;
        float v;
        if (o3 < 32)      v = ldf(wu, (long)o3 * 96 + i, ubf);
        else if (o3 < 64) v = ldf(wd, (long)(o3 - 32) * 96 + i, dbf);
        else              v = ldf(wb, (long)(o3 - 64) * 96 + i, bbf);
        wt[j] = v;
    }
    long nb = (long)blockIdx.x * 32;
    for (int j = tid; j < 32 * 24; j += 256) {   // 768 float4, coalesced
        int node = j / 24, c = j % 24;
        long gn = nb + node;
        float4 v = make_float4(0.f, 0.f, 0.f, 0.f);
        if (gn < N) v = ((const float4*)(xin + gn * 96))[c];
        *(float4*)&xs[node * 100 + c * 4] = v;
    }
    __syncthreads();
    int node = tid >> 3;
    int o0 = (tid & 7) * 12;
    float acc[12];
#pragma unroll
    for (int s = 0; s < 12; s++) acc[s] = 0.f;
    const float* xrow = &xs[node * 100];
#pragma unroll 4
    for (int c = 0; c < 24; c++) {
        float4 xv = *(const float4*)&xrow[c * 4];
        const float* w0 = &wt[(c * 4) * 96 + o0];
#pragma unroll
        for (int k = 0; k < 4; k++) {
            float xk = (k == 0) ? xv.x : (k == 1) ? xv.y : (k == 2) ? xv.z : xv.w;
            const float* wr = w0 + k * 96;
            float4 wa = *(const float4*)(wr);
            float4 wb4 = *(const float4*)(wr + 4);
            float4 wc = *(const float4*)(wr + 8);
            acc[0] += xk * wa.x;  acc[1] += xk * wa.y;  acc[2]  += xk * wa.z;  acc[3]  += xk * wa.w;
            acc[4] += xk * wb4.x; acc[5] += xk * wb4.y; acc[6]  += xk * wb4.z; acc[7]  += xk * wb4.w;
            acc[8] += xk * wc.x;  acc[9] += xk * wc.y;  acc[10] += xk * wc.z;  acc[11] += xk * wc.w;
        }
    }
    __syncthreads();                       // everyone done reading xs
    ushort_t* sbuf = (ushort_t*)xs;        // 32*96 ushorts = 6 KB staging
#pragma unroll
    for (int s = 0; s < 12; s++) sbuf[node * 96 + o0 + s] = f2u(acc[s]);
    __syncthreads();
    for (int j = tid; j < 32 * 96; j += 256) {
        int nd = j / 96, o3 = j % 96;
        long gn = nb + nd;
        if (gn < N) {
            int blk = o3 >> 5, fo = o3 & 31;
            ushort_t v = sbuf[j];
            (blk == 0 ? Su : blk == 1 ? Sd : Sb)[gn * 32 + fo] = v;
        }
    }
}

// ================================================================ generic linear -> bf16 S arrays (layer 1)
__global__ void k_linear_b16(const void* __restrict__ xin, int xfi, int din, int dout, long N,
                             const void* __restrict__ wu, const void* __restrict__ wd,
                             const void* __restrict__ wb, int wfi,
                             const int* __restrict__ flags, int uselds,
                             ushort_t* __restrict__ Su, ushort_t* __restrict__ Sd,
                             ushort_t* __restrict__ Sb) {
    __shared__ float smem[12288];
    int xbf = (xfi >= 0) ? flags[xfi] : 0;
    int ubf = flags[wfi], dbf = flags[wfi + 1], bbf = flags[wfi + 2];
    float* su = smem;
    float* sd = smem + (long)din * dout;
    float* sb = smem + 2l * din * dout;
    if (uselds) {
        for (int j = threadIdx.x; j < din * dout; j += 256) {
            int o = j % dout, i = j / dout;
            su[j] = ldf(wu, (long)o * din + i, ubf);
            sd[j] = ldf(wd, (long)o * din + i, dbf);
            sb[j] = ldf(wb, (long)o * din + i, bbf);
        }
        __syncthreads();
    }
    long idx = (long)blockIdx.x * blockDim.x + threadIdx.x;
    long node = idx / dout;
    int o = (int)(idx % dout);
    if (node >= N) return;
    float au = 0.f, ad = 0.f, ab = 0.f;
    long xb = node * din;
    if (uselds) {
        for (int i = 0; i < din; i++) {
            float xv = ldf(xin, xb + i, xbf);
            au += xv * su[i * dout + o];
            ad += xv * sd[i * dout + o];
            ab += xv * sb[i * dout + o];
        }
    } else {
        for (int i = 0; i < din; i++) {
            float xv = ldf(xin, xb + i, xbf);
            au += xv * ldf(wu, (long)o * din + i, ubf);
            ad += xv * ldf(wd, (long)o * din + i, dbf);
            ab += xv * ldf(wb, (long)o * din + i, bbf);
        }
    }
    Su[node * dout + o] = f2u(au);
    Sd[node * dout + o] = f2u(ad);
    Sb[node * dout + o] = f2u(ab);
}

// ================================================================ fallback (round-4 proven) kernels
__global__ void k_linear(const void* __restrict__ xin, int xfi, int din, int dout, int rs, long N,
                         const void* __restrict__ wu, const void* __restrict__ wd,
                         const void* __restrict__ wb, int wfi,
                         const int* __restrict__ flags, int uselds,
                         float* __restrict__ A, float* __restrict__ B, float* __restrict__ C) {
    __shared__ float smem[12288];
    int xbf = (xfi >= 0) ? flags[xfi] : 0;
    int ubf = flags[wfi], dbf = flags[wfi + 1], bbf = flags[wfi + 2];
    float* su = smem;
    float* sd = smem + (long)din * dout;
    float* sb = smem + 2l * din * dout;
    if (uselds) {
        for (int j = threadIdx.x; j < din * dout; j += 256) {
            int o = j % dout, i = j / dout;
            su[j] = ldf(wu, (long)o * din + i, ubf);
            sd[j] = ldf(wd, (long)o * din + i, dbf);
            sb[j] = ldf(wb, (long)o * din + i, bbf);
        }
        __syncthreads();
    }
    long idx = (long)blockIdx.x * blockDim.x + threadIdx.x;
    long node = idx / dout;
    int o = (int)(idx % dout);
    if (node >= N) return;
    float au = 0.f, ad = 0.f, ab = 0.f;
    long xb = node * din;
    if (uselds) {
        for (int i = 0; i < din; i++) {
            float xv = ldf(xin, xb + i, xbf);
            au += xv * su[i * dout + o];
            ad += xv * sd[i * dout + o];
            ab += xv * sb[i * dout + o];
        }
    } else {
        for (int i = 0; i < din; i++) {
            float xv = ldf(xin, xb + i, xbf);
            au += xv * ldf(wu, (long)o * din + i, ubf);
            ad += xv * ldf(wd, (long)o * din + i, dbf);
            ab += xv * ldf(wb, (long)o * din + i, bbf);
        }
    }
    A[node * rs + o] = au;
    B[node * rs + o] = ad;
    C[node * rs + o] = ab;
}

__global__ void k_deg(const int* __restrict__ ei, long E, const int* __restrict__ flags,
                      float* __restrict__ degc, float* __restrict__ degr) {
    long e = (long)blockIdx.x * blockDim.x + threadIdx.x;
    if (e < E) {
        int is64 = flags[16];
        atomicAdd(&degc[lde(ei, 1, e, E, is64)], 1.0f);
        atomicAdd(&degr[lde(ei, 0, e, E, is64)], 1.0f);
    }
}

__global__ void k_inv(float* __restrict__ a, long n) {
    long i = (long)blockIdx.x * blockDim.x + threadIdx.x;
    if (i < n) { float v = a[i]; a[i] = (v > 0.0f) ? 1.0f / v : 0.0f; }
}

__global__ void k_scatter(const int* __restrict__ ei, long E, int F,
                          const void* __restrict__ ewu, const void* __restrict__ ewd,
                          int fu, int fd, const int* __restrict__ flags,
                          const float* __restrict__ degci, const float* __restrict__ degri,
                          const float* __restrict__ A, const float* __restrict__ B,
                          float* __restrict__ U, float* __restrict__ D) {
    long idx = (long)blockIdx.x * blockDim.x + threadIdx.x;
    long tot = E * 2 * F;
    if (idx >= tot) return;
    int is64 = flags[16];
    long e = idx / (2 * F);
    int rem = (int)(idx - e * 2 * F);
    int dir = rem >= F;
    int f = rem - dir * F;
    int r = lde(ei, 0, e, E, is64), c = lde(ei, 1, e, E, is64);
    if (!dir) {
        float w = degci[c] * ldf(ewu, e, flags[fu]);
        atomicAdd(&U[(long)c * F + f], w * A[(long)r * F + f]);
    } else {
        float w = degri[r] * ldf(ewd, e, flags[fd]);
        atomicAdd(&D[(long)r * F + f], w * B[(long)c * F + f]);
    }
}

__global__ void k_finalize(const float* __restrict__ U, const float* __restrict__ D,
                           const float* __restrict__ C, int F, long N,
                           float* __restrict__ out) {
    long t = (long)blockIdx.x * blockDim.x + threadIdx.x;
    long n = t >> 6;
    if (n >= N) return;
    int lane = (int)(t & 63);
    int cat = 3 * F;
    float ss = 0.f;
    for (int j = lane; j < cat; j += 64) {
        float v = (j < F) ? U[n * F + j] : (j < 2 * F) ? D[n * F + j - F] : C[n * F + j - 2 * F];
        ss += v * v;
    }
#pragma unroll
    for (int m = 1; m < 64; m <<= 1) ss += __shfl_xor(ss, m, 64);
    float inv = 1.0f / fmaxf(sqrtf(ss), 1e-12f);
    for (int j = lane; j < cat; j += 64) {
        float v = (j < F) ? U[n * F + j] : (j < 2 * F) ? D[n * F + j - F] : C[n * F + j - 2 * F];
        float a = v * inv;
        a = (a >= 0.0f) ? a : 0.1f * a;
        out[n * cat + j] = a;
    }
}

// ---------------------------------------------------------------- edge-weight means (fp32 out)
__global__ void k_mean(const void* e1u, const void* e2u, const void* e3u,
                       const void* e1d, const void* e2d, const void* e3d,
                       const int* __restrict__ flags, long E,
                       float* __restrict__ mu, float* __restrict__ md) {
    long e = (long)blockIdx.x * blockDim.x + threadIdx.x;
    if (e >= E) return;
    float su = ldf(e1u, e, flags[4]) + ldf(e2u, e, flags[9]) + ldf(e3u, e, flags[14]);
    float sd = ldf(e1d, e, flags[5]) + ldf(e2d, e, flags[10]) + ldf(e3d, e, flags[15]);
    mu[e] = su / 3.0f;
    md[e] = sd / 3.0f;
}

extern "C" void kernel_launch(void* const* d_in, const int* in_sizes, int n_in,
                              void* d_out, int out_size, void* d_ws, size_t ws_size,
                              hipStream_t stream) {
    const int* ei = (const int*)d_in[1];
    const void* w_up[3]   = {d_in[2], d_in[7],  d_in[12]};
    const void* w_down[3] = {d_in[3], d_in[8],  d_in[13]};
    const void* w_bias[3] = {d_in[4], d_in[9],  d_in[14]};
    const void* ew_up[3]  = {d_in[5], d_in[10], d_in[15]};
    const void* ew_down[3]= {d_in[6], d_in[11], d_in[16]};

    // ---- derive true sizes from in_sizes
    long E = in_sizes[5];
    if (E <= 0) E = 1600000;
    int HID = (int)(sqrt((double)in_sizes[7] / 3.0) + 0.5);
    if (HID <= 0 || (long)3 * HID * HID != (long)in_sizes[7]) HID = 32;
    int DIN = in_sizes[2] / HID;
    if (DIN <= 0) DIN = 8;
    long N = (long)in_sizes[0] / DIN;
    if (N <= 0) N = 50000;
    int EMB = in_sizes[12] / (3 * HID);
    if (EMB <= 0) EMB = 32;
    int Fm = HID > EMB ? HID : EMB;
    int NB = (int)((N + 255) >> BSH);

    // ---- outputs: fp32, concatenated (h, mean_up, mean_down)
    float* out_h  = (float*)d_out;
    float* out_mu = out_h + N * 3l * EMB;
    float* out_md = out_mu + E;

    const int TB = 256;
    int lds1  = (3l * DIN * HID <= 12288) ? 1 : 0;
    int lds12 = (3l * (3 * HID) * HID <= 12288) ? 1 : 0;
    int lds3  = (3l * (3 * HID) * EMB <= 12288) ? 1 : 0;
    dim3 linG1((unsigned)((N * HID + TB - 1) / TB));
    dim3 linG3((unsigned)((N * EMB + TB - 1) / TB));
    dim3 lin96G((unsigned)((N + 31) / 32));
    dim3 finG((unsigned)((N * 64 + TB - 1) / TB));
    dim3 edgeG((unsigned)((E + TB - 1) / TB));
    dim3 chunkG((unsigned)((E + 2047) / 2048), 2);

    // ---- fast-path workspace layout
    int* flags = (int*)d_ws;                       // 64
    int* bc    = flags + 64;                       // 2*NBMAX
    int* bb    = bc + 2 * NBMAX;                   // 2*(NBMAX+1)
    int* gcur  = bb + 2 * (NBMAX + 1);             // 2*NBMAX
    int* off_c = gcur + 2 * NBMAX;                 // N+1
    int* off_r = off_c + (N + 1);                  // N+1
    long li = (long)(off_r + (N + 1) - (int*)d_ws);
    li = (li + 3) & ~3l;                           // 16B-align lists
    int2* list_c = (int2*)((int*)d_ws + li);       // E
    int2* list_r = list_c + E;                     // E
    int* scratch = (int*)(list_r + E);
    // bucket phase overlay:
    int* bdst = scratch;                           // 2E ints (dir-major)
    int2* bse = (int2*)(scratch + 2 * E);          // 2E int2
    // compute phase overlay (after kb_csr, bucket arrays dead):
    ushort_t* ebu = (ushort_t*)scratch;            // E bf16 (per-layer rewritten)
    ushort_t* ebd = ebu + E;                       // E bf16
    ushort_t* Su  = ebd + E;                       // N*Fm bf16
    ushort_t* Sd  = Su + N * Fm;                   // N*Fm bf16
    ushort_t* Sb  = Sd + N * Fm;                   // N*Fm bf16
    float* H = (float*)(((uintptr_t)(Sb + N * Fm) + 15) & ~(uintptr_t)15);  // N*3*HID fp32
    long postBytes = (uintptr_t)((char*)(H + N * 3l * HID)) - (uintptr_t)scratch;
    long scrBytes = 6l * E * 4;
    if (postBytes > scrBytes) scrBytes = postBytes;
    size_t need = (size_t)(li * 4l + 16l * E + scrBytes + 256);

    bool fast = (HID <= 32 && EMB <= 32) && (NB <= NBMAX) &&
                (ws_size == 0 || ws_size >= need);
    bool use96_2 = fast && (HID == 32);
    bool use96_3 = fast && (HID == 32 && EMB == 32);

    // ---- dtype detection (both paths)
    DetectArgs da;
    da.p[0] = d_in[0]; da.n[0] = in_sizes[0];
    for (int L = 0; L < 3; L++) {
        da.p[1 + 5 * L] = w_up[L];    da.n[1 + 5 * L] = in_sizes[2 + 5 * L];
        da.p[2 + 5 * L] = w_down[L];  da.n[2 + 5 * L] = in_sizes[3 + 5 * L];
        da.p[3 + 5 * L] = w_bias[L];  da.n[3 + 5 * L] = in_sizes[4 + 5 * L];
        da.p[4 + 5 * L] = ew_up[L];   da.n[4 + 5 * L] = in_sizes[5 + 5 * L];
        da.p[5 + 5 * L] = ew_down[L]; da.n[5 + 5 * L] = in_sizes[6 + 5 * L];
    }
    da.ei = ei; da.E = E; da.flags = flags;
    k_detect<<<17, TB, 0, stream>>>(da);

    if (fast) {
        // ---- bucketed CSR build (once; reused 3 layers x 2 directions)
        hipMemsetAsync(bc, 0, 2 * NBMAX * sizeof(int), stream);
        kb_count<<<chunkG, TB, 0, stream>>>(ei, E, flags, NB, bc);
        kb_scan<<<1, 512, 0, stream>>>(bc, bb, gcur, NB);
        kb_fill<<<chunkG, TB, 0, stream>>>(ei, E, flags, NB, gcur, bdst, bse);
        kb_csr<<<dim3((unsigned)NB, 2), TB, 0, stream>>>(bb, bdst, bse, E, NB, N,
                                                         off_c, off_r, list_c, list_r);

        // ---- layer 1 (din=DIN, generic, bf16 S output)
        k_linear_b16<<<linG1, TB, 0, stream>>>(d_in[0], 0, DIN, HID, N,
                                               w_up[0], w_down[0], w_bias[0], 1, flags, lds1,
                                               Su, Sd, Sb);
        k_ewcast<<<edgeG, TB, 0, stream>>>(ew_up[0], ew_down[0], 4, 5, flags, E, ebu, ebd);
        k_gather_fin<<<finG, TB, 0, stream>>>(off_c, list_c, off_r, list_r, ebu, ebd,
                                              Su, Sd, Sb, HID, N, H);
        // ---- layer 2 (din=96 specialized)
        if (use96_2)
            k_lin96<<<lin96G, TB, 0, stream>>>(H, N, w_up[1], w_down[1], w_bias[1], 6, flags,
                                               Su, Sd, Sb);
        else
            k_linear_b16<<<linG1, TB, 0, stream>>>(H, -1, 3 * HID, HID, N,
                                                   w_up[1], w_down[1], w_bias[1], 6, flags, lds12,
                                                   Su, Sd, Sb);
        k_ewcast<<<edgeG, TB, 0, stream>>>(ew_up[1], ew_down[1], 9, 10, flags, E, ebu, ebd);
        k_gather_fin<<<finG, TB, 0, stream>>>(off_c, list_c, off_r, list_r, ebu, ebd,
                                              Su, Sd, Sb, HID, N, H);
        // ---- layer 3 -> fp32 output
        if (use96_3)
            k_lin96<<<lin96G, TB, 0, stream>>>(H, N, w_up[2], w_down[2], w_bias[2], 11, flags,
                                               Su, Sd, Sb);
        else
            k_linear_b16<<<linG3, TB, 0, stream>>>(H, -1, 3 * HID, EMB, N,
                                                   w_up[2], w_down[2], w_bias[2], 11, flags, lds3,
                                                   Su, Sd, Sb);
        k_ewcast<<<edgeG, TB, 0, stream>>>(ew_up[2], ew_down[2], 14, 15, flags, E, ebu, ebd);
        k_gather_fin<<<finG, TB, 0, stream>>>(off_c, list_c, off_r, list_r, ebu, ebd,
                                              Su, Sd, Sb, EMB, N, out_h);
    } else {
        // ---- fallback: round-4 proven atomic-scatter path
        float* degci = (float*)(flags + 64);
        float* degri = degci + N;
        float* fA = degri + N;
        float* fB = fA + N * Fm;
        float* fC = fB + N * Fm;
        float* fU = fC + N * Fm;
        float* fD = fU + N * Fm;
        float* fH = fD + N * Fm;
        dim3 scatG12((unsigned)((E * 2 * HID + TB - 1) / TB));
        dim3 scatG3((unsigned)((E * 2 * EMB + TB - 1) / TB));

        hipMemsetAsync(degci, 0, 2 * N * sizeof(float), stream);
        k_deg<<<edgeG, TB, 0, stream>>>(ei, E, flags, degci, degri);
        k_inv<<<dim3((unsigned)((2 * N + TB - 1) / TB)), TB, 0, stream>>>(degci, 2 * N);

        k_linear<<<linG1, TB, 0, stream>>>(d_in[0], 0, DIN, HID, HID, N,
                                           w_up[0], w_down[0], w_bias[0], 1, flags, lds1, fA, fB, fC);
        hipMemsetAsync(fU, 0, 2l * N * Fm * sizeof(float), stream);
        k_scatter<<<scatG12, TB, 0, stream>>>(ei, E, HID, ew_up[0], ew_down[0], 4, 5, flags,
                                              degci, degri, fA, fB, fU, fD);
        k_finalize<<<finG, TB, 0, stream>>>(fU, fD, fC, HID, N, fH);

        k_linear<<<linG1, TB, 0, stream>>>(fH, -1, 3 * HID, HID, HID, N,
                                           w_up[1], w_down[1], w_bias[1], 6, flags, lds12, fA, fB, fC);
        hipMemsetAsync(fU, 0, 2l * N * Fm * sizeof(float), stream);
        k_scatter<<<scatG12, TB, 0, stream>>>(ei, E, HID, ew_up[1], ew_down[1], 9, 10, flags,
                                              degci, degri, fA, fB, fU, fD);
        k_finalize<<<finG, TB, 0, stream>>>(fU, fD, fC, HID, N, fH);

        k_linear<<<linG3, TB, 0, stream>>>(fH, -1, 3 * HID, EMB, EMB, N,
                                           w_up[2], w_down[2], w_bias[2], 11, flags, lds3, fA, fB, fC);
        hipMemsetAsync(fU, 0, 2l * N * Fm * sizeof(float), stream);
        k_scatter<<<scatG3, TB, 0, stream>>>(ei, E, EMB, ew_up[2], ew_down[2], 14, 15, flags,
                                             degci, degri, fA, fB, fU, fD);
        k_finalize<<<finG, TB, 0, stream>>>(fU, fD, fC, EMB, N, out_h);
    }

    // ---- edge-weight means
    k_mean<<<edgeG, TB, 0, stream>>>(ew_up[0], ew_up[1], ew_up[2],
                                     ew_down[0], ew_down[1], ew_down[2],
                                     flags, E, out_mu, out_md);
}

// Round 9
// 714.795 us; speedup vs baseline: 2.8044x; 1.0883x over previous
//
#include <hip/hip_runtime.h>
#include <hip/hip_bf16.h>
#include <math.h>

typedef __hip_bfloat16 bf16;
typedef unsigned short ushort_t;

#define NBMAX 1024   // max buckets (N <= 262144 for fast path)
#define BSH 8        // 256 nodes per bucket

// flags[0..15]: 1 if float-array slot is bf16, 0 if fp32.
//   slot 0:x | per layer L(0..2): 1+5L:w_up 2+5L:w_down 3+5L:w_bias 4+5L:ew_up 5+5L:ew_down
// flags[16]: 1 if edge_index is int64 (little-endian, values < 2^31), else int32.
__device__ __forceinline__ float ldf(const void* p, long i, int isbf) {
    return isbf ? __bfloat162float(((const bf16*)p)[i]) : ((const float*)p)[i];
}
__device__ __forceinline__ int lde(const int* ei, int half, long e, long E, int is64) {
    long idx = half ? (E + e) : e;
    return is64 ? ei[idx * 2] : ei[idx];
}
__device__ __forceinline__ float u2f(ushort_t u) {
    union { unsigned int i; float f; } v; v.i = ((unsigned)u) << 16; return v.f;
}
__device__ __forceinline__ ushort_t f2u(float f) {
    bf16 h = __float2bfloat16(f);
    return *reinterpret_cast<ushort_t*>(&h);
}
__device__ __forceinline__ float lo2f(unsigned sp) {
    union { unsigned i; float f; } v; v.i = sp << 16; return v.f;
}
__device__ __forceinline__ float hi2f(unsigned sp) {
    union { unsigned i; float f; } v; v.i = sp & 0xffff0000u; return v.f;
}

// ---------------------------------------------------------------- dtype detection
struct DetectArgs {
    const void* p[16];
    long n[16];
    const int* ei;
    long E;
    int* flags;
};

__global__ void k_detect(DetectArgs a) {
    __shared__ int cnt;
    if (threadIdx.x == 0) cnt = 0;
    __syncthreads();
    int b = blockIdx.x;
    int bad = 0;
    if (b < 16) {
        const bf16* p = (const bf16*)a.p[b];
        long m = a.n[b] < 4096 ? a.n[b] : 4096;
        for (long i = threadIdx.x; i < m; i += 256) {
            float v = __bfloat162float(p[i]);
            if (!(fabsf(v) < 100.0f)) bad++;
        }
        atomicAdd(&cnt, bad);
        __syncthreads();
        if (threadIdx.x == 0) a.flags[b] = ((long)cnt * 16 < m) ? 1 : 0;
    } else {
        long m = a.E / 2 < 4096 ? a.E / 2 : 4096;
        for (long i = threadIdx.x; i < m; i += 256) {
            if (a.ei[2 * i + 1] != 0) bad++;
        }
        atomicAdd(&cnt, bad);
        __syncthreads();
        if (threadIdx.x == 0) a.flags[16] = (cnt < (int)(m / 16) + 1) ? 1 : 0;
    }
}

// ================================================================ bucketed CSR build
// dir 0: dst=col (up-list), dir 1: dst=row (down-list). bucket = dst>>8.

__global__ void kb_count(const int* __restrict__ ei, long E, const int* __restrict__ flags,
                         int NB, int* __restrict__ bc) {
    __shared__ int h[NBMAX];
    for (int i = threadIdx.x; i < NB; i += 256) h[i] = 0;
    __syncthreads();
    int dir = blockIdx.y;
    int is64 = flags[16];
    long base = (long)blockIdx.x * 2048;
#pragma unroll
    for (int i = 0; i < 8; i++) {
        long e = base + i * 256 + threadIdx.x;
        if (e < E) {
            int d = lde(ei, dir ? 0 : 1, e, E, is64);
            atomicAdd(&h[d >> BSH], 1);
        }
    }
    __syncthreads();
    for (int i = threadIdx.x; i < NB; i += 256)
        if (h[i]) atomicAdd(&bc[dir * NBMAX + i], h[i]);
}

__global__ void kb_scan(const int* __restrict__ bc, int* __restrict__ bb,
                        int* __restrict__ gcur, int NB) {
    if (threadIdx.x < 2) {
        int dir = threadIdx.x;
        int acc = 0;
        for (int i = 0; i < NB; i++) { bb[dir * (NBMAX + 1) + i] = acc; acc += bc[dir * NBMAX + i]; }
        bb[dir * (NBMAX + 1) + NB] = acc;
    }
    __syncthreads();
    for (int i = threadIdx.x; i < 2 * NBMAX; i += blockDim.x) {
        int d = i / NBMAX, b = i - d * NBMAX;
        gcur[i] = bb[d * (NBMAX + 1) + (b < NB ? b : NB)];
    }
}

// Per-block counting-sort of a 2048-edge chunk by bucket, then bucket-contiguous
// global append.
__global__ void kb_fill(const int* __restrict__ ei, long E, const int* __restrict__ flags,
                        int NB, int* __restrict__ gcur,
                        int* __restrict__ bdst, int2* __restrict__ bse) {
    __shared__ int sdst[2048], ssrc[2048], seid[2048];
    __shared__ int h[NBMAX], lofs[NBMAX], cur[NBMAX], gb[NBMAX];
    __shared__ int sc[256];
    int tid = threadIdx.x;
    int dir = blockIdx.y;
    int is64 = flags[16];
    for (int i = tid; i < NBMAX; i += 256) { h[i] = 0; cur[i] = 0; }
    __syncthreads();
    long base = (long)blockIdx.x * 2048;
    int myd[8], mys[8], mye[8];
#pragma unroll
    for (int i = 0; i < 8; i++) {
        long e = base + i * 256 + tid;
        myd[i] = -1;
        if (e < E) {
            myd[i] = lde(ei, dir ? 0 : 1, e, E, is64);
            mys[i] = lde(ei, dir ? 1 : 0, e, E, is64);
            mye[i] = (int)e;
            atomicAdd(&h[myd[i] >> BSH], 1);
        }
    }
    __syncthreads();
    int i0 = tid * 4;
    int a0 = h[i0], a1 = h[i0 + 1], a2 = h[i0 + 2], a3 = h[i0 + 3];
    int ts = a0 + a1 + a2 + a3;
    sc[tid] = ts;
    __syncthreads();
    for (int d = 1; d < 256; d <<= 1) {
        int t = (tid >= d) ? sc[tid - d] : 0;
        __syncthreads();
        sc[tid] += t;
        __syncthreads();
    }
    int eb = sc[tid] - ts;
    lofs[i0] = eb; lofs[i0 + 1] = eb + a0; lofs[i0 + 2] = eb + a0 + a1; lofs[i0 + 3] = eb + a0 + a1 + a2;
    __syncthreads();
#pragma unroll
    for (int i = 0; i < 8; i++) {
        if (myd[i] >= 0) {
            int b = myd[i] >> BSH;
            int r = atomicAdd(&cur[b], 1);
            int p = lofs[b] + r;
            sdst[p] = myd[i]; ssrc[p] = mys[i]; seid[p] = mye[i];
        }
    }
    __syncthreads();
    for (int b = tid; b < NB; b += 256) {
        int c = h[b];
        gb[b] = c ? atomicAdd(&gcur[dir * NBMAX + b], c) : 0;
    }
    __syncthreads();
    long rem = E - base;
    int nvalid = rem >= 2048 ? 2048 : (rem > 0 ? (int)rem : 0);
    int* od = bdst + (long)dir * E;
    int2* os = bse + (long)dir * E;
    for (int s = tid; s < nvalid; s += 256) {
        int b = sdst[s] >> BSH;
        long p = (long)gb[b] + (s - lofs[b]);
        od[p] = sdst[s];
        os[p] = make_int2(ssrc[s], seid[s]);
    }
}

// Per-(bucket,dir) counting sort into final per-node CSR (L2-resident window).
__global__ void kb_csr(const int* __restrict__ bb, const int* __restrict__ bdst,
                       const int2* __restrict__ bse, long E, int NB, long N,
                       int* __restrict__ off_c, int* __restrict__ off_r,
                       int2* __restrict__ list_c, int2* __restrict__ list_r) {
    __shared__ int h[256], lofs[256], cur[256], sc[256];
    int tid = threadIdx.x;
    int b = blockIdx.x, dir = blockIdx.y;
    int base = bb[dir * (NBMAX + 1) + b];
    int cnt  = bb[dir * (NBMAX + 1) + b + 1] - base;
    const int* bd = bdst + (long)dir * E;
    const int2* bs = bse + (long)dir * E;
    int* off = dir ? off_r : off_c;
    int2* list = dir ? list_r : list_c;
    h[tid] = 0; cur[tid] = 0;
    __syncthreads();
    int nb0 = b << BSH;
    for (int s = tid; s < cnt; s += 256)
        atomicAdd(&h[bd[base + s] - nb0], 1);
    __syncthreads();
    int v = h[tid];
    sc[tid] = v;
    __syncthreads();
    for (int d = 1; d < 256; d <<= 1) {
        int t = (tid >= d) ? sc[tid - d] : 0;
        __syncthreads();
        sc[tid] += t;
        __syncthreads();
    }
    lofs[tid] = sc[tid] - v;
    __syncthreads();
    long n = (long)nb0 + tid;
    if (n < N) off[n] = base + lofs[tid];
    if (b == 0 && tid == 0) off[N] = (int)E;
    for (int s = tid; s < cnt; s += 256) {
        int local = bd[base + s] - nb0;
        int r = atomicAdd(&cur[local], 1);
        list[(long)base + lofs[local] + r] = bs[base + s];
    }
}

// ================================================================ ew: bf16 cast + CSR-order weights
__global__ void k_ewcast(const void* __restrict__ ewu, const void* __restrict__ ewd,
                         int fu, int fd, const int* __restrict__ flags, long E,
                         ushort_t* __restrict__ ebu, ushort_t* __restrict__ ebd) {
    long e = (long)blockIdx.x * blockDim.x + threadIdx.x;
    if (e >= E) return;
    ebu[e] = f2u(ldf(ewu, e, flags[fu]));
    ebd[e] = f2u(ldf(ewd, e, flags[fd]));
}

// wout[j] = ebc[list[j].eid]: random read confined to 3.2MB L2-resident table,
// sequential write. Removes all random ew reads from the hot gather.
__global__ void k_wcsr(const int2* __restrict__ list, long E,
                       const ushort_t* __restrict__ ebc, ushort_t* __restrict__ wout) {
    long j = (long)blockIdx.x * blockDim.x + threadIdx.x;
    if (j < E) wout[j] = ebc[list[j].y];
}

// ================================================================ fused gather + normalize (F==32)
// Wave per node. lane<32: up (col-CSR over Su), else down (row-CSR over Sd).
// Within a half: sub=(lane>>4)&1 picks edge parity (2 edges in flight),
// fp=lane&15 picks a feature PAIR (one packed 4B bf16x2 load per edge).
// Weights read sequentially from CSR-ordered wcu/wcd. No atomics.
__global__ void k_gather_fin32(const int* __restrict__ off_c, const int2* __restrict__ list_c,
                               const int* __restrict__ off_r, const int2* __restrict__ list_r,
                               const ushort_t* __restrict__ wcu, const ushort_t* __restrict__ wcd,
                               const ushort_t* __restrict__ Su, const ushort_t* __restrict__ Sd,
                               const ushort_t* __restrict__ Sb, long N,
                               float* __restrict__ out) {
    long t = (long)blockIdx.x * blockDim.x + threadIdx.x;
    long n = t >> 6;
    if (n >= N) return;
    int lane = (int)(t & 63);
    int up  = (lane < 32) ? 1 : 0;
    int sub = (lane >> 4) & 1;
    int fp  = lane & 15;
    const int*  off  = up ? off_c : off_r;
    const int2* list = up ? list_c : list_r;
    const ushort_t* wc = up ? wcu : wcd;
    const ushort_t* S  = up ? Su : Sd;
    int j0 = off[n], j1 = off[n + 1];
    float ax = 0.f, ay = 0.f;
    int j = j0 + sub;
    for (; j + 2 < j1; j += 4) {          // this lane: edges j and j+2
        int s0 = list[j].x, s1 = list[j + 2].x;
        float w0 = u2f(wc[j]), w1 = u2f(wc[j + 2]);
        unsigned p0 = *(const unsigned*)&S[((long)s0 << 5) + (fp << 1)];
        unsigned p1 = *(const unsigned*)&S[((long)s1 << 5) + (fp << 1)];
        ax += w0 * lo2f(p0) + w1 * lo2f(p1);
        ay += w0 * hi2f(p0) + w1 * hi2f(p1);
    }
    if (j < j1) {
        int s0 = list[j].x;
        float w0 = u2f(wc[j]);
        unsigned p0 = *(const unsigned*)&S[((long)s0 << 5) + (fp << 1)];
        ax += w0 * lo2f(p0);
        ay += w0 * hi2f(p0);
    }
    ax += __shfl_xor(ax, 16, 64);         // combine edge parities
    ay += __shfl_xor(ay, 16, 64);
    int deg = j1 - j0;
    float dinv = (deg > 0) ? 1.0f / (float)deg : 0.f;
    float vx = ax * dinv, vy = ay * dinv;
    float cx = 0.f, cy = 0.f;
    if (up) {
        unsigned bp = *(const unsigned*)&Sb[(n << 5) + (fp << 1)];
        cx = lo2f(bp); cy = hi2f(bp);
    }
    float ss = (sub == 0) ? (vx * vx + vy * vy + cx * cx + cy * cy) : 0.f;
#pragma unroll
    for (int m = 1; m < 64; m <<= 1) ss += __shfl_xor(ss, m, 64);
    float inv = 1.0f / fmaxf(sqrtf(ss), 1e-12f);
    if (sub == 0) {
        float a = vx * inv; a = (a >= 0.f) ? a : 0.1f * a;
        float b = vy * inv; b = (b >= 0.f) ? b : 0.1f * b;
        *(float2*)&out[n * 96 + (up ? 0 : 32) + (fp << 1)] = make_float2(a, b);
        if (up) {
            float p = cx * inv; p = (p >= 0.f) ? p : 0.1f * p;
            float q = cy * inv; q = (q >= 0.f) ? q : 0.1f * q;
            *(float2*)&out[n * 96 + 64 + (fp << 1)] = make_float2(p, q);
        }
    }
}

// ================================================================ specialized linear, din=96, dout=3x32 fused, bf16 out
__global__ void k_lin96(const float* __restrict__ xin, long N,
                        const void* __restrict__ wu, const void* __restrict__ wd,
                        const void* __restrict__ wb, int wfi,
                        const int* __restrict__ flags,
                        ushort_t* __restrict__ Su, ushort_t* __restrict__ Sd,
                        ushort_t* __restrict__ Sb) {
    __shared__ float xs[32 * 100];   // 12.8 KB (reused as bf16 staging after compute)
    __shared__ float wt[96 * 96];    // 36.9 KB
    int tid = threadIdx.x;
    int ubf = flags[wfi], dbf = flags[wfi + 1], bbf = flags[wfi + 2];
    for (int j = tid; j < 96 * 96; j += 256) {
        int o3 = j % 96, i = j / 96;
        float v;
        if (o3 < 32)      v = ldf(wu, (long)o3 * 96 + i, ubf);
        else if (o3 < 64) v = ldf(wd, (long)(o3 - 32) * 96 + i, dbf);
        else              v = ldf(wb, (long)(o3 - 64) * 96 + i, bbf);
        wt[j] = v;
    }
    long nb = (long)blockIdx.x * 32;
    for (int j = tid; j < 32 * 24; j += 256) {
        int node = j / 24, c = j % 24;
        long gn = nb + node;
        float4 v = make_float4(0.f, 0.f, 0.f, 0.f);
        if (gn < N) v = ((const float4*)(xin + gn * 96))[c];
        *(float4*)&xs[node * 100 + c * 4] = v;
    }
    __syncthreads();
    int node = tid >> 3;
    int o0 = (tid & 7) * 12;
    float acc[12];
#pragma unroll
    for (int s = 0; s < 12; s++) acc[s] = 0.f;
    const float* xrow = &xs[node * 100];
#pragma unroll 4
    for (int c = 0; c < 24; c++) {
        float4 xv = *(const float4*)&xrow[c * 4];
        const float* w0 = &wt[(c * 4) * 96 + o0];
#pragma unroll
        for (int k = 0; k < 4; k++) {
            float xk = (k == 0) ? xv.x : (k == 1) ? xv.y : (k == 2) ? xv.z : xv.w;
            const float* wr = w0 + k * 96;
            float4 wa = *(const float4*)(wr);
            float4 wb4 = *(const float4*)(wr + 4);
            float4 wc = *(const float4*)(wr + 8);
            acc[0] += xk * wa.x;  acc[1] += xk * wa.y;  acc[2]  += xk * wa.z;  acc[3]  += xk * wa.w;
            acc[4] += xk * wb4.x; acc[5] += xk * wb4.y; acc[6]  += xk * wb4.z; acc[7]  += xk * wb4.w;
            acc[8] += xk * wc.x;  acc[9] += xk * wc.y;  acc[10] += xk * wc.z;  acc[11] += xk * wc.w;
        }
    }
    __syncthreads();
    ushort_t* sbuf = (ushort_t*)xs;
#pragma unroll
    for (int s = 0; s < 12; s++) sbuf[node * 96 + o0 + s] = f2u(acc[s]);
    __syncthreads();
    for (int j = tid; j < 32 * 96; j += 256) {
        int nd = j / 96, o3 = j % 96;
        long gn = nb + nd;
        if (gn < N) {
            int blk = o3 >> 5, fo = o3 & 31;
            ushort_t v = sbuf[j];
            (blk == 0 ? Su : blk == 1 ? Sd : Sb)[gn * 32 + fo] = v;
        }
    }
}

// ================================================================ generic linear -> bf16 S arrays (layer 1)
__global__ void k_linear_b16(const void* __restrict__ xin, int xfi, int din, int dout, long N,
                             const void* __restrict__ wu, const void* __restrict__ wd,
                             const void* __restrict__ wb, int wfi,
                             const int* __restrict__ flags, int uselds,
                             ushort_t* __restrict__ Su, ushort_t* __restrict__ Sd,
                             ushort_t* __restrict__ Sb) {
    __shared__ float smem[12288];
    int xbf = (xfi >= 0) ? flags[xfi] : 0;
    int ubf = flags[wfi], dbf = flags[wfi + 1], bbf = flags[wfi + 2];
    float* su = smem;
    float* sd = smem + (long)din * dout;
    float* sb = smem + 2l * din * dout;
    if (uselds) {
        for (int j = threadIdx.x; j < din * dout; j += 256) {
            int o = j % dout, i = j / dout;
            su[j] = ldf(wu, (long)o * din + i, ubf);
            sd[j] = ldf(wd, (long)o * din + i, dbf);
            sb[j] = ldf(wb, (long)o * din + i, bbf);
        }
        __syncthreads();
    }
    long idx = (long)blockIdx.x * blockDim.x + threadIdx.x;
    long node = idx / dout;
    int o = (int)(idx % dout);
    if (node >= N) return;
    float au = 0.f, ad = 0.f, ab = 0.f;
    long xb = node * din;
    if (uselds) {
        for (int i = 0; i < din; i++) {
            float xv = ldf(xin, xb + i, xbf);
            au += xv * su[i * dout + o];
            ad += xv * sd[i * dout + o];
            ab += xv * sb[i * dout + o];
        }
    } else {
        for (int i = 0; i < din; i++) {
            float xv = ldf(xin, xb + i, xbf);
            au += xv * ldf(wu, (long)o * din + i, ubf);
            ad += xv * ldf(wd, (long)o * din + i, dbf);
            ab += xv * ldf(wb, (long)o * din + i, bbf);
        }
    }
    Su[node * dout + o] = f2u(au);
    Sd[node * dout + o] = f2u(ad);
    Sb[node * dout + o] = f2u(ab);
}

// ================================================================ fallback (round-4 proven) kernels
__global__ void k_linear(const void* __restrict__ xin, int xfi, int din, int dout, int rs, long N,
                         const void* __restrict__ wu, const void* __restrict__ wd,
                         const void* __restrict__ wb, int wfi,
                         const int* __restrict__ flags, int uselds,
                         float* __restrict__ A, float* __restrict__ B, float* __restrict__ C) {
    __shared__ float smem[12288];
    int xbf = (xfi >= 0) ? flags[xfi] : 0;
    int ubf = flags[wfi], dbf = flags[wfi + 1], bbf = flags[wfi + 2];
    float* su = smem;
    float* sd = smem + (long)din * dout;
    float* sb = smem + 2l * din * dout;
    if (uselds) {
        for (int j = threadIdx.x; j < din * dout; j += 256) {
            int o = j % dout, i = j / dout;
            su[j] = ldf(wu, (long)o * din + i, ubf);
            sd[j] = ldf(wd, (long)o * din + i, dbf);
            sb[j] = ldf(wb, (long)o * din + i, bbf);
        }
        __syncthreads();
    }
    long idx = (long)blockIdx.x * blockDim.x + threadIdx.x;
    long node = idx / dout;
    int o = (int)(idx % dout);
    if (node >= N) return;
    float au = 0.f, ad = 0.f, ab = 0.f;
    long xb = node * din;
    if (uselds) {
        for (int i = 0; i < din; i++) {
            float xv = ldf(xin, xb + i, xbf);
            au += xv * su[i * dout + o];
            ad += xv * sd[i * dout + o];
            ab += xv * sb[i * dout + o];
        }
    } else {
        for (int i = 0; i < din; i++) {
            float xv = ldf(xin, xb + i, xbf);
            au += xv * ldf(wu, (long)o * din + i, ubf);
            ad += xv * ldf(wd, (long)o * din + i, dbf);
            ab += xv * ldf(wb, (long)o * din + i, bbf);
        }
    }
    A[node * rs + o] = au;
    B[node * rs + o] = ad;
    C[node * rs + o] = ab;
}

__global__ void k_deg(const int* __restrict__ ei, long E, const int* __restrict__ flags,
                      float* __restrict__ degc, float* __restrict__ degr) {
    long e = (long)blockIdx.x * blockDim.x + threadIdx.x;
    if (e < E) {
        int is64 = flags[16];
        atomicAdd(&degc[lde(ei, 1, e, E, is64)], 1.0f);
        atomicAdd(&degr[lde(ei, 0, e, E, is64)], 1.0f);
    }
}

__global__ void k_inv(float* __restrict__ a, long n) {
    long i = (long)blockIdx.x * blockDim.x + threadIdx.x;
    if (i < n) { float v = a[i]; a[i] = (v > 0.0f) ? 1.0f / v : 0.0f; }
}

__global__ void k_scatter(const int* __restrict__ ei, long E, int F,
                          const void* __restrict__ ewu, const void* __restrict__ ewd,
                          int fu, int fd, const int* __restrict__ flags,
                          const float* __restrict__ degci, const float* __restrict__ degri,
                          const float* __restrict__ A, const float* __restrict__ B,
                          float* __restrict__ U, float* __restrict__ D) {
    long idx = (long)blockIdx.x * blockDim.x + threadIdx.x;
    long tot = E * 2 * F;
    if (idx >= tot) return;
    int is64 = flags[16];
    long e = idx / (2 * F);
    int rem = (int)(idx - e * 2 * F);
    int dir = rem >= F;
    int f = rem - dir * F;
    int r = lde(ei, 0, e, E, is64), c = lde(ei, 1, e, E, is64);
    if (!dir) {
        float w = degci[c] * ldf(ewu, e, flags[fu]);
        atomicAdd(&U[(long)c * F + f], w * A[(long)r * F + f]);
    } else {
        float w = degri[r] * ldf(ewd, e, flags[fd]);
        atomicAdd(&D[(long)r * F + f], w * B[(long)c * F + f]);
    }
}

__global__ void k_finalize(const float* __restrict__ U, const float* __restrict__ D,
                           const float* __restrict__ C, int F, long N,
                           float* __restrict__ out) {
    long t = (long)blockIdx.x * blockDim.x + threadIdx.x;
    long n = t >> 6;
    if (n >= N) return;
    int lane = (int)(t & 63);
    int cat = 3 * F;
    float ss = 0.f;
    for (int j = lane; j < cat; j += 64) {
        float v = (j < F) ? U[n * F + j] : (j < 2 * F) ? D[n * F + j - F] : C[n * F + j - 2 * F];
        ss += v * v;
    }
#pragma unroll
    for (int m = 1; m < 64; m <<= 1) ss += __shfl_xor(ss, m, 64);
    float inv = 1.0f / fmaxf(sqrtf(ss), 1e-12f);
    for (int j = lane; j < cat; j += 64) {
        float v = (j < F) ? U[n * F + j] : (j < 2 * F) ? D[n * F + j - F] : C[n * F + j - 2 * F];
        float a = v * inv;
        a = (a >= 0.0f) ? a : 0.1f * a;
        out[n * cat + j] = a;
    }
}

// ---------------------------------------------------------------- edge-weight means (fp32 out)
__global__ void k_mean(const void* e1u, const void* e2u, const void* e3u,
                       const void* e1d, const void* e2d, const void* e3d,
                       const int* __restrict__ flags, long E,
                       float* __restrict__ mu, float* __restrict__ md) {
    long e = (long)blockIdx.x * blockDim.x + threadIdx.x;
    if (e >= E) return;
    float su = ldf(e1u, e, flags[4]) + ldf(e2u, e, flags[9]) + ldf(e3u, e, flags[14]);
    float sd = ldf(e1d, e, flags[5]) + ldf(e2d, e, flags[10]) + ldf(e3d, e, flags[15]);
    mu[e] = su / 3.0f;
    md[e] = sd / 3.0f;
}

extern "C" void kernel_launch(void* const* d_in, const int* in_sizes, int n_in,
                              void* d_out, int out_size, void* d_ws, size_t ws_size,
                              hipStream_t stream) {
    const int* ei = (const int*)d_in[1];
    const void* w_up[3]   = {d_in[2], d_in[7],  d_in[12]};
    const void* w_down[3] = {d_in[3], d_in[8],  d_in[13]};
    const void* w_bias[3] = {d_in[4], d_in[9],  d_in[14]};
    const void* ew_up[3]  = {d_in[5], d_in[10], d_in[15]};
    const void* ew_down[3]= {d_in[6], d_in[11], d_in[16]};

    // ---- derive true sizes from in_sizes
    long E = in_sizes[5];
    if (E <= 0) E = 1600000;
    int HID = (int)(sqrt((double)in_sizes[7] / 3.0) + 0.5);
    if (HID <= 0 || (long)3 * HID * HID != (long)in_sizes[7]) HID = 32;
    int DIN = in_sizes[2] / HID;
    if (DIN <= 0) DIN = 8;
    long N = (long)in_sizes[0] / DIN;
    if (N <= 0) N = 50000;
    int EMB = in_sizes[12] / (3 * HID);
    if (EMB <= 0) EMB = 32;
    int Fm = HID > EMB ? HID : EMB;
    int NB = (int)((N + 255) >> BSH);

    // ---- outputs: fp32, concatenated (h, mean_up, mean_down)
    float* out_h  = (float*)d_out;
    float* out_mu = out_h + N * 3l * EMB;
    float* out_md = out_mu + E;

    const int TB = 256;
    int lds1  = (3l * DIN * HID <= 12288) ? 1 : 0;
    int lds12 = (3l * (3 * HID) * HID <= 12288) ? 1 : 0;
    int lds3  = (3l * (3 * HID) * EMB <= 12288) ? 1 : 0;
    dim3 linG1((unsigned)((N * HID + TB - 1) / TB));
    dim3 linG3((unsigned)((N * EMB + TB - 1) / TB));
    dim3 lin96G((unsigned)((N + 31) / 32));
    dim3 finG((unsigned)((N * 64 + TB - 1) / TB));
    dim3 edgeG((unsigned)((E + TB - 1) / TB));
    dim3 chunkG((unsigned)((E + 2047) / 2048), 2);

    // ---- fast-path workspace layout
    int* flags = (int*)d_ws;                       // 64
    int* bc    = flags + 64;                       // 2*NBMAX
    int* bb    = bc + 2 * NBMAX;                   // 2*(NBMAX+1)
    int* gcur  = bb + 2 * (NBMAX + 1);             // 2*NBMAX
    int* off_c = gcur + 2 * NBMAX;                 // N+1
    int* off_r = off_c + (N + 1);                  // N+1
    long li = (long)(off_r + (N + 1) - (int*)d_ws);
    li = (li + 3) & ~3l;                           // 16B-align lists
    int2* list_c = (int2*)((int*)d_ws + li);       // E (src,eid)
    int2* list_r = list_c + E;                     // E
    int* R = (int*)(list_r + E);
    // phase 1 (bucket build):
    int* bdst = R;                                 // 2E ints (dir-major)
    int2* bse = (int2*)(R + 2 * E);                // 2E int2
    // phase 2+3 overlay:
    ushort_t* wc6 = (ushort_t*)R;                  // 6*E bf16 CSR-ordered weights [l*2+dir]
    ushort_t* ebc = (ushort_t*)(R + 3 * E);        // 2*E bf16 transient cast (per layer)
    ushort_t* Su  = (ushort_t*)(R + 3 * E);        // N*Fm bf16 (overlays ebc after wcsr)
    ushort_t* Sd  = Su + N * Fm;
    ushort_t* Sb  = Sd + N * Fm;
    // H lives in d_out (fully rewritten each layer)
    long sInts = (3l * N * Fm + 1) / 2;
    long zInts = (E > sInts) ? E : sInts;          // ebc vs S arrays
    long Rints = 6l * E;                           // bucket phase
    if (3l * E + zInts > Rints) Rints = 3l * E + zInts;
    size_t need = (size_t)((li + 4l * E + Rints) * 4l + 256);

    bool fast = (HID == 32 && EMB == 32) && (NB <= NBMAX) &&
                (ws_size == 0 || ws_size >= need);

    // ---- dtype detection (both paths)
    DetectArgs da;
    da.p[0] = d_in[0]; da.n[0] = in_sizes[0];
    for (int L = 0; L < 3; L++) {
        da.p[1 + 5 * L] = w_up[L];    da.n[1 + 5 * L] = in_sizes[2 + 5 * L];
        da.p[2 + 5 * L] = w_down[L];  da.n[2 + 5 * L] = in_sizes[3 + 5 * L];
        da.p[3 + 5 * L] = w_bias[L];  da.n[3 + 5 * L] = in_sizes[4 + 5 * L];
        da.p[4 + 5 * L] = ew_up[L];   da.n[4 + 5 * L] = in_sizes[5 + 5 * L];
        da.p[5 + 5 * L] = ew_down[L]; da.n[5 + 5 * L] = in_sizes[6 + 5 * L];
    }
    da.ei = ei; da.E = E; da.flags = flags;
    k_detect<<<17, TB, 0, stream>>>(da);

    if (fast) {
        // ---- bucketed CSR build (once; reused 3 layers x 2 directions)
        hipMemsetAsync(bc, 0, 2 * NBMAX * sizeof(int), stream);
        kb_count<<<chunkG, TB, 0, stream>>>(ei, E, flags, NB, bc);
        kb_scan<<<1, 512, 0, stream>>>(bc, bb, gcur, NB);
        kb_fill<<<chunkG, TB, 0, stream>>>(ei, E, flags, NB, gcur, bdst, bse);
        kb_csr<<<dim3((unsigned)NB, 2), TB, 0, stream>>>(bb, bdst, bse, E, NB, N,
                                                         off_c, off_r, list_c, list_r);

        // ---- CSR-ordered bf16 weights, all 3 layers (bucket scratch now dead)
        for (int L = 0; L < 3; L++) {
            k_ewcast<<<edgeG, TB, 0, stream>>>(ew_up[L], ew_down[L], 4 + 5 * L, 5 + 5 * L,
                                               flags, E, ebc, ebc + E);
            k_wcsr<<<edgeG, TB, 0, stream>>>(list_c, E, ebc,     wc6 + (long)(2 * L) * E);
            k_wcsr<<<edgeG, TB, 0, stream>>>(list_r, E, ebc + E, wc6 + (long)(2 * L + 1) * E);
        }

        float* H = (float*)d_out;   // intermediate 96-wide activations live in d_out

        // ---- layer 1 (din=DIN, generic, bf16 S output)
        k_linear_b16<<<linG1, TB, 0, stream>>>(d_in[0], 0, DIN, HID, N,
                                               w_up[0], w_down[0], w_bias[0], 1, flags, lds1,
                                               Su, Sd, Sb);
        k_gather_fin32<<<finG, TB, 0, stream>>>(off_c, list_c, off_r, list_r,
                                                wc6, wc6 + E, Su, Sd, Sb, N, H);
        // ---- layer 2 (din=96 specialized)
        k_lin96<<<lin96G, TB, 0, stream>>>(H, N, w_up[1], w_down[1], w_bias[1], 6, flags,
                                           Su, Sd, Sb);
        k_gather_fin32<<<finG, TB, 0, stream>>>(off_c, list_c, off_r, list_r,
                                                wc6 + 2l * E, wc6 + 3l * E, Su, Sd, Sb, N, H);
        // ---- layer 3 -> final fp32 output
        k_lin96<<<lin96G, TB, 0, stream>>>(H, N, w_up[2], w_down[2], w_bias[2], 11, flags,
                                           Su, Sd, Sb);
        k_gather_fin32<<<finG, TB, 0, stream>>>(off_c, list_c, off_r, list_r,
                                                wc6 + 4l * E, wc6 + 5l * E, Su, Sd, Sb, N, out_h);
    } else {
        // ---- fallback: round-4 proven atomic-scatter path
        float* degci = (float*)(flags + 64);
        float* degri = degci + N;
        float* fA = degri + N;
        float* fB = fA + N * Fm;
        float* fC = fB + N * Fm;
        float* fU = fC + N * Fm;
        float* fD = fU + N * Fm;
        float* fH = fD + N * Fm;
        dim3 scatG12((unsigned)((E * 2 * HID + TB - 1) / TB));
        dim3 scatG3((unsigned)((E * 2 * EMB + TB - 1) / TB));

        hipMemsetAsync(degci, 0, 2 * N * sizeof(float), stream);
        k_deg<<<edgeG, TB, 0, stream>>>(ei, E, flags, degci, degri);
        k_inv<<<dim3((unsigned)((2 * N + TB - 1) / TB)), TB, 0, stream>>>(degci, 2 * N);

        k_linear<<<linG1, TB, 0, stream>>>(d_in[0], 0, DIN, HID, HID, N,
                                           w_up[0], w_down[0], w_bias[0], 1, flags, lds1, fA, fB, fC);
        hipMemsetAsync(fU, 0, 2l * N * Fm * sizeof(float), stream);
        k_scatter<<<scatG12, TB, 0, stream>>>(ei, E, HID, ew_up[0], ew_down[0], 4, 5, flags,
                                              degci, degri, fA, fB, fU, fD);
        k_finalize<<<finG, TB, 0, stream>>>(fU, fD, fC, HID, N, fH);

        k_linear<<<linG1, TB, 0, stream>>>(fH, -1, 3 * HID, HID, HID, N,
                                           w_up[1], w_down[1], w_bias[1], 6, flags, lds12, fA, fB, fC);
        hipMemsetAsync(fU, 0, 2l * N * Fm * sizeof(float), stream);
        k_scatter<<<scatG12, TB, 0, stream>>>(ei, E, HID, ew_up[1], ew_down[1], 9, 10, flags,
                                              degci, degri, fA, fB, fU, fD);
        k_finalize<<<finG, TB, 0, stream>>>(fU, fD, fC, HID, N, fH);

        k_linear<<<linG3, TB, 0, stream>>>(fH, -1, 3 * HID, EMB, EMB, N,
                                           w_up[2], w_down[2], w_bias[2], 11, flags, lds3, fA, fB, fC);
        hipMemsetAsync(fU, 0, 2l * N * Fm * sizeof(float), stream);
        k_scatter<<<scatG3, TB, 0, stream>>>(ei, E, EMB, ew_up[2], ew_down[2], 14, 15, flags,
                                             degci, degri, fA, fB, fU, fD);
        k_finalize<<<finG, TB, 0, stream>>>(fU, fD, fC, EMB, N, out_h);
    }

    // ---- edge-weight means
    k_mean<<<edgeG, TB, 0, stream>>>(ew_up[0], ew_up[1], ew_up[2],
                                     ew_down[0], ew_down[1], ew_down[2],
                                     flags, E, out_mu, out_md);
}

// Round 10
// 698.058 us; speedup vs baseline: 2.8717x; 1.0240x over previous
//
#include <hip/hip_runtime.h>
#include <hip/hip_bf16.h>
#include <math.h>

typedef __hip_bfloat16 bf16;
typedef unsigned short ushort_t;

#define NBMAX 1024   // max buckets (N <= 262144 for fast path)
#define BSH 8        // 256 nodes per bucket

// flags[0..15]: 1 if float-array slot is bf16, 0 if fp32.
//   slot 0:x | per layer L(0..2): 1+5L:w_up 2+5L:w_down 3+5L:w_bias 4+5L:ew_up 5+5L:ew_down
// flags[16]: 1 if edge_index is int64 (little-endian, values < 2^31), else int32.
__device__ __forceinline__ float ldf(const void* p, long i, int isbf) {
    return isbf ? __bfloat162float(((const bf16*)p)[i]) : ((const float*)p)[i];
}
__device__ __forceinline__ int lde(const int* ei, int half, long e, long E, int is64) {
    long idx = half ? (E + e) : e;
    return is64 ? ei[idx * 2] : ei[idx];
}
__device__ __forceinline__ float u2f(ushort_t u) {
    union { unsigned int i; float f; } v; v.i = ((unsigned)u) << 16; return v.f;
}
__device__ __forceinline__ ushort_t f2u(float f) {
    bf16 h = __float2bfloat16(f);
    return *reinterpret_cast<ushort_t*>(&h);
}
__device__ __forceinline__ float lo2f(unsigned sp) {
    union { unsigned i; float f; } v; v.i = sp << 16; return v.f;
}
__device__ __forceinline__ float hi2f(unsigned sp) {
    union { unsigned i; float f; } v; v.i = sp & 0xffff0000u; return v.f;
}

// ---------------------------------------------------------------- dtype detection
struct DetectArgs {
    const void* p[16];
    long n[16];
    const int* ei;
    long E;
    int* flags;
};

__global__ void k_detect(DetectArgs a) {
    __shared__ int cnt;
    if (threadIdx.x == 0) cnt = 0;
    __syncthreads();
    int b = blockIdx.x;
    int bad = 0;
    if (b < 16) {
        const bf16* p = (const bf16*)a.p[b];
        long m = a.n[b] < 4096 ? a.n[b] : 4096;
        for (long i = threadIdx.x; i < m; i += 256) {
            float v = __bfloat162float(p[i]);
            if (!(fabsf(v) < 100.0f)) bad++;
        }
        atomicAdd(&cnt, bad);
        __syncthreads();
        if (threadIdx.x == 0) a.flags[b] = ((long)cnt * 16 < m) ? 1 : 0;
    } else {
        long m = a.E / 2 < 4096 ? a.E / 2 : 4096;
        for (long i = threadIdx.x; i < m; i += 256) {
            if (a.ei[2 * i + 1] != 0) bad++;
        }
        atomicAdd(&cnt, bad);
        __syncthreads();
        if (threadIdx.x == 0) a.flags[16] = (cnt < (int)(m / 16) + 1) ? 1 : 0;
    }
}

// ================================================================ bucketed CSR build
// dir 0: dst=col (up-list), dir 1: dst=row (down-list). bucket = dst>>8.

__global__ void kb_count(const int* __restrict__ ei, long E, const int* __restrict__ flags,
                         int NB, int* __restrict__ bc) {
    __shared__ int h[NBMAX];
    for (int i = threadIdx.x; i < NB; i += 256) h[i] = 0;
    __syncthreads();
    int dir = blockIdx.y;
    int is64 = flags[16];
    long base = (long)blockIdx.x * 2048;
#pragma unroll
    for (int i = 0; i < 8; i++) {
        long e = base + i * 256 + threadIdx.x;
        if (e < E) {
            int d = lde(ei, dir ? 0 : 1, e, E, is64);
            atomicAdd(&h[d >> BSH], 1);
        }
    }
    __syncthreads();
    for (int i = threadIdx.x; i < NB; i += 256)
        if (h[i]) atomicAdd(&bc[dir * NBMAX + i], h[i]);
}

__global__ void kb_scan(const int* __restrict__ bc, int* __restrict__ bb,
                        int* __restrict__ gcur, int NB) {
    if (threadIdx.x < 2) {
        int dir = threadIdx.x;
        int acc = 0;
        for (int i = 0; i < NB; i++) { bb[dir * (NBMAX + 1) + i] = acc; acc += bc[dir * NBMAX + i]; }
        bb[dir * (NBMAX + 1) + NB] = acc;
    }
    __syncthreads();
    for (int i = threadIdx.x; i < 2 * NBMAX; i += blockDim.x) {
        int d = i / NBMAX, b = i - d * NBMAX;
        gcur[i] = bb[d * (NBMAX + 1) + (b < NB ? b : NB)];
    }
}

// Per-block counting-sort of a 2048-edge chunk by bucket, then bucket-contiguous
// global append.
__global__ void kb_fill(const int* __restrict__ ei, long E, const int* __restrict__ flags,
                        int NB, int* __restrict__ gcur,
                        int* __restrict__ bdst, int2* __restrict__ bse) {
    __shared__ int sdst[2048], ssrc[2048], seid[2048];
    __shared__ int h[NBMAX], lofs[NBMAX], cur[NBMAX], gb[NBMAX];
    __shared__ int sc[256];
    int tid = threadIdx.x;
    int dir = blockIdx.y;
    int is64 = flags[16];
    for (int i = tid; i < NBMAX; i += 256) { h[i] = 0; cur[i] = 0; }
    __syncthreads();
    long base = (long)blockIdx.x * 2048;
    int myd[8], mys[8], mye[8];
#pragma unroll
    for (int i = 0; i < 8; i++) {
        long e = base + i * 256 + tid;
        myd[i] = -1;
        if (e < E) {
            myd[i] = lde(ei, dir ? 0 : 1, e, E, is64);
            mys[i] = lde(ei, dir ? 1 : 0, e, E, is64);
            mye[i] = (int)e;
            atomicAdd(&h[myd[i] >> BSH], 1);
        }
    }
    __syncthreads();
    int i0 = tid * 4;
    int a0 = h[i0], a1 = h[i0 + 1], a2 = h[i0 + 2], a3 = h[i0 + 3];
    int ts = a0 + a1 + a2 + a3;
    sc[tid] = ts;
    __syncthreads();
    for (int d = 1; d < 256; d <<= 1) {
        int t = (tid >= d) ? sc[tid - d] : 0;
        __syncthreads();
        sc[tid] += t;
        __syncthreads();
    }
    int eb = sc[tid] - ts;
    lofs[i0] = eb; lofs[i0 + 1] = eb + a0; lofs[i0 + 2] = eb + a0 + a1; lofs[i0 + 3] = eb + a0 + a1 + a2;
    __syncthreads();
#pragma unroll
    for (int i = 0; i < 8; i++) {
        if (myd[i] >= 0) {
            int b = myd[i] >> BSH;
            int r = atomicAdd(&cur[b], 1);
            int p = lofs[b] + r;
            sdst[p] = myd[i]; ssrc[p] = mys[i]; seid[p] = mye[i];
        }
    }
    __syncthreads();
    for (int b = tid; b < NB; b += 256) {
        int c = h[b];
        gb[b] = c ? atomicAdd(&gcur[dir * NBMAX + b], c) : 0;
    }
    __syncthreads();
    long rem = E - base;
    int nvalid = rem >= 2048 ? 2048 : (rem > 0 ? (int)rem : 0);
    int* od = bdst + (long)dir * E;
    int2* os = bse + (long)dir * E;
    for (int s = tid; s < nvalid; s += 256) {
        int b = sdst[s] >> BSH;
        long p = (long)gb[b] + (s - lofs[b]);
        od[p] = sdst[s];
        os[p] = make_int2(ssrc[s], seid[s]);
    }
}

// Per-(bucket,dir) counting sort into final per-node CSR (L2-resident window).
// Emits src-only list (gather hot path) + parallel eid array (wcsr only).
__global__ void kb_csr(const int* __restrict__ bb, const int* __restrict__ bdst,
                       const int2* __restrict__ bse, long E, int NB, long N,
                       int* __restrict__ off_c, int* __restrict__ off_r,
                       int* __restrict__ list_c, int* __restrict__ list_r,
                       int* __restrict__ eidx_c, int* __restrict__ eidx_r) {
    __shared__ int h[256], lofs[256], cur[256], sc[256];
    int tid = threadIdx.x;
    int b = blockIdx.x, dir = blockIdx.y;
    int base = bb[dir * (NBMAX + 1) + b];
    int cnt  = bb[dir * (NBMAX + 1) + b + 1] - base;
    const int* bd = bdst + (long)dir * E;
    const int2* bs = bse + (long)dir * E;
    int* off  = dir ? off_r : off_c;
    int* list = dir ? list_r : list_c;
    int* eidx = dir ? eidx_r : eidx_c;
    h[tid] = 0; cur[tid] = 0;
    __syncthreads();
    int nb0 = b << BSH;
    for (int s = tid; s < cnt; s += 256)
        atomicAdd(&h[bd[base + s] - nb0], 1);
    __syncthreads();
    int v = h[tid];
    sc[tid] = v;
    __syncthreads();
    for (int d = 1; d < 256; d <<= 1) {
        int t = (tid >= d) ? sc[tid - d] : 0;
        __syncthreads();
        sc[tid] += t;
        __syncthreads();
    }
    lofs[tid] = sc[tid] - v;
    __syncthreads();
    long n = (long)nb0 + tid;
    if (n < N) off[n] = base + lofs[tid];
    if (b == 0 && tid == 0) off[N] = (int)E;
    for (int s = tid; s < cnt; s += 256) {
        int local = bd[base + s] - nb0;
        int r = atomicAdd(&cur[local], 1);
        long p = (long)base + lofs[local] + r;
        int2 se = bs[base + s];
        list[p] = se.x;
        eidx[p] = se.y;
    }
}

// ================================================================ ew: cast all 6 arrays + means, one pass
__global__ void k_ewcast6(const void* __restrict__ e1u, const void* __restrict__ e2u,
                          const void* __restrict__ e3u, const void* __restrict__ e1d,
                          const void* __restrict__ e2d, const void* __restrict__ e3d,
                          const int* __restrict__ flags, long E,
                          ushort_t* __restrict__ ebc6,
                          float* __restrict__ mu, float* __restrict__ md) {
    long e = (long)blockIdx.x * blockDim.x + threadIdx.x;
    if (e >= E) return;
    float v1u = ldf(e1u, e, flags[4]),  v2u = ldf(e2u, e, flags[9]),  v3u = ldf(e3u, e, flags[14]);
    float v1d = ldf(e1d, e, flags[5]),  v2d = ldf(e2d, e, flags[10]), v3d = ldf(e3d, e, flags[15]);
    ebc6[0 * E + e] = f2u(v1u); ebc6[1 * E + e] = f2u(v1d);
    ebc6[2 * E + e] = f2u(v2u); ebc6[3 * E + e] = f2u(v2d);
    ebc6[4 * E + e] = f2u(v3u); ebc6[5 * E + e] = f2u(v3d);
    mu[e] = (v1u + v2u + v3u) / 3.0f;
    md[e] = (v1d + v2d + v3d) / 3.0f;
}

// wout[j] = tab[eidx[j]]: sequential eidx read, random read confined to a
// 3.2MB L2-resident table, sequential write.
__global__ void k_wcsr(const int* __restrict__ eidx, long E,
                       const ushort_t* __restrict__ tab, ushort_t* __restrict__ wout) {
    long j = (long)blockIdx.x * blockDim.x + threadIdx.x;
    if (j < E) wout[j] = tab[eidx[j]];
}

// ================================================================ phase-split gather (F==32)
// 4 edge parities per wave (sub=lane>>4), 16 feature-pair lanes (fp=lane&15).
// Each dispatch's random hot set is ONE 3.2MB bf16 table -> per-XCD L2 resident.

// Phase A: up-direction (col-CSR over Su) -> U[n][32] fp32 (deg-normalized).
__global__ void k_gather_up(const int* __restrict__ off_c, const int* __restrict__ list_c,
                            const ushort_t* __restrict__ wcu, const ushort_t* __restrict__ Su,
                            long N, float* __restrict__ U) {
    long t = (long)blockIdx.x * blockDim.x + threadIdx.x;
    long n = t >> 6;
    if (n >= N) return;
    int lane = (int)(t & 63);
    int sub = lane >> 4;
    int fp  = lane & 15;
    int j0 = off_c[n], j1 = off_c[n + 1];
    float ax = 0.f, ay = 0.f;
    int j = j0 + sub;
    for (; j + 4 < j1; j += 8) {          // 2 edges in flight per lane
        int s0 = list_c[j], s1 = list_c[j + 4];
        float w0 = u2f(wcu[j]), w1 = u2f(wcu[j + 4]);
        unsigned p0 = *(const unsigned*)&Su[((long)s0 << 5) + (fp << 1)];
        unsigned p1 = *(const unsigned*)&Su[((long)s1 << 5) + (fp << 1)];
        ax += w0 * lo2f(p0) + w1 * lo2f(p1);
        ay += w0 * hi2f(p0) + w1 * hi2f(p1);
    }
    if (j < j1) {
        int s0 = list_c[j];
        float w0 = u2f(wcu[j]);
        unsigned p0 = *(const unsigned*)&Su[((long)s0 << 5) + (fp << 1)];
        ax += w0 * lo2f(p0);
        ay += w0 * hi2f(p0);
    }
    ax += __shfl_xor(ax, 16, 64); ay += __shfl_xor(ay, 16, 64);
    ax += __shfl_xor(ax, 32, 64); ay += __shfl_xor(ay, 32, 64);
    if (sub == 0) {
        int deg = j1 - j0;
        float dinv = (deg > 0) ? 1.0f / (float)deg : 0.f;
        *(float2*)&U[(n << 5) + (fp << 1)] = make_float2(ax * dinv, ay * dinv);
    }
}

// Phase B: down-direction (row-CSR over Sd) + U + Sb -> normalize+leaky -> out.
__global__ void k_gather_downfin(const int* __restrict__ off_r, const int* __restrict__ list_r,
                                 const ushort_t* __restrict__ wcd, const ushort_t* __restrict__ Sd,
                                 const ushort_t* __restrict__ Sb, const float* __restrict__ U,
                                 long N, float* __restrict__ out) {
    long t = (long)blockIdx.x * blockDim.x + threadIdx.x;
    long n = t >> 6;
    if (n >= N) return;
    int lane = (int)(t & 63);
    int sub = lane >> 4;
    int fp  = lane & 15;
    int j0 = off_r[n], j1 = off_r[n + 1];
    float ax = 0.f, ay = 0.f;
    int j = j0 + sub;
    for (; j + 4 < j1; j += 8) {
        int s0 = list_r[j], s1 = list_r[j + 4];
        float w0 = u2f(wcd[j]), w1 = u2f(wcd[j + 4]);
        unsigned p0 = *(const unsigned*)&Sd[((long)s0 << 5) + (fp << 1)];
        unsigned p1 = *(const unsigned*)&Sd[((long)s1 << 5) + (fp << 1)];
        ax += w0 * lo2f(p0) + w1 * lo2f(p1);
        ay += w0 * hi2f(p0) + w1 * hi2f(p1);
    }
    if (j < j1) {
        int s0 = list_r[j];
        float w0 = u2f(wcd[j]);
        unsigned p0 = *(const unsigned*)&Sd[((long)s0 << 5) + (fp << 1)];
        ax += w0 * lo2f(p0);
        ay += w0 * hi2f(p0);
    }
    ax += __shfl_xor(ax, 16, 64); ay += __shfl_xor(ay, 16, 64);
    ax += __shfl_xor(ax, 32, 64); ay += __shfl_xor(ay, 32, 64);
    float vx = 0.f, vy = 0.f, ux = 0.f, uy = 0.f, cx = 0.f, cy = 0.f;
    float ss = 0.f;
    if (sub == 0) {
        int deg = j1 - j0;
        float dinv = (deg > 0) ? 1.0f / (float)deg : 0.f;
        vx = ax * dinv; vy = ay * dinv;
        float2 uv = *(const float2*)&U[(n << 5) + (fp << 1)];
        ux = uv.x; uy = uv.y;
        unsigned bp = *(const unsigned*)&Sb[(n << 5) + (fp << 1)];
        cx = lo2f(bp); cy = hi2f(bp);
        ss = vx * vx + vy * vy + ux * ux + uy * uy + cx * cx + cy * cy;
    }
#pragma unroll
    for (int m = 1; m < 64; m <<= 1) ss += __shfl_xor(ss, m, 64);
    float inv = 1.0f / fmaxf(sqrtf(ss), 1e-12f);
    if (sub == 0) {
        float a, b;
        a = ux * inv; a = (a >= 0.f) ? a : 0.1f * a;
        b = uy * inv; b = (b >= 0.f) ? b : 0.1f * b;
        *(float2*)&out[n * 96 + (fp << 1)] = make_float2(a, b);
        a = vx * inv; a = (a >= 0.f) ? a : 0.1f * a;
        b = vy * inv; b = (b >= 0.f) ? b : 0.1f * b;
        *(float2*)&out[n * 96 + 32 + (fp << 1)] = make_float2(a, b);
        a = cx * inv; a = (a >= 0.f) ? a : 0.1f * a;
        b = cy * inv; b = (b >= 0.f) ? b : 0.1f * b;
        *(float2*)&out[n * 96 + 64 + (fp << 1)] = make_float2(a, b);
    }
}

// ================================================================ specialized linear, din=96, dout=3x32 fused, bf16 out
__global__ void k_lin96(const float* __restrict__ xin, long N,
                        const void* __restrict__ wu, const void* __restrict__ wd,
                        const void* __restrict__ wb, int wfi,
                        const int* __restrict__ flags,
                        ushort_t* __restrict__ Su, ushort_t* __restrict__ Sd,
                        ushort_t* __restrict__ Sb) {
    __shared__ float xs[32 * 100];   // 12.8 KB (reused as bf16 staging after compute)
    __shared__ float wt[96 * 96];    // 36.9 KB
    int tid = threadIdx.x;
    int ubf = flags[wfi], dbf = flags[wfi + 1], bbf = flags[wfi + 2];
    for (int j = tid; j < 96 * 96; j += 256) {
        int o3 = j % 96, i = j / 96;
        float v;
        if (o3 < 32)      v = ldf(wu, (long)o3 * 96 + i, ubf);
        else if (o3 < 64) v = ldf(wd, (long)(o3 - 32) * 96 + i, dbf);
        else              v = ldf(wb, (long)(o3 - 64) * 96 + i, bbf);
        wt[j] = v;
    }
    long nb = (long)blockIdx.x * 32;
    for (int j = tid; j < 32 * 24; j += 256) {
        int node = j / 24, c = j % 24;
        long gn = nb + node;
        float4 v = make_float4(0.f, 0.f, 0.f, 0.f);
        if (gn < N) v = ((const float4*)(xin + gn * 96))[c];
        *(float4*)&xs[node * 100 + c * 4] = v;
    }
    __syncthreads();
    int node = tid >> 3;
    int o0 = (tid & 7) * 12;
    float acc[12];
#pragma unroll
    for (int s = 0; s < 12; s++) acc[s] = 0.f;
    const float* xrow = &xs[node * 100];
#pragma unroll 4
    for (int c = 0; c < 24; c++) {
        float4 xv = *(const float4*)&xrow[c * 4];
        const float* w0 = &wt[(c * 4) * 96 + o0];
#pragma unroll
        for (int k = 0; k < 4; k++) {
            float xk = (k == 0) ? xv.x : (k == 1) ? xv.y : (k == 2) ? xv.z : xv.w;
            const float* wr = w0 + k * 96;
            float4 wa = *(const float4*)(wr);
            float4 wb4 = *(const float4*)(wr + 4);
            float4 wc = *(const float4*)(wr + 8);
            acc[0] += xk * wa.x;  acc[1] += xk * wa.y;  acc[2]  += xk * wa.z;  acc[3]  += xk * wa.w;
            acc[4] += xk * wb4.x; acc[5] += xk * wb4.y; acc[6]  += xk * wb4.z; acc[7]  += xk * wb4.w;
            acc[8] += xk * wc.x;  acc[9] += xk * wc.y;  acc[10] += xk * wc.z;  acc[11] += xk * wc.w;
        }
    }
    __syncthreads();
    ushort_t* sbuf = (ushort_t*)xs;
#pragma unroll
    for (int s = 0; s < 12; s++) sbuf[node * 96 + o0 + s] = f2u(acc[s]);
    __syncthreads();
    for (int j = tid; j < 32 * 96; j += 256) {
        int nd = j / 96, o3 = j % 96;
        long gn = nb + nd;
        if (gn < N) {
            int blk = o3 >> 5, fo = o3 & 31;
            ushort_t v = sbuf[j];
            (blk == 0 ? Su : blk == 1 ? Sd : Sb)[gn * 32 + fo] = v;
        }
    }
}

// ================================================================ generic linear -> bf16 S arrays (layer 1)
__global__ void k_linear_b16(const void* __restrict__ xin, int xfi, int din, int dout, long N,
                             const void* __restrict__ wu, const void* __restrict__ wd,
                             const void* __restrict__ wb, int wfi,
                             const int* __restrict__ flags, int uselds,
                             ushort_t* __restrict__ Su, ushort_t* __restrict__ Sd,
                             ushort_t* __restrict__ Sb) {
    __shared__ float smem[12288];
    int xbf = (xfi >= 0) ? flags[xfi] : 0;
    int ubf = flags[wfi], dbf = flags[wfi + 1], bbf = flags[wfi + 2];
    float* su = smem;
    float* sd = smem + (long)din * dout;
    float* sb = smem + 2l * din * dout;
    if (uselds) {
        for (int j = threadIdx.x; j < din * dout; j += 256) {
            int o = j % dout, i = j / dout;
            su[j] = ldf(wu, (long)o * din + i, ubf);
            sd[j] = ldf(wd, (long)o * din + i, dbf);
            sb[j] = ldf(wb, (long)o * din + i, bbf);
        }
        __syncthreads();
    }
    long idx = (long)blockIdx.x * blockDim.x + threadIdx.x;
    long node = idx / dout;
    int o = (int)(idx % dout);
    if (node >= N) return;
    float au = 0.f, ad = 0.f, ab = 0.f;
    long xb = node * din;
    if (uselds) {
        for (int i = 0; i < din; i++) {
            float xv = ldf(xin, xb + i, xbf);
            au += xv * su[i * dout + o];
            ad += xv * sd[i * dout + o];
            ab += xv * sb[i * dout + o];
        }
    } else {
        for (int i = 0; i < din; i++) {
            float xv = ldf(xin, xb + i, xbf);
            au += xv * ldf(wu, (long)o * din + i, ubf);
            ad += xv * ldf(wd, (long)o * din + i, dbf);
            ab += xv * ldf(wb, (long)o * din + i, bbf);
        }
    }
    Su[node * dout + o] = f2u(au);
    Sd[node * dout + o] = f2u(ad);
    Sb[node * dout + o] = f2u(ab);
}

// ================================================================ fallback (round-4 proven) kernels
__global__ void k_linear(const void* __restrict__ xin, int xfi, int din, int dout, int rs, long N,
                         const void* __restrict__ wu, const void* __restrict__ wd,
                         const void* __restrict__ wb, int wfi,
                         const int* __restrict__ flags, int uselds,
                         float* __restrict__ A, float* __restrict__ B, float* __restrict__ C) {
    __shared__ float smem[12288];
    int xbf = (xfi >= 0) ? flags[xfi] : 0;
    int ubf = flags[wfi], dbf = flags[wfi + 1], bbf = flags[wfi + 2];
    float* su = smem;
    float* sd = smem + (long)din * dout;
    float* sb = smem + 2l * din * dout;
    if (uselds) {
        for (int j = threadIdx.x; j < din * dout; j += 256) {
            int o = j % dout, i = j / dout;
            su[j] = ldf(wu, (long)o * din + i, ubf);
            sd[j] = ldf(wd, (long)o * din + i, dbf);
            sb[j] = ldf(wb, (long)o * din + i, bbf);
        }
        __syncthreads();
    }
    long idx = (long)blockIdx.x * blockDim.x + threadIdx.x;
    long node = idx / dout;
    int o = (int)(idx % dout);
    if (node >= N) return;
    float au = 0.f, ad = 0.f, ab = 0.f;
    long xb = node * din;
    if (uselds) {
        for (int i = 0; i < din; i++) {
            float xv = ldf(xin, xb + i, xbf);
            au += xv * su[i * dout + o];
            ad += xv * sd[i * dout + o];
            ab += xv * sb[i * dout + o];
        }
    } else {
        for (int i = 0; i < din; i++) {
            float xv = ldf(xin, xb + i, xbf);
            au += xv * ldf(wu, (long)o * din + i, ubf);
            ad += xv * ldf(wd, (long)o * din + i, dbf);
            ab += xv * ldf(wb, (long)o * din + i, bbf);
        }
    }
    A[node * rs + o] = au;
    B[node * rs + o] = ad;
    C[node * rs + o] = ab;
}

__global__ void k_deg(const int* __restrict__ ei, long E, const int* __restrict__ flags,
                      float* __restrict__ degc, float* __restrict__ degr) {
    long e = (long)blockIdx.x * blockDim.x + threadIdx.x;
    if (e < E) {
        int is64 = flags[16];
        atomicAdd(&degc[lde(ei, 1, e, E, is64)], 1.0f);
        atomicAdd(&degr[lde(ei, 0, e, E, is64)], 1.0f);
    }
}

__global__ void k_inv(float* __restrict__ a, long n) {
    long i = (long)blockIdx.x * blockDim.x + threadIdx.x;
    if (i < n) { float v = a[i]; a[i] = (v > 0.0f) ? 1.0f / v : 0.0f; }
}

__global__ void k_scatter(const int* __restrict__ ei, long E, int F,
                          const void* __restrict__ ewu, const void* __restrict__ ewd,
                          int fu, int fd, const int* __restrict__ flags,
                          const float* __restrict__ degci, const float* __restrict__ degri,
                          const float* __restrict__ A, const float* __restrict__ B,
                          float* __restrict__ U, float* __restrict__ D) {
    long idx = (long)blockIdx.x * blockDim.x + threadIdx.x;
    long tot = E * 2 * F;
    if (idx >= tot) return;
    int is64 = flags[16];
    long e = idx / (2 * F);
    int rem = (int)(idx - e * 2 * F);
    int dir = rem >= F;
    int f = rem - dir * F;
    int r = lde(ei, 0, e, E, is64), c = lde(ei, 1, e, E, is64);
    if (!dir) {
        float w = degci[c] * ldf(ewu, e, flags[fu]);
        atomicAdd(&U[(long)c * F + f], w * A[(long)r * F + f]);
    } else {
        float w = degri[r] * ldf(ewd, e, flags[fd]);
        atomicAdd(&D[(long)r * F + f], w * B[(long)c * F + f]);
    }
}

__global__ void k_finalize(const float* __restrict__ U, const float* __restrict__ D,
                           const float* __restrict__ C, int F, long N,
                           float* __restrict__ out) {
    long t = (long)blockIdx.x * blockDim.x + threadIdx.x;
    long n = t >> 6;
    if (n >= N) return;
    int lane = (int)(t & 63);
    int cat = 3 * F;
    float ss = 0.f;
    for (int j = lane; j < cat; j += 64) {
        float v = (j < F) ? U[n * F + j] : (j < 2 * F) ? D[n * F + j - F] : C[n * F + j - 2 * F];
        ss += v * v;
    }
#pragma unroll
    for (int m = 1; m < 64; m <<= 1) ss += __shfl_xor(ss, m, 64);
    float inv = 1.0f / fmaxf(sqrtf(ss), 1e-12f);
    for (int j = lane; j < cat; j += 64) {
        float v = (j < F) ? U[n * F + j] : (j < 2 * F) ? D[n * F + j - F] : C[n * F + j - 2 * F];
        float a = v * inv;
        a = (a >= 0.0f) ? a : 0.1f * a;
        out[n * cat + j] = a;
    }
}

__global__ void k_mean(const void* e1u, const void* e2u, const void* e3u,
                       const void* e1d, const void* e2d, const void* e3d,
                       const int* __restrict__ flags, long E,
                       float* __restrict__ mu, float* __restrict__ md) {
    long e = (long)blockIdx.x * blockDim.x + threadIdx.x;
    if (e >= E) return;
    float su = ldf(e1u, e, flags[4]) + ldf(e2u, e, flags[9]) + ldf(e3u, e, flags[14]);
    float sd = ldf(e1d, e, flags[5]) + ldf(e2d, e, flags[10]) + ldf(e3d, e, flags[15]);
    mu[e] = su / 3.0f;
    md[e] = sd / 3.0f;
}

extern "C" void kernel_launch(void* const* d_in, const int* in_sizes, int n_in,
                              void* d_out, int out_size, void* d_ws, size_t ws_size,
                              hipStream_t stream) {
    const int* ei = (const int*)d_in[1];
    const void* w_up[3]   = {d_in[2], d_in[7],  d_in[12]};
    const void* w_down[3] = {d_in[3], d_in[8],  d_in[13]};
    const void* w_bias[3] = {d_in[4], d_in[9],  d_in[14]};
    const void* ew_up[3]  = {d_in[5], d_in[10], d_in[15]};
    const void* ew_down[3]= {d_in[6], d_in[11], d_in[16]};

    // ---- derive true sizes from in_sizes
    long E = in_sizes[5];
    if (E <= 0) E = 1600000;
    int HID = (int)(sqrt((double)in_sizes[7] / 3.0) + 0.5);
    if (HID <= 0 || (long)3 * HID * HID != (long)in_sizes[7]) HID = 32;
    int DIN = in_sizes[2] / HID;
    if (DIN <= 0) DIN = 8;
    long N = (long)in_sizes[0] / DIN;
    if (N <= 0) N = 50000;
    int EMB = in_sizes[12] / (3 * HID);
    if (EMB <= 0) EMB = 32;
    int Fm = HID > EMB ? HID : EMB;
    int NB = (int)((N + 255) >> BSH);

    // ---- outputs: fp32, concatenated (h, mean_up, mean_down)
    float* out_h  = (float*)d_out;
    float* out_mu = out_h + N * 3l * EMB;
    float* out_md = out_mu + E;

    const int TB = 256;
    int lds1  = (3l * DIN * HID <= 12288) ? 1 : 0;
    int lds12 = (3l * (3 * HID) * HID <= 12288) ? 1 : 0;
    int lds3  = (3l * (3 * HID) * EMB <= 12288) ? 1 : 0;
    dim3 linG1((unsigned)((N * HID + TB - 1) / TB));
    dim3 linG3((unsigned)((N * EMB + TB - 1) / TB));
    dim3 lin96G((unsigned)((N + 31) / 32));
    dim3 finG((unsigned)((N * 64 + TB - 1) / TB));
    dim3 edgeG((unsigned)((E + TB - 1) / TB));
    dim3 chunkG((unsigned)((E + 2047) / 2048), 2);

    // ---- fast-path workspace layout
    int* flags = (int*)d_ws;                       // 64
    int* bc    = flags + 64;                       // 2*NBMAX
    int* bb    = bc + 2 * NBMAX;                   // 2*(NBMAX+1)
    int* gcur  = bb + 2 * (NBMAX + 1);             // 2*NBMAX
    int* off_c = gcur + 2 * NBMAX;                 // N+1
    int* off_r = off_c + (N + 1);                  // N+1
    long li = (long)(off_r + (N + 1) - (int*)d_ws);
    li = (li + 3) & ~3l;
    int* list_c = (int*)d_ws + li;                 // E (src only - gather hot path)
    int* list_r = list_c + E;                      // E
    int* eidx_c = list_r + E;                      // E (eids - wcsr only)
    int* eidx_r = eidx_c + E;                      // E
    int* R = eidx_r + E;
    // phase 1 (bucket build): bdst 2E ints + bse 2E int2
    int* bdst = R;
    int2* bse = (int2*)(R + 2 * E);
    // phase 2+: wc6 persists; ebc6 transient; S/U overlay ebc6
    ushort_t* wc6  = (ushort_t*)R;                 // 6E ushorts = 3E ints
    ushort_t* ebc6 = (ushort_t*)(R + 3 * E);       // 6E ushorts = 3E ints
    ushort_t* Su = ebc6;                           // N*Fm (after wcsr, ebc6 dead)
    ushort_t* Sd = Su + N * Fm;
    ushort_t* Sb = Sd + N * Fm;
    float* U = (float*)(Sb + N * Fm);              // N*Fm fp32 (int-aligned: 3*N*Fm even)
    long zInts = (3l * N * Fm + 1) / 2 + N * Fm;   // S arrays + U
    long Rints = 6l * E;
    long p2 = 3l * E + ((zInts > 3l * E) ? zInts : 3l * E);
    if (p2 > Rints) Rints = p2;
    size_t need = (size_t)((li + 4l * E + Rints) * 4l + 256);

    bool fast = (HID == 32 && EMB == 32) && (NB <= NBMAX) &&
                (ws_size == 0 || ws_size >= need);

    // ---- dtype detection (both paths)
    DetectArgs da;
    da.p[0] = d_in[0]; da.n[0] = in_sizes[0];
    for (int L = 0; L < 3; L++) {
        da.p[1 + 5 * L] = w_up[L];    da.n[1 + 5 * L] = in_sizes[2 + 5 * L];
        da.p[2 + 5 * L] = w_down[L];  da.n[2 + 5 * L] = in_sizes[3 + 5 * L];
        da.p[3 + 5 * L] = w_bias[L];  da.n[3 + 5 * L] = in_sizes[4 + 5 * L];
        da.p[4 + 5 * L] = ew_up[L];   da.n[4 + 5 * L] = in_sizes[5 + 5 * L];
        da.p[5 + 5 * L] = ew_down[L]; da.n[5 + 5 * L] = in_sizes[6 + 5 * L];
    }
    da.ei = ei; da.E = E; da.flags = flags;
    k_detect<<<17, TB, 0, stream>>>(da);

    if (fast) {
        // ---- bucketed CSR build (once; reused 3 layers x 2 directions)
        hipMemsetAsync(bc, 0, 2 * NBMAX * sizeof(int), stream);
        kb_count<<<chunkG, TB, 0, stream>>>(ei, E, flags, NB, bc);
        kb_scan<<<1, 512, 0, stream>>>(bc, bb, gcur, NB);
        kb_fill<<<chunkG, TB, 0, stream>>>(ei, E, flags, NB, gcur, bdst, bse);
        kb_csr<<<dim3((unsigned)NB, 2), TB, 0, stream>>>(bb, bdst, bse, E, NB, N,
                                                         off_c, off_r, list_c, list_r,
                                                         eidx_c, eidx_r);

        // ---- cast all 6 ew arrays + write mean outputs, one pass
        k_ewcast6<<<edgeG, TB, 0, stream>>>(ew_up[0], ew_up[1], ew_up[2],
                                            ew_down[0], ew_down[1], ew_down[2],
                                            flags, E, ebc6, out_mu, out_md);
        // ---- CSR-ordered bf16 weights, 3 layers x 2 dirs
        for (int L = 0; L < 3; L++) {
            k_wcsr<<<edgeG, TB, 0, stream>>>(eidx_c, E, ebc6 + (long)(2 * L) * E,
                                             wc6 + (long)(2 * L) * E);
            k_wcsr<<<edgeG, TB, 0, stream>>>(eidx_r, E, ebc6 + (long)(2 * L + 1) * E,
                                             wc6 + (long)(2 * L + 1) * E);
        }

        float* H = (float*)d_out;   // intermediate 96-wide activations live in d_out

        // ---- layer 1 (din=DIN, generic, bf16 S output)
        k_linear_b16<<<linG1, TB, 0, stream>>>(d_in[0], 0, DIN, HID, N,
                                               w_up[0], w_down[0], w_bias[0], 1, flags, lds1,
                                               Su, Sd, Sb);
        k_gather_up<<<finG, TB, 0, stream>>>(off_c, list_c, wc6, Su, N, U);
        k_gather_downfin<<<finG, TB, 0, stream>>>(off_r, list_r, wc6 + E, Sd, Sb, U, N, H);
        // ---- layer 2 (din=96 specialized)
        k_lin96<<<lin96G, TB, 0, stream>>>(H, N, w_up[1], w_down[1], w_bias[1], 6, flags,
                                           Su, Sd, Sb);
        k_gather_up<<<finG, TB, 0, stream>>>(off_c, list_c, wc6 + 2l * E, Su, N, U);
        k_gather_downfin<<<finG, TB, 0, stream>>>(off_r, list_r, wc6 + 3l * E, Sd, Sb, U, N, H);
        // ---- layer 3 -> final fp32 output
        k_lin96<<<lin96G, TB, 0, stream>>>(H, N, w_up[2], w_down[2], w_bias[2], 11, flags,
                                           Su, Sd, Sb);
        k_gather_up<<<finG, TB, 0, stream>>>(off_c, list_c, wc6 + 4l * E, Su, N, U);
        k_gather_downfin<<<finG, TB, 0, stream>>>(off_r, list_r, wc6 + 5l * E, Sd, Sb, U, N, out_h);
    } else {
        // ---- fallback: round-4 proven atomic-scatter path
        float* degci = (float*)(flags + 64);
        float* degri = degci + N;
        float* fA = degri + N;
        float* fB = fA + N * Fm;
        float* fC = fB + N * Fm;
        float* fU = fC + N * Fm;
        float* fD = fU + N * Fm;
        float* fH = fD + N * Fm;
        dim3 scatG12((unsigned)((E * 2 * HID + TB - 1) / TB));
        dim3 scatG3((unsigned)((E * 2 * EMB + TB - 1) / TB));

        hipMemsetAsync(degci, 0, 2 * N * sizeof(float), stream);
        k_deg<<<edgeG, TB, 0, stream>>>(ei, E, flags, degci, degri);
        k_inv<<<dim3((unsigned)((2 * N + TB - 1) / TB)), TB, 0, stream>>>(degci, 2 * N);

        k_linear<<<linG1, TB, 0, stream>>>(d_in[0], 0, DIN, HID, HID, N,
                                           w_up[0], w_down[0], w_bias[0], 1, flags, lds1, fA, fB, fC);
        hipMemsetAsync(fU, 0, 2l * N * Fm * sizeof(float), stream);
        k_scatter<<<scatG12, TB, 0, stream>>>(ei, E, HID, ew_up[0], ew_down[0], 4, 5, flags,
                                              degci, degri, fA, fB, fU, fD);
        k_finalize<<<finG, TB, 0, stream>>>(fU, fD, fC, HID, N, fH);

        k_linear<<<linG1, TB, 0, stream>>>(fH, -1, 3 * HID, HID, HID, N,
                                           w_up[1], w_down[1], w_bias[1], 6, flags, lds12, fA, fB, fC);
        hipMemsetAsync(fU, 0, 2l * N * Fm * sizeof(float), stream);
        k_scatter<<<scatG12, TB, 0, stream>>>(ei, E, HID, ew_up[1], ew_down[1], 9, 10, flags,
                                              degci, degri, fA, fB, fU, fD);
        k_finalize<<<finG, TB, 0, stream>>>(fU, fD, fC, HID, N, fH);

        k_linear<<<linG3, TB, 0, stream>>>(fH, -1, 3 * HID, EMB, EMB, N,
                                           w_up[2], w_down[2], w_bias[2], 11, flags, lds3, fA, fB, fC);
        hipMemsetAsync(fU, 0, 2l * N * Fm * sizeof(float), stream);
        k_scatter<<<scatG3, TB, 0, stream>>>(ei, E, EMB, ew_up[2], ew_down[2], 14, 15, flags,
                                             degci, degri, fA, fB, fU, fD);
        k_finalize<<<finG, TB, 0, stream>>>(fU, fD, fC, EMB, N, out_h);

        k_mean<<<edgeG, TB, 0, stream>>>(ew_up[0], ew_up[1], ew_up[2],
                                         ew_down[0], ew_down[1], ew_down[2],
                                         flags, E, out_mu, out_md);
    }
}

// Round 11
// 645.631 us; speedup vs baseline: 3.1049x; 1.0812x over previous
//
#include <hip/hip_runtime.h>
#include <hip/hip_bf16.h>
#include <math.h>

typedef __hip_bfloat16 bf16;
typedef unsigned short ushort_t;

#define NBMAX 1024   // max buckets (N <= 262144 for fast path; also guarantees src < 2^24)
#define BSH 8        // 256 nodes per bucket
#define CH 4096      // edges per kb_fill chunk
#define CSRCAP 6144  // LDS staging capacity per half-bucket in kb_csr

// flags[0..15]: 1 if float-array slot is bf16, 0 if fp32.
//   slot 0:x | per layer L(0..2): 1+5L:w_up 2+5L:w_down 3+5L:w_bias 4+5L:ew_up 5+5L:ew_down
// flags[16]: 1 if edge_index is int64 (little-endian, values < 2^31), else int32.
__device__ __forceinline__ float ldf(const void* p, long i, int isbf) {
    return isbf ? __bfloat162float(((const bf16*)p)[i]) : ((const float*)p)[i];
}
__device__ __forceinline__ int lde(const int* ei, int half, long e, long E, int is64) {
    long idx = half ? (E + e) : e;
    return is64 ? ei[idx * 2] : ei[idx];
}
__device__ __forceinline__ float u2f(ushort_t u) {
    union { unsigned int i; float f; } v; v.i = ((unsigned)u) << 16; return v.f;
}
__device__ __forceinline__ ushort_t f2u(float f) {
    bf16 h = __float2bfloat16(f);
    return *reinterpret_cast<ushort_t*>(&h);
}
__device__ __forceinline__ float lo2f(unsigned sp) {
    union { unsigned i; float f; } v; v.i = sp << 16; return v.f;
}
__device__ __forceinline__ float hi2f(unsigned sp) {
    union { unsigned i; float f; } v; v.i = sp & 0xffff0000u; return v.f;
}

// ---------------------------------------------------------------- dtype detection
struct DetectArgs {
    const void* p[16];
    long n[16];
    const int* ei;
    long E;
    int* flags;
};

__global__ void k_detect(DetectArgs a) {
    __shared__ int cnt;
    if (threadIdx.x == 0) cnt = 0;
    __syncthreads();
    int b = blockIdx.x;
    int bad = 0;
    if (b < 16) {
        const bf16* p = (const bf16*)a.p[b];
        long m = a.n[b] < 4096 ? a.n[b] : 4096;
        for (long i = threadIdx.x; i < m; i += 256) {
            float v = __bfloat162float(p[i]);
            if (!(fabsf(v) < 100.0f)) bad++;
        }
        atomicAdd(&cnt, bad);
        __syncthreads();
        if (threadIdx.x == 0) a.flags[b] = ((long)cnt * 16 < m) ? 1 : 0;
    } else {
        long m = a.E / 2 < 4096 ? a.E / 2 : 4096;
        for (long i = threadIdx.x; i < m; i += 256) {
            if (a.ei[2 * i + 1] != 0) bad++;
        }
        atomicAdd(&cnt, bad);
        __syncthreads();
        if (threadIdx.x == 0) a.flags[16] = (cnt < (int)(m / 16) + 1) ? 1 : 0;
    }
}

// ================================================================ bucketed CSR build
// dir 0: dst=col (up-list), dir 1: dst=row (down-list). bucket = dst>>8.

// Both directions per chunk, one edge-read pass.
__global__ void kb_count(const int* __restrict__ ei, long E, const int* __restrict__ flags,
                         int NB, int* __restrict__ bc) {
    __shared__ int h0[NBMAX], h1[NBMAX];
    for (int i = threadIdx.x; i < NB; i += 256) { h0[i] = 0; h1[i] = 0; }
    __syncthreads();
    int is64 = flags[16];
    long base = (long)blockIdx.x * CH;
#pragma unroll
    for (int i = 0; i < CH / 256; i++) {
        long e = base + i * 256 + threadIdx.x;
        if (e < E) {
            int c = lde(ei, 1, e, E, is64);   // dir0 dst=col
            int r = lde(ei, 0, e, E, is64);   // dir1 dst=row
            atomicAdd(&h0[c >> BSH], 1);
            atomicAdd(&h1[r >> BSH], 1);
        }
    }
    __syncthreads();
    for (int i = threadIdx.x; i < NB; i += 256) {
        if (h0[i]) atomicAdd(&bc[i], h0[i]);
        if (h1[i]) atomicAdd(&bc[NBMAX + i], h1[i]);
    }
}

__global__ void kb_scan(const int* __restrict__ bc, int* __restrict__ bb,
                        int* __restrict__ gcur, int NB) {
    if (threadIdx.x < 2) {
        int dir = threadIdx.x;
        int acc = 0;
        for (int i = 0; i < NB; i++) { bb[dir * (NBMAX + 1) + i] = acc; acc += bc[dir * NBMAX + i]; }
        bb[dir * (NBMAX + 1) + NB] = acc;
    }
    __syncthreads();
    for (int i = threadIdx.x; i < 2 * NBMAX; i += blockDim.x) {
        int d = i / NBMAX, b = i - d * NBMAX;
        gcur[i] = bb[d * (NBMAX + 1) + (b < NB ? b : NB)];
    }
}

// Per-block counting-sort of a 4096-edge chunk by bucket, bucket-contiguous
// global append. Record: (src | local<<24, eid) — no separate dst array.
__global__ void kb_fill(const int* __restrict__ ei, long E, const int* __restrict__ flags,
                        int NB, int* __restrict__ gcur, int2* __restrict__ bse) {
    __shared__ int2 ssE[CH];            // 32 KB sorted (src|local<<24, eid)
    __shared__ ushort_t sbkt[CH];       // 8 KB bucket id per staged entry
    __shared__ int h[NBMAX], lofs[NBMAX], cur[NBMAX], gb[NBMAX];  // 16 KB
    __shared__ int sc[256];
    int tid = threadIdx.x;
    int dir = blockIdx.y;
    int is64 = flags[16];
    for (int i = tid; i < NBMAX; i += 256) { h[i] = 0; cur[i] = 0; }
    __syncthreads();
    long base = (long)blockIdx.x * CH;
    int myd[CH / 256], mys[CH / 256], mye[CH / 256];
#pragma unroll
    for (int i = 0; i < CH / 256; i++) {
        long e = base + i * 256 + tid;
        myd[i] = -1;
        if (e < E) {
            myd[i] = lde(ei, dir ? 0 : 1, e, E, is64);
            mys[i] = lde(ei, dir ? 1 : 0, e, E, is64);
            mye[i] = (int)e;
            atomicAdd(&h[myd[i] >> BSH], 1);
        }
    }
    __syncthreads();
    int i0 = tid * 4;
    int a0 = h[i0], a1 = h[i0 + 1], a2 = h[i0 + 2], a3 = h[i0 + 3];
    int ts = a0 + a1 + a2 + a3;
    sc[tid] = ts;
    __syncthreads();
    for (int d = 1; d < 256; d <<= 1) {
        int t = (tid >= d) ? sc[tid - d] : 0;
        __syncthreads();
        sc[tid] += t;
        __syncthreads();
    }
    int eb = sc[tid] - ts;
    lofs[i0] = eb; lofs[i0 + 1] = eb + a0; lofs[i0 + 2] = eb + a0 + a1; lofs[i0 + 3] = eb + a0 + a1 + a2;
    __syncthreads();
#pragma unroll
    for (int i = 0; i < CH / 256; i++) {
        if (myd[i] >= 0) {
            int b = myd[i] >> BSH;
            int r = atomicAdd(&cur[b], 1);
            int p = lofs[b] + r;
            ssE[p] = make_int2(mys[i] | ((myd[i] & 255) << 24), mye[i]);
            sbkt[p] = (ushort_t)b;
        }
    }
    __syncthreads();
    for (int b = tid; b < NB; b += 256) {
        int c = h[b];
        gb[b] = c ? atomicAdd(&gcur[dir * NBMAX + b], c) : 0;
    }
    __syncthreads();
    long rem = E - base;
    int nvalid = rem >= CH ? CH : (rem > 0 ? (int)rem : 0);
    int2* os = bse + (long)dir * E;
    for (int s = tid; s < nvalid; s += 256) {
        int b = sbkt[s];
        long p = (long)gb[b] + (s - lofs[b]);
        os[p] = ssE[s];
    }
}

// Per-(bucket,dir) counting sort into final per-node CSR. Sorted bucket staged
// in LDS (two half-passes over locals <128/>=128), then written out coalesced
// -> no random global writes at all. Guarded fallback if a half exceeds CSRCAP.
__global__ void kb_csr(const int* __restrict__ bb, const int2* __restrict__ bse,
                       long E, int NB, long N,
                       int* __restrict__ off_c, int* __restrict__ off_r,
                       int* __restrict__ list_c, int* __restrict__ list_r,
                       int* __restrict__ eidx_c, int* __restrict__ eidx_r) {
    __shared__ int2 sbuf[CSRCAP];       // 48 KB
    __shared__ int h[256], lofs[256], cur[256], sc[256];
    int tid = threadIdx.x;
    int b = blockIdx.x, dir = blockIdx.y;
    int base = bb[dir * (NBMAX + 1) + b];
    int cnt  = bb[dir * (NBMAX + 1) + b + 1] - base;
    const int2* bs = bse + (long)dir * E;
    int* off  = dir ? off_r : off_c;
    int* list = dir ? list_r : list_c;
    int* eidx = dir ? eidx_r : eidx_c;
    h[tid] = 0; cur[tid] = 0;
    __syncthreads();
    int nb0 = b << BSH;
    for (int s = tid; s < cnt; s += 256)
        atomicAdd(&h[(unsigned)bs[base + s].x >> 24], 1);
    __syncthreads();
    int v = h[tid];
    sc[tid] = v;
    __syncthreads();
    for (int d = 1; d < 256; d <<= 1) {
        int t = (tid >= d) ? sc[tid - d] : 0;
        __syncthreads();
        sc[tid] += t;
        __syncthreads();
    }
    lofs[tid] = sc[tid] - v;
    __syncthreads();
    long n = (long)nb0 + tid;
    if (n < N) off[n] = base + lofs[tid];
    if (b == 0 && tid == 0) off[N] = (int)E;
    int mid = lofs[128];
    int cnt1 = cnt - mid;
    if (mid <= CSRCAP && cnt1 <= CSRCAP) {
        // half 0: locals 0..127
        for (int s = tid; s < cnt; s += 256) {
            int2 se = bs[base + s];
            int local = (unsigned)se.x >> 24;
            if (local < 128) {
                int r = atomicAdd(&cur[local], 1);
                sbuf[lofs[local] + r] = se;
            }
        }
        __syncthreads();
        for (int s = tid; s < mid; s += 256) {
            int2 se = sbuf[s];
            list[base + s] = se.x & 0xFFFFFF;
            eidx[base + s] = se.y;
        }
        __syncthreads();
        // half 1: locals 128..255
        for (int s = tid; s < cnt; s += 256) {
            int2 se = bs[base + s];
            int local = (unsigned)se.x >> 24;
            if (local >= 128) {
                int r = atomicAdd(&cur[local], 1);
                sbuf[lofs[local] - mid + r] = se;
            }
        }
        __syncthreads();
        for (int s = tid; s < cnt1; s += 256) {
            int2 se = sbuf[s];
            list[base + mid + s] = se.x & 0xFFFFFF;
            eidx[base + mid + s] = se.y;
        }
    } else {
        // fallback: direct random writes (correct, slower)
        for (int s = tid; s < cnt; s += 256) {
            int2 se = bs[base + s];
            int local = (unsigned)se.x >> 24;
            int r = atomicAdd(&cur[local], 1);
            long p = (long)base + lofs[local] + r;
            list[p] = se.x & 0xFFFFFF;
            eidx[p] = se.y;
        }
    }
}

// ================================================================ ew: cast all 6 arrays + means, one pass
__global__ void k_ewcast6(const void* __restrict__ e1u, const void* __restrict__ e2u,
                          const void* __restrict__ e3u, const void* __restrict__ e1d,
                          const void* __restrict__ e2d, const void* __restrict__ e3d,
                          const int* __restrict__ flags, long E,
                          ushort_t* __restrict__ ebc6,
                          float* __restrict__ mu, float* __restrict__ md) {
    long e = (long)blockIdx.x * blockDim.x + threadIdx.x;
    if (e >= E) return;
    float v1u = ldf(e1u, e, flags[4]),  v2u = ldf(e2u, e, flags[9]),  v3u = ldf(e3u, e, flags[14]);
    float v1d = ldf(e1d, e, flags[5]),  v2d = ldf(e2d, e, flags[10]), v3d = ldf(e3d, e, flags[15]);
    ebc6[0 * E + e] = f2u(v1u); ebc6[1 * E + e] = f2u(v1d);
    ebc6[2 * E + e] = f2u(v2u); ebc6[3 * E + e] = f2u(v2d);
    ebc6[4 * E + e] = f2u(v3u); ebc6[5 * E + e] = f2u(v3d);
    mu[e] = (v1u + v2u + v3u) / 3.0f;
    md[e] = (v1d + v2d + v3d) / 3.0f;
}

// wout[j] = tab[eidx[j]]: sequential eidx read, random read confined to a
// 3.2MB L2-resident table, sequential write.
__global__ void k_wcsr(const int* __restrict__ eidx, long E,
                       const ushort_t* __restrict__ tab, ushort_t* __restrict__ wout) {
    long j = (long)blockIdx.x * blockDim.x + threadIdx.x;
    if (j < E) wout[j] = tab[eidx[j]];
}

// ================================================================ phase-split gather (F==32)
// 4 edge parities per wave (sub=lane>>4), 16 feature-pair lanes (fp=lane&15).
// Each dispatch's random hot set is ONE 3.2MB bf16 table -> per-XCD L2 resident.

// Phase A: up-direction (col-CSR over Su) -> U[n][32] fp32 (deg-normalized).
__global__ void k_gather_up(const int* __restrict__ off_c, const int* __restrict__ list_c,
                            const ushort_t* __restrict__ wcu, const ushort_t* __restrict__ Su,
                            long N, float* __restrict__ U) {
    long t = (long)blockIdx.x * blockDim.x + threadIdx.x;
    long n = t >> 6;
    if (n >= N) return;
    int lane = (int)(t & 63);
    int sub = lane >> 4;
    int fp  = lane & 15;
    int j0 = off_c[n], j1 = off_c[n + 1];
    float ax = 0.f, ay = 0.f;
    int j = j0 + sub;
    for (; j + 4 < j1; j += 8) {          // 2 edges in flight per lane
        int s0 = list_c[j], s1 = list_c[j + 4];
        float w0 = u2f(wcu[j]), w1 = u2f(wcu[j + 4]);
        unsigned p0 = *(const unsigned*)&Su[((long)s0 << 5) + (fp << 1)];
        unsigned p1 = *(const unsigned*)&Su[((long)s1 << 5) + (fp << 1)];
        ax += w0 * lo2f(p0) + w1 * lo2f(p1);
        ay += w0 * hi2f(p0) + w1 * hi2f(p1);
    }
    if (j < j1) {
        int s0 = list_c[j];
        float w0 = u2f(wcu[j]);
        unsigned p0 = *(const unsigned*)&Su[((long)s0 << 5) + (fp << 1)];
        ax += w0 * lo2f(p0);
        ay += w0 * hi2f(p0);
    }
    ax += __shfl_xor(ax, 16, 64); ay += __shfl_xor(ay, 16, 64);
    ax += __shfl_xor(ax, 32, 64); ay += __shfl_xor(ay, 32, 64);
    if (sub == 0) {
        int deg = j1 - j0;
        float dinv = (deg > 0) ? 1.0f / (float)deg : 0.f;
        *(float2*)&U[(n << 5) + (fp << 1)] = make_float2(ax * dinv, ay * dinv);
    }
}

// Phase B: down-direction (row-CSR over Sd) + U + Sb -> normalize+leaky -> out.
__global__ void k_gather_downfin(const int* __restrict__ off_r, const int* __restrict__ list_r,
                                 const ushort_t* __restrict__ wcd, const ushort_t* __restrict__ Sd,
                                 const ushort_t* __restrict__ Sb, const float* __restrict__ U,
                                 long N, float* __restrict__ out) {
    long t = (long)blockIdx.x * blockDim.x + threadIdx.x;
    long n = t >> 6;
    if (n >= N) return;
    int lane = (int)(t & 63);
    int sub = lane >> 4;
    int fp  = lane & 15;
    int j0 = off_r[n], j1 = off_r[n + 1];
    float ax = 0.f, ay = 0.f;
    int j = j0 + sub;
    for (; j + 4 < j1; j += 8) {
        int s0 = list_r[j], s1 = list_r[j + 4];
        float w0 = u2f(wcd[j]), w1 = u2f(wcd[j + 4]);
        unsigned p0 = *(const unsigned*)&Sd[((long)s0 << 5) + (fp << 1)];
        unsigned p1 = *(const unsigned*)&Sd[((long)s1 << 5) + (fp << 1)];
        ax += w0 * lo2f(p0) + w1 * lo2f(p1);
        ay += w0 * hi2f(p0) + w1 * hi2f(p1);
    }
    if (j < j1) {
        int s0 = list_r[j];
        float w0 = u2f(wcd[j]);
        unsigned p0 = *(const unsigned*)&Sd[((long)s0 << 5) + (fp << 1)];
        ax += w0 * lo2f(p0);
        ay += w0 * hi2f(p0);
    }
    ax += __shfl_xor(ax, 16, 64); ay += __shfl_xor(ay, 16, 64);
    ax += __shfl_xor(ax, 32, 64); ay += __shfl_xor(ay, 32, 64);
    float vx = 0.f, vy = 0.f, ux = 0.f, uy = 0.f, cx = 0.f, cy = 0.f;
    float ss = 0.f;
    if (sub == 0) {
        int deg = j1 - j0;
        float dinv = (deg > 0) ? 1.0f / (float)deg : 0.f;
        vx = ax * dinv; vy = ay * dinv;
        float2 uv = *(const float2*)&U[(n << 5) + (fp << 1)];
        ux = uv.x; uy = uv.y;
        unsigned bp = *(const unsigned*)&Sb[(n << 5) + (fp << 1)];
        cx = lo2f(bp); cy = hi2f(bp);
        ss = vx * vx + vy * vy + ux * ux + uy * uy + cx * cx + cy * cy;
    }
#pragma unroll
    for (int m = 1; m < 64; m <<= 1) ss += __shfl_xor(ss, m, 64);
    float inv = 1.0f / fmaxf(sqrtf(ss), 1e-12f);
    if (sub == 0) {
        float a, b;
        a = ux * inv; a = (a >= 0.f) ? a : 0.1f * a;
        b = uy * inv; b = (b >= 0.f) ? b : 0.1f * b;
        *(float2*)&out[n * 96 + (fp << 1)] = make_float2(a, b);
        a = vx * inv; a = (a >= 0.f) ? a : 0.1f * a;
        b = vy * inv; b = (b >= 0.f) ? b : 0.1f * b;
        *(float2*)&out[n * 96 + 32 + (fp << 1)] = make_float2(a, b);
        a = cx * inv; a = (a >= 0.f) ? a : 0.1f * a;
        b = cy * inv; b = (b >= 0.f) ? b : 0.1f * b;
        *(float2*)&out[n * 96 + 64 + (fp << 1)] = make_float2(a, b);
    }
}

// ================================================================ specialized linear, din=96, dout=3x32 fused, bf16 out
__global__ void k_lin96(const float* __restrict__ xin, long N,
                        const void* __restrict__ wu, const void* __restrict__ wd,
                        const void* __restrict__ wb, int wfi,
                        const int* __restrict__ flags,
                        ushort_t* __restrict__ Su, ushort_t* __restrict__ Sd,
                        ushort_t* __restrict__ Sb) {
    __shared__ float xs[32 * 100];   // 12.8 KB (reused as bf16 staging after compute)
    __shared__ float wt[96 * 96];    // 36.9 KB
    int tid = threadIdx.x;
    int ubf = flags[wfi], dbf = flags[wfi + 1], bbf = flags[wfi + 2];
    for (int j = tid; j < 96 * 96; j += 256) {
        int o3 = j % 96, i = j / 96;
        float v;
        if (o3 < 32)      v = ldf(wu, (long)o3 * 96 + i, ubf);
        else if (o3 < 64) v = ldf(wd, (long)(o3 - 32) * 96 + i, dbf);
        else              v = ldf(wb, (long)(o3 - 64) * 96 + i, bbf);
        wt[j] = v;
    }
    long nb = (long)blockIdx.x * 32;
    for (int j = tid; j < 32 * 24; j += 256) {
        int node = j / 24, c = j % 24;
        long gn = nb + node;
        float4 v = make_float4(0.f, 0.f, 0.f, 0.f);
        if (gn < N) v = ((const float4*)(xin + gn * 96))[c];
        *(float4*)&xs[node * 100 + c * 4] = v;
    }
    __syncthreads();
    int node = tid >> 3;
    int o0 = (tid & 7) * 12;
    float acc[12];
#pragma unroll
    for (int s = 0; s < 12; s++) acc[s] = 0.f;
    const float* xrow = &xs[node * 100];
#pragma unroll 4
    for (int c = 0; c < 24; c++) {
        float4 xv = *(const float4*)&xrow[c * 4];
        const float* w0 = &wt[(c * 4) * 96 + o0];
#pragma unroll
        for (int k = 0; k < 4; k++) {
            float xk = (k == 0) ? xv.x : (k == 1) ? xv.y : (k == 2) ? xv.z : xv.w;
            const float* wr = w0 + k * 96;
            float4 wa = *(const float4*)(wr);
            float4 wb4 = *(const float4*)(wr + 4);
            float4 wc = *(const float4*)(wr + 8);
            acc[0] += xk * wa.x;  acc[1] += xk * wa.y;  acc[2]  += xk * wa.z;  acc[3]  += xk * wa.w;
            acc[4] += xk * wb4.x; acc[5] += xk * wb4.y; acc[6]  += xk * wb4.z; acc[7]  += xk * wb4.w;
            acc[8] += xk * wc.x;  acc[9] += xk * wc.y;  acc[10] += xk * wc.z;  acc[11] += xk * wc.w;
        }
    }
    __syncthreads();
    ushort_t* sbuf = (ushort_t*)xs;
#pragma unroll
    for (int s = 0; s < 12; s++) sbuf[node * 96 + o0 + s] = f2u(acc[s]);
    __syncthreads();
    for (int j = tid; j < 32 * 96; j += 256) {
        int nd = j / 96, o3 = j % 96;
        long gn = nb + nd;
        if (gn < N) {
            int blk = o3 >> 5, fo = o3 & 31;
            ushort_t v = sbuf[j];
            (blk == 0 ? Su : blk == 1 ? Sd : Sb)[gn * 32 + fo] = v;
        }
    }
}

// ================================================================ generic linear -> bf16 S arrays (layer 1)
__global__ void k_linear_b16(const void* __restrict__ xin, int xfi, int din, int dout, long N,
                             const void* __restrict__ wu, const void* __restrict__ wd,
                             const void* __restrict__ wb, int wfi,
                             const int* __restrict__ flags, int uselds,
                             ushort_t* __restrict__ Su, ushort_t* __restrict__ Sd,
                             ushort_t* __restrict__ Sb) {
    __shared__ float smem[12288];
    int xbf = (xfi >= 0) ? flags[xfi] : 0;
    int ubf = flags[wfi], dbf = flags[wfi + 1], bbf = flags[wfi + 2];
    float* su = smem;
    float* sd = smem + (long)din * dout;
    float* sb = smem + 2l * din * dout;
    if (uselds) {
        for (int j = threadIdx.x; j < din * dout; j += 256) {
            int o = j % dout, i = j / dout;
            su[j] = ldf(wu, (long)o * din + i, ubf);
            sd[j] = ldf(wd, (long)o * din + i, dbf);
            sb[j] = ldf(wb, (long)o * din + i, bbf);
        }
        __syncthreads();
    }
    long idx = (long)blockIdx.x * blockDim.x + threadIdx.x;
    long node = idx / dout;
    int o = (int)(idx % dout);
    if (node >= N) return;
    float au = 0.f, ad = 0.f, ab = 0.f;
    long xb = node * din;
    if (uselds) {
        for (int i = 0; i < din; i++) {
            float xv = ldf(xin, xb + i, xbf);
            au += xv * su[i * dout + o];
            ad += xv * sd[i * dout + o];
            ab += xv * sb[i * dout + o];
        }
    } else {
        for (int i = 0; i < din; i++) {
            float xv = ldf(xin, xb + i, xbf);
            au += xv * ldf(wu, (long)o * din + i, ubf);
            ad += xv * ldf(wd, (long)o * din + i, dbf);
            ab += xv * ldf(wb, (long)o * din + i, bbf);
        }
    }
    Su[node * dout + o] = f2u(au);
    Sd[node * dout + o] = f2u(ad);
    Sb[node * dout + o] = f2u(ab);
}

// ================================================================ fallback (round-4 proven) kernels
__global__ void k_linear(const void* __restrict__ xin, int xfi, int din, int dout, int rs, long N,
                         const void* __restrict__ wu, const void* __restrict__ wd,
                         const void* __restrict__ wb, int wfi,
                         const int* __restrict__ flags, int uselds,
                         float* __restrict__ A, float* __restrict__ B, float* __restrict__ C) {
    __shared__ float smem[12288];
    int xbf = (xfi >= 0) ? flags[xfi] : 0;
    int ubf = flags[wfi], dbf = flags[wfi + 1], bbf = flags[wfi + 2];
    float* su = smem;
    float* sd = smem + (long)din * dout;
    float* sb = smem + 2l * din * dout;
    if (uselds) {
        for (int j = threadIdx.x; j < din * dout; j += 256) {
            int o = j % dout, i = j / dout;
            su[j] = ldf(wu, (long)o * din + i, ubf);
            sd[j] = ldf(wd, (long)o * din + i, dbf);
            sb[j] = ldf(wb, (long)o * din + i, bbf);
        }
        __syncthreads();
    }
    long idx = (long)blockIdx.x * blockDim.x + threadIdx.x;
    long node = idx / dout;
    int o = (int)(idx % dout);
    if (node >= N) return;
    float au = 0.f, ad = 0.f, ab = 0.f;
    long xb = node * din;
    if (uselds) {
        for (int i = 0; i < din; i++) {
            float xv = ldf(xin, xb + i, xbf);
            au += xv * su[i * dout + o];
            ad += xv * sd[i * dout + o];
            ab += xv * sb[i * dout + o];
        }
    } else {
        for (int i = 0; i < din; i++) {
            float xv = ldf(xin, xb + i, xbf);
            au += xv * ldf(wu, (long)o * din + i, ubf);
            ad += xv * ldf(wd, (long)o * din + i, dbf);
            ab += xv * ldf(wb, (long)o * din + i, bbf);
        }
    }
    A[node * rs + o] = au;
    B[node * rs + o] = ad;
    C[node * rs + o] = ab;
}

__global__ void k_deg(const int* __restrict__ ei, long E, const int* __restrict__ flags,
                      float* __restrict__ degc, float* __restrict__ degr) {
    long e = (long)blockIdx.x * blockDim.x + threadIdx.x;
    if (e < E) {
        int is64 = flags[16];
        atomicAdd(&degc[lde(ei, 1, e, E, is64)], 1.0f);
        atomicAdd(&degr[lde(ei, 0, e, E, is64)], 1.0f);
    }
}

__global__ void k_inv(float* __restrict__ a, long n) {
    long i = (long)blockIdx.x * blockDim.x + threadIdx.x;
    if (i < n) { float v = a[i]; a[i] = (v > 0.0f) ? 1.0f / v : 0.0f; }
}

__global__ void k_scatter(const int* __restrict__ ei, long E, int F,
                          const void* __restrict__ ewu, const void* __restrict__ ewd,
                          int fu, int fd, const int* __restrict__ flags,
                          const float* __restrict__ degci, const float* __restrict__ degri,
                          const float* __restrict__ A, const float* __restrict__ B,
                          float* __restrict__ U, float* __restrict__ D) {
    long idx = (long)blockIdx.x * blockDim.x + threadIdx.x;
    long tot = E * 2 * F;
    if (idx >= tot) return;
    int is64 = flags[16];
    long e = idx / (2 * F);
    int rem = (int)(idx - e * 2 * F);
    int dir = rem >= F;
    int f = rem - dir * F;
    int r = lde(ei, 0, e, E, is64), c = lde(ei, 1, e, E, is64);
    if (!dir) {
        float w = degci[c] * ldf(ewu, e, flags[fu]);
        atomicAdd(&U[(long)c * F + f], w * A[(long)r * F + f]);
    } else {
        float w = degri[r] * ldf(ewd, e, flags[fd]);
        atomicAdd(&D[(long)r * F + f], w * B[(long)c * F + f]);
    }
}

__global__ void k_finalize(const float* __restrict__ U, const float* __restrict__ D,
                           const float* __restrict__ C, int F, long N,
                           float* __restrict__ out) {
    long t = (long)blockIdx.x * blockDim.x + threadIdx.x;
    long n = t >> 6;
    if (n >= N) return;
    int lane = (int)(t & 63);
    int cat = 3 * F;
    float ss = 0.f;
    for (int j = lane; j < cat; j += 64) {
        float v = (j < F) ? U[n * F + j] : (j < 2 * F) ? D[n * F + j - F] : C[n * F + j - 2 * F];
        ss += v * v;
    }
#pragma unroll
    for (int m = 1; m < 64; m <<= 1) ss += __shfl_xor(ss, m, 64);
    float inv = 1.0f / fmaxf(sqrtf(ss), 1e-12f);
    for (int j = lane; j < cat; j += 64) {
        float v = (j < F) ? U[n * F + j] : (j < 2 * F) ? D[n * F + j - F] : C[n * F + j - 2 * F];
        float a = v * inv;
        a = (a >= 0.0f) ? a : 0.1f * a;
        out[n * cat + j] = a;
    }
}

__global__ void k_mean(const void* e1u, const void* e2u, const void* e3u,
                       const void* e1d, const void* e2d, const void* e3d,
                       const int* __restrict__ flags, long E,
                       float* __restrict__ mu, float* __restrict__ md) {
    long e = (long)blockIdx.x * blockDim.x + threadIdx.x;
    if (e >= E) return;
    float su = ldf(e1u, e, flags[4]) + ldf(e2u, e, flags[9]) + ldf(e3u, e, flags[14]);
    float sd = ldf(e1d, e, flags[5]) + ldf(e2d, e, flags[10]) + ldf(e3d, e, flags[15]);
    mu[e] = su / 3.0f;
    md[e] = sd / 3.0f;
}

extern "C" void kernel_launch(void* const* d_in, const int* in_sizes, int n_in,
                              void* d_out, int out_size, void* d_ws, size_t ws_size,
                              hipStream_t stream) {
    const int* ei = (const int*)d_in[1];
    const void* w_up[3]   = {d_in[2], d_in[7],  d_in[12]};
    const void* w_down[3] = {d_in[3], d_in[8],  d_in[13]};
    const void* w_bias[3] = {d_in[4], d_in[9],  d_in[14]};
    const void* ew_up[3]  = {d_in[5], d_in[10], d_in[15]};
    const void* ew_down[3]= {d_in[6], d_in[11], d_in[16]};

    // ---- derive true sizes from in_sizes
    long E = in_sizes[5];
    if (E <= 0) E = 1600000;
    int HID = (int)(sqrt((double)in_sizes[7] / 3.0) + 0.5);
    if (HID <= 0 || (long)3 * HID * HID != (long)in_sizes[7]) HID = 32;
    int DIN = in_sizes[2] / HID;
    if (DIN <= 0) DIN = 8;
    long N = (long)in_sizes[0] / DIN;
    if (N <= 0) N = 50000;
    int EMB = in_sizes[12] / (3 * HID);
    if (EMB <= 0) EMB = 32;
    int Fm = HID > EMB ? HID : EMB;
    int NB = (int)((N + 255) >> BSH);

    // ---- outputs: fp32, concatenated (h, mean_up, mean_down)
    float* out_h  = (float*)d_out;
    float* out_mu = out_h + N * 3l * EMB;
    float* out_md = out_mu + E;

    const int TB = 256;
    int lds1  = (3l * DIN * HID <= 12288) ? 1 : 0;
    int lds12 = (3l * (3 * HID) * HID <= 12288) ? 1 : 0;
    int lds3  = (3l * (3 * HID) * EMB <= 12288) ? 1 : 0;
    dim3 linG1((unsigned)((N * HID + TB - 1) / TB));
    dim3 linG3((unsigned)((N * EMB + TB - 1) / TB));
    dim3 lin96G((unsigned)((N + 31) / 32));
    dim3 finG((unsigned)((N * 64 + TB - 1) / TB));
    dim3 edgeG((unsigned)((E + TB - 1) / TB));
    dim3 chunkG1((unsigned)((E + CH - 1) / CH));
    dim3 chunkG2((unsigned)((E + CH - 1) / CH), 2);

    // ---- fast-path workspace layout
    int* flags = (int*)d_ws;                       // 64
    int* bc    = flags + 64;                       // 2*NBMAX
    int* bb    = bc + 2 * NBMAX;                   // 2*(NBMAX+1)
    int* gcur  = bb + 2 * (NBMAX + 1);             // 2*NBMAX
    int* off_c = gcur + 2 * NBMAX;                 // N+1
    int* off_r = off_c + (N + 1);                  // N+1
    long li = (long)(off_r + (N + 1) - (int*)d_ws);
    li = (li + 3) & ~3l;
    int* list_c = (int*)d_ws + li;                 // E (src only - gather hot path)
    int* list_r = list_c + E;                      // E
    int* eidx_c = list_r + E;                      // E (eids - wcsr only)
    int* eidx_r = eidx_c + E;                      // E
    int* R = eidx_r + E;
    // phase 1 (bucket build): bse 2E int2 = 4E ints (record: src|local<<24, eid)
    int2* bse = (int2*)R;
    // phase 2+: wc6 persists; ebc6 transient; S/U overlay ebc6
    ushort_t* wc6  = (ushort_t*)R;                 // 6E ushorts = 3E ints
    ushort_t* ebc6 = (ushort_t*)(R + 3 * E);       // 6E ushorts = 3E ints
    ushort_t* Su = ebc6;                           // N*Fm (after wcsr, ebc6 dead)
    ushort_t* Sd = Su + N * Fm;
    ushort_t* Sb = Sd + N * Fm;
    float* U = (float*)(Sb + N * Fm);              // N*Fm fp32 (int-aligned: 3*N*Fm even)
    long zInts = (3l * N * Fm + 1) / 2 + N * Fm;   // S arrays + U
    long Rints = 4l * E;                           // phase 1
    long p2 = 3l * E + ((zInts > 3l * E) ? zInts : 3l * E);
    if (p2 > Rints) Rints = p2;
    size_t need = (size_t)((li + 4l * E + Rints) * 4l + 256);

    bool fast = (HID == 32 && EMB == 32) && (NB <= NBMAX) &&
                (ws_size == 0 || ws_size >= need);

    // ---- dtype detection (both paths)
    DetectArgs da;
    da.p[0] = d_in[0]; da.n[0] = in_sizes[0];
    for (int L = 0; L < 3; L++) {
        da.p[1 + 5 * L] = w_up[L];    da.n[1 + 5 * L] = in_sizes[2 + 5 * L];
        da.p[2 + 5 * L] = w_down[L];  da.n[2 + 5 * L] = in_sizes[3 + 5 * L];
        da.p[3 + 5 * L] = w_bias[L];  da.n[3 + 5 * L] = in_sizes[4 + 5 * L];
        da.p[4 + 5 * L] = ew_up[L];   da.n[4 + 5 * L] = in_sizes[5 + 5 * L];
        da.p[5 + 5 * L] = ew_down[L]; da.n[5 + 5 * L] = in_sizes[6 + 5 * L];
    }
    da.ei = ei; da.E = E; da.flags = flags;
    k_detect<<<17, TB, 0, stream>>>(da);

    if (fast) {
        // ---- bucketed CSR build (once; reused 3 layers x 2 directions)
        hipMemsetAsync(bc, 0, 2 * NBMAX * sizeof(int), stream);
        kb_count<<<chunkG1, TB, 0, stream>>>(ei, E, flags, NB, bc);
        kb_scan<<<1, 512, 0, stream>>>(bc, bb, gcur, NB);
        kb_fill<<<chunkG2, TB, 0, stream>>>(ei, E, flags, NB, gcur, bse);
        kb_csr<<<dim3((unsigned)NB, 2), TB, 0, stream>>>(bb, bse, E, NB, N,
                                                         off_c, off_r, list_c, list_r,
                                                         eidx_c, eidx_r);

        // ---- cast all 6 ew arrays + write mean outputs, one pass
        k_ewcast6<<<edgeG, TB, 0, stream>>>(ew_up[0], ew_up[1], ew_up[2],
                                            ew_down[0], ew_down[1], ew_down[2],
                                            flags, E, ebc6, out_mu, out_md);
        // ---- CSR-ordered bf16 weights, 3 layers x 2 dirs
        for (int L = 0; L < 3; L++) {
            k_wcsr<<<edgeG, TB, 0, stream>>>(eidx_c, E, ebc6 + (long)(2 * L) * E,
                                             wc6 + (long)(2 * L) * E);
            k_wcsr<<<edgeG, TB, 0, stream>>>(eidx_r, E, ebc6 + (long)(2 * L + 1) * E,
                                             wc6 + (long)(2 * L + 1) * E);
        }

        float* H = (float*)d_out;   // intermediate 96-wide activations live in d_out

        // ---- layer 1 (din=DIN, generic, bf16 S output)
        k_linear_b16<<<linG1, TB, 0, stream>>>(d_in[0], 0, DIN, HID, N,
                                               w_up[0], w_down[0], w_bias[0], 1, flags, lds1,
                                               Su, Sd, Sb);
        k_gather_up<<<finG, TB, 0, stream>>>(off_c, list_c, wc6, Su, N, U);
        k_gather_downfin<<<finG, TB, 0, stream>>>(off_r, list_r, wc6 + E, Sd, Sb, U, N, H);
        // ---- layer 2 (din=96 specialized)
        k_lin96<<<lin96G, TB, 0, stream>>>(H, N, w_up[1], w_down[1], w_bias[1], 6, flags,
                                           Su, Sd, Sb);
        k_gather_up<<<finG, TB, 0, stream>>>(off_c, list_c, wc6 + 2l * E, Su, N, U);
        k_gather_downfin<<<finG, TB, 0, stream>>>(off_r, list_r, wc6 + 3l * E, Sd, Sb, U, N, H);
        // ---- layer 3 -> final fp32 output
        k_lin96<<<lin96G, TB, 0, stream>>>(H, N, w_up[2], w_down[2], w_bias[2], 11, flags,
                                           Su, Sd, Sb);
        k_gather_up<<<finG, TB, 0, stream>>>(off_c, list_c, wc6 + 4l * E, Su, N, U);
        k_gather_downfin<<<finG, TB, 0, stream>>>(off_r, list_r, wc6 + 5l * E, Sd, Sb, U, N, out_h);
    } else {
        // ---- fallback: round-4 proven atomic-scatter path
        float* degci = (float*)(flags + 64);
        float* degri = degci + N;
        float* fA = degri + N;
        float* fB = fA + N * Fm;
        float* fC = fB + N * Fm;
        float* fU = fC + N * Fm;
        float* fD = fU + N * Fm;
        float* fH = fD + N * Fm;
        dim3 scatG12((unsigned)((E * 2 * HID + TB - 1) / TB));
        dim3 scatG3((unsigned)((E * 2 * EMB + TB - 1) / TB));

        hipMemsetAsync(degci, 0, 2 * N * sizeof(float), stream);
        k_deg<<<edgeG, TB, 0, stream>>>(ei, E, flags, degci, degri);
        k_inv<<<dim3((unsigned)((2 * N + TB - 1) / TB)), TB, 0, stream>>>(degci, 2 * N);

        k_linear<<<linG1, TB, 0, stream>>>(d_in[0], 0, DIN, HID, HID, N,
                                           w_up[0], w_down[0], w_bias[0], 1, flags, lds1, fA, fB, fC);
        hipMemsetAsync(fU, 0, 2l * N * Fm * sizeof(float), stream);
        k_scatter<<<scatG12, TB, 0, stream>>>(ei, E, HID, ew_up[0], ew_down[0], 4, 5, flags,
                                              degci, degri, fA, fB, fU, fD);
        k_finalize<<<finG, TB, 0, stream>>>(fU, fD, fC, HID, N, fH);

        k_linear<<<linG1, TB, 0, stream>>>(fH, -1, 3 * HID, HID, HID, N,
                                           w_up[1], w_down[1], w_bias[1], 6, flags, lds12, fA, fB, fC);
        hipMemsetAsync(fU, 0, 2l * N * Fm * sizeof(float), stream);
        k_scatter<<<scatG12, TB, 0, stream>>>(ei, E, HID, ew_up[1], ew_down[1], 9, 10, flags,
                                              degci, degri, fA, fB, fU, fD);
        k_finalize<<<finG, TB, 0, stream>>>(fU, fD, fC, HID, N, fH);

        k_linear<<<linG3, TB, 0, stream>>>(fH, -1, 3 * HID, EMB, EMB, N,
                                           w_up[2], w_down[2], w_bias[2], 11, flags, lds3, fA, fB, fC);
        hipMemsetAsync(fU, 0, 2l * N * Fm * sizeof(float), stream);
        k_scatter<<<scatG3, TB, 0, stream>>>(ei, E, EMB, ew_up[2], ew_down[2], 14, 15, flags,
                                             degci, degri, fA, fB, fU, fD);
        k_finalize<<<finG, TB, 0, stream>>>(fU, fD, fC, EMB, N, out_h);

        k_mean<<<edgeG, TB, 0, stream>>>(ew_up[0], ew_up[1], ew_up[2],
                                         ew_down[0], ew_down[1], ew_down[2],
                                         flags, E, out_mu, out_md);
    }
}

// Round 12
// 610.106 us; speedup vs baseline: 3.2856x; 1.0582x over previous
//
#include <hip/hip_runtime.h>
#include <hip/hip_bf16.h>
#include <math.h>

typedef __hip_bfloat16 bf16;
typedef unsigned short ushort_t;

#define NBMAX 1024   // max buckets (N <= 262144 for fast path; also guarantees src < 2^24)
#define BSH 8        // 256 nodes per bucket
#define CH 4096      // edges per kb_fill chunk
#define CSRCAP 6144  // LDS staging capacity per half-bucket in kb_csr

// flags[0..15]: 1 if float-array slot is bf16, 0 if fp32.
//   slot 0:x | per layer L(0..2): 1+5L:w_up 2+5L:w_down 3+5L:w_bias 4+5L:ew_up 5+5L:ew_down
// flags[16]: 1 if edge_index is int64 (little-endian, values < 2^31), else int32.
__device__ __forceinline__ float ldf(const void* p, long i, int isbf) {
    return isbf ? __bfloat162float(((const bf16*)p)[i]) : ((const float*)p)[i];
}
__device__ __forceinline__ int lde(const int* ei, int half, long e, long E, int is64) {
    long idx = half ? (E + e) : e;
    return is64 ? ei[idx * 2] : ei[idx];
}
__device__ __forceinline__ float u2f(ushort_t u) {
    union { unsigned int i; float f; } v; v.i = ((unsigned)u) << 16; return v.f;
}
__device__ __forceinline__ ushort_t f2u(float f) {
    bf16 h = __float2bfloat16(f);
    return *reinterpret_cast<ushort_t*>(&h);
}
__device__ __forceinline__ float lo2f(unsigned sp) {
    union { unsigned i; float f; } v; v.i = sp << 16; return v.f;
}
__device__ __forceinline__ float hi2f(unsigned sp) {
    union { unsigned i; float f; } v; v.i = sp & 0xffff0000u; return v.f;
}

// ---------------------------------------------------------------- dtype detection
struct DetectArgs {
    const void* p[16];
    long n[16];
    const int* ei;
    long E;
    int* flags;
};

__global__ void k_detect(DetectArgs a) {
    __shared__ int cnt;
    if (threadIdx.x == 0) cnt = 0;
    __syncthreads();
    int b = blockIdx.x;
    int bad = 0;
    if (b < 16) {
        const bf16* p = (const bf16*)a.p[b];
        long m = a.n[b] < 4096 ? a.n[b] : 4096;
        for (long i = threadIdx.x; i < m; i += 256) {
            float v = __bfloat162float(p[i]);
            if (!(fabsf(v) < 100.0f)) bad++;
        }
        atomicAdd(&cnt, bad);
        __syncthreads();
        if (threadIdx.x == 0) a.flags[b] = ((long)cnt * 16 < m) ? 1 : 0;
    } else {
        long m = a.E / 2 < 4096 ? a.E / 2 : 4096;
        for (long i = threadIdx.x; i < m; i += 256) {
            if (a.ei[2 * i + 1] != 0) bad++;
        }
        atomicAdd(&cnt, bad);
        __syncthreads();
        if (threadIdx.x == 0) a.flags[16] = (cnt < (int)(m / 16) + 1) ? 1 : 0;
    }
}

// ================================================================ bucketed CSR build
// dir 0: dst=col (up-list), dir 1: dst=row (down-list). bucket = dst>>8.

// Both directions per chunk, one edge-read pass.
__global__ void kb_count(const int* __restrict__ ei, long E, const int* __restrict__ flags,
                         int NB, int* __restrict__ bc) {
    __shared__ int h0[NBMAX], h1[NBMAX];
    for (int i = threadIdx.x; i < NB; i += 256) { h0[i] = 0; h1[i] = 0; }
    __syncthreads();
    int is64 = flags[16];
    long base = (long)blockIdx.x * CH;
#pragma unroll
    for (int i = 0; i < CH / 256; i++) {
        long e = base + i * 256 + threadIdx.x;
        if (e < E) {
            int c = lde(ei, 1, e, E, is64);   // dir0 dst=col
            int r = lde(ei, 0, e, E, is64);   // dir1 dst=row
            atomicAdd(&h0[c >> BSH], 1);
            atomicAdd(&h1[r >> BSH], 1);
        }
    }
    __syncthreads();
    for (int i = threadIdx.x; i < NB; i += 256) {
        if (h0[i]) atomicAdd(&bc[i], h0[i]);
        if (h1[i]) atomicAdd(&bc[NBMAX + i], h1[i]);
    }
}

__global__ void kb_scan(const int* __restrict__ bc, int* __restrict__ bb,
                        int* __restrict__ gcur, int NB) {
    if (threadIdx.x < 2) {
        int dir = threadIdx.x;
        int acc = 0;
        for (int i = 0; i < NB; i++) { bb[dir * (NBMAX + 1) + i] = acc; acc += bc[dir * NBMAX + i]; }
        bb[dir * (NBMAX + 1) + NB] = acc;
    }
    __syncthreads();
    for (int i = threadIdx.x; i < 2 * NBMAX; i += blockDim.x) {
        int d = i / NBMAX, b = i - d * NBMAX;
        gcur[i] = bb[d * (NBMAX + 1) + (b < NB ? b : NB)];
    }
}

// Per-block counting-sort of a 4096-edge chunk by bucket, bucket-contiguous
// global append. Record: (src | local<<24, eid) — no separate dst array.
__global__ void kb_fill(const int* __restrict__ ei, long E, const int* __restrict__ flags,
                        int NB, int* __restrict__ gcur, int2* __restrict__ bse) {
    __shared__ int2 ssE[CH];            // 32 KB sorted (src|local<<24, eid)
    __shared__ ushort_t sbkt[CH];       // 8 KB bucket id per staged entry
    __shared__ int h[NBMAX], lofs[NBMAX], cur[NBMAX], gb[NBMAX];  // 16 KB
    __shared__ int sc[256];
    int tid = threadIdx.x;
    int dir = blockIdx.y;
    int is64 = flags[16];
    for (int i = tid; i < NBMAX; i += 256) { h[i] = 0; cur[i] = 0; }
    __syncthreads();
    long base = (long)blockIdx.x * CH;
    int myd[CH / 256], mys[CH / 256], mye[CH / 256];
#pragma unroll
    for (int i = 0; i < CH / 256; i++) {
        long e = base + i * 256 + tid;
        myd[i] = -1;
        if (e < E) {
            myd[i] = lde(ei, dir ? 0 : 1, e, E, is64);
            mys[i] = lde(ei, dir ? 1 : 0, e, E, is64);
            mye[i] = (int)e;
            atomicAdd(&h[myd[i] >> BSH], 1);
        }
    }
    __syncthreads();
    int i0 = tid * 4;
    int a0 = h[i0], a1 = h[i0 + 1], a2 = h[i0 + 2], a3 = h[i0 + 3];
    int ts = a0 + a1 + a2 + a3;
    sc[tid] = ts;
    __syncthreads();
    for (int d = 1; d < 256; d <<= 1) {
        int t = (tid >= d) ? sc[tid - d] : 0;
        __syncthreads();
        sc[tid] += t;
        __syncthreads();
    }
    int eb = sc[tid] - ts;
    lofs[i0] = eb; lofs[i0 + 1] = eb + a0; lofs[i0 + 2] = eb + a0 + a1; lofs[i0 + 3] = eb + a0 + a1 + a2;
    __syncthreads();
#pragma unroll
    for (int i = 0; i < CH / 256; i++) {
        if (myd[i] >= 0) {
            int b = myd[i] >> BSH;
            int r = atomicAdd(&cur[b], 1);
            int p = lofs[b] + r;
            ssE[p] = make_int2(mys[i] | ((myd[i] & 255) << 24), mye[i]);
            sbkt[p] = (ushort_t)b;
        }
    }
    __syncthreads();
    for (int b = tid; b < NB; b += 256) {
        int c = h[b];
        gb[b] = c ? atomicAdd(&gcur[dir * NBMAX + b], c) : 0;
    }
    __syncthreads();
    long rem = E - base;
    int nvalid = rem >= CH ? CH : (rem > 0 ? (int)rem : 0);
    int2* os = bse + (long)dir * E;
    for (int s = tid; s < nvalid; s += 256) {
        int b = sbkt[s];
        long p = (long)gb[b] + (s - lofs[b]);
        os[p] = ssE[s];
    }
}

// Per-(bucket,dir) counting sort into final per-node CSR. Sorted bucket staged
// in LDS (two half-passes over locals <128/>=128), then written out coalesced
// -> no random global writes at all. Guarded fallback if a half exceeds CSRCAP.
__global__ void kb_csr(const int* __restrict__ bb, const int2* __restrict__ bse,
                       long E, int NB, long N,
                       int* __restrict__ off_c, int* __restrict__ off_r,
                       int* __restrict__ list_c, int* __restrict__ list_r,
                       int* __restrict__ eidx_c, int* __restrict__ eidx_r) {
    __shared__ int2 sbuf[CSRCAP];       // 48 KB
    __shared__ int h[256], lofs[256], cur[256], sc[256];
    int tid = threadIdx.x;
    int b = blockIdx.x, dir = blockIdx.y;
    int base = bb[dir * (NBMAX + 1) + b];
    int cnt  = bb[dir * (NBMAX + 1) + b + 1] - base;
    const int2* bs = bse + (long)dir * E;
    int* off  = dir ? off_r : off_c;
    int* list = dir ? list_r : list_c;
    int* eidx = dir ? eidx_r : eidx_c;
    h[tid] = 0; cur[tid] = 0;
    __syncthreads();
    int nb0 = b << BSH;
    for (int s = tid; s < cnt; s += 256)
        atomicAdd(&h[(unsigned)bs[base + s].x >> 24], 1);
    __syncthreads();
    int v = h[tid];
    sc[tid] = v;
    __syncthreads();
    for (int d = 1; d < 256; d <<= 1) {
        int t = (tid >= d) ? sc[tid - d] : 0;
        __syncthreads();
        sc[tid] += t;
        __syncthreads();
    }
    lofs[tid] = sc[tid] - v;
    __syncthreads();
    long n = (long)nb0 + tid;
    if (n < N) off[n] = base + lofs[tid];
    if (b == 0 && tid == 0) off[N] = (int)E;
    int mid = lofs[128];
    int cnt1 = cnt - mid;
    if (mid <= CSRCAP && cnt1 <= CSRCAP) {
        for (int s = tid; s < cnt; s += 256) {
            int2 se = bs[base + s];
            int local = (unsigned)se.x >> 24;
            if (local < 128) {
                int r = atomicAdd(&cur[local], 1);
                sbuf[lofs[local] + r] = se;
            }
        }
        __syncthreads();
        for (int s = tid; s < mid; s += 256) {
            int2 se = sbuf[s];
            list[base + s] = se.x & 0xFFFFFF;
            eidx[base + s] = se.y;
        }
        __syncthreads();
        for (int s = tid; s < cnt; s += 256) {
            int2 se = bs[base + s];
            int local = (unsigned)se.x >> 24;
            if (local >= 128) {
                int r = atomicAdd(&cur[local], 1);
                sbuf[lofs[local] - mid + r] = se;
            }
        }
        __syncthreads();
        for (int s = tid; s < cnt1; s += 256) {
            int2 se = sbuf[s];
            list[base + mid + s] = se.x & 0xFFFFFF;
            eidx[base + mid + s] = se.y;
        }
    } else {
        for (int s = tid; s < cnt; s += 256) {
            int2 se = bs[base + s];
            int local = (unsigned)se.x >> 24;
            int r = atomicAdd(&cur[local], 1);
            long p = (long)base + lofs[local] + r;
            list[p] = se.x & 0xFFFFFF;
            eidx[p] = se.y;
        }
    }
}

// ================================================================ ew: cast all 6 arrays + means, one pass
__global__ void k_ewcast6(const void* __restrict__ e1u, const void* __restrict__ e2u,
                          const void* __restrict__ e3u, const void* __restrict__ e1d,
                          const void* __restrict__ e2d, const void* __restrict__ e3d,
                          const int* __restrict__ flags, long E,
                          ushort_t* __restrict__ ebc6,
                          float* __restrict__ mu, float* __restrict__ md) {
    long e = (long)blockIdx.x * blockDim.x + threadIdx.x;
    if (e >= E) return;
    float v1u = ldf(e1u, e, flags[4]),  v2u = ldf(e2u, e, flags[9]),  v3u = ldf(e3u, e, flags[14]);
    float v1d = ldf(e1d, e, flags[5]),  v2d = ldf(e2d, e, flags[10]), v3d = ldf(e3d, e, flags[15]);
    ebc6[0 * E + e] = f2u(v1u); ebc6[1 * E + e] = f2u(v1d);
    ebc6[2 * E + e] = f2u(v2u); ebc6[3 * E + e] = f2u(v2d);
    ebc6[4 * E + e] = f2u(v3u); ebc6[5 * E + e] = f2u(v3d);
    mu[e] = (v1u + v2u + v3u) / 3.0f;
    md[e] = (v1d + v2d + v3d) / 3.0f;
}

// All 6 CSR-ordered weight tables in one launch: y = L*2+dir.
// Random read confined to one 3.2MB L2-resident table per (block,y).
__global__ void k_wcsr6(const int* __restrict__ eidx_c, const int* __restrict__ eidx_r,
                        long E, const ushort_t* __restrict__ ebc6,
                        ushort_t* __restrict__ wc6) {
    int y = blockIdx.y;
    int dir = y & 1;
    const int* eidx = dir ? eidx_r : eidx_c;
    const ushort_t* tab = ebc6 + (long)y * E;
    ushort_t* wout = wc6 + (long)y * E;
    long j = (long)blockIdx.x * blockDim.x + threadIdx.x;
    if (j < E) wout[j] = tab[eidx[j]];
}

// ================================================================ phase-split gather (F==32)
// 4 edge parities per wave (sub=lane>>4), 16 feature-pair lanes (fp=lane&15).
// Each dispatch's random hot set is ONE 3.2MB bf16 table -> per-XCD L2 resident.

// Phase A: up-direction (col-CSR over Su) -> U[n][32] fp32 (deg-normalized).
__global__ void k_gather_up(const int* __restrict__ off_c, const int* __restrict__ list_c,
                            const ushort_t* __restrict__ wcu, const ushort_t* __restrict__ Su,
                            long N, float* __restrict__ U) {
    long t = (long)blockIdx.x * blockDim.x + threadIdx.x;
    long n = t >> 6;
    if (n >= N) return;
    int lane = (int)(t & 63);
    int sub = lane >> 4;
    int fp  = lane & 15;
    int j0 = off_c[n], j1 = off_c[n + 1];
    float ax = 0.f, ay = 0.f;
    int j = j0 + sub;
    for (; j + 4 < j1; j += 8) {          // 2 edges in flight per lane
        int s0 = list_c[j], s1 = list_c[j + 4];
        float w0 = u2f(wcu[j]), w1 = u2f(wcu[j + 4]);
        unsigned p0 = *(const unsigned*)&Su[((long)s0 << 5) + (fp << 1)];
        unsigned p1 = *(const unsigned*)&Su[((long)s1 << 5) + (fp << 1)];
        ax += w0 * lo2f(p0) + w1 * lo2f(p1);
        ay += w0 * hi2f(p0) + w1 * hi2f(p1);
    }
    if (j < j1) {
        int s0 = list_c[j];
        float w0 = u2f(wcu[j]);
        unsigned p0 = *(const unsigned*)&Su[((long)s0 << 5) + (fp << 1)];
        ax += w0 * lo2f(p0);
        ay += w0 * hi2f(p0);
    }
    ax += __shfl_xor(ax, 16, 64); ay += __shfl_xor(ay, 16, 64);
    ax += __shfl_xor(ax, 32, 64); ay += __shfl_xor(ay, 32, 64);
    if (sub == 0) {
        int deg = j1 - j0;
        float dinv = (deg > 0) ? 1.0f / (float)deg : 0.f;
        *(float2*)&U[(n << 5) + (fp << 1)] = make_float2(ax * dinv, ay * dinv);
    }
}

// Phase B: down-direction (row-CSR over Sd) + U + Sb -> normalize+leaky -> out.
__global__ void k_gather_downfin(const int* __restrict__ off_r, const int* __restrict__ list_r,
                                 const ushort_t* __restrict__ wcd, const ushort_t* __restrict__ Sd,
                                 const ushort_t* __restrict__ Sb, const float* __restrict__ U,
                                 long N, float* __restrict__ out) {
    long t = (long)blockIdx.x * blockDim.x + threadIdx.x;
    long n = t >> 6;
    if (n >= N) return;
    int lane = (int)(t & 63);
    int sub = lane >> 4;
    int fp  = lane & 15;
    int j0 = off_r[n], j1 = off_r[n + 1];
    float ax = 0.f, ay = 0.f;
    int j = j0 + sub;
    for (; j + 4 < j1; j += 8) {
        int s0 = list_r[j], s1 = list_r[j + 4];
        float w0 = u2f(wcd[j]), w1 = u2f(wcd[j + 4]);
        unsigned p0 = *(const unsigned*)&Sd[((long)s0 << 5) + (fp << 1)];
        unsigned p1 = *(const unsigned*)&Sd[((long)s1 << 5) + (fp << 1)];
        ax += w0 * lo2f(p0) + w1 * lo2f(p1);
        ay += w0 * hi2f(p0) + w1 * hi2f(p1);
    }
    if (j < j1) {
        int s0 = list_r[j];
        float w0 = u2f(wcd[j]);
        unsigned p0 = *(const unsigned*)&Sd[((long)s0 << 5) + (fp << 1)];
        ax += w0 * lo2f(p0);
        ay += w0 * hi2f(p0);
    }
    ax += __shfl_xor(ax, 16, 64); ay += __shfl_xor(ay, 16, 64);
    ax += __shfl_xor(ax, 32, 64); ay += __shfl_xor(ay, 32, 64);
    float vx = 0.f, vy = 0.f, ux = 0.f, uy = 0.f, cx = 0.f, cy = 0.f;
    float ss = 0.f;
    if (sub == 0) {
        int deg = j1 - j0;
        float dinv = (deg > 0) ? 1.0f / (float)deg : 0.f;
        vx = ax * dinv; vy = ay * dinv;
        float2 uv = *(const float2*)&U[(n << 5) + (fp << 1)];
        ux = uv.x; uy = uv.y;
        unsigned bp = *(const unsigned*)&Sb[(n << 5) + (fp << 1)];
        cx = lo2f(bp); cy = hi2f(bp);
        ss = vx * vx + vy * vy + ux * ux + uy * uy + cx * cx + cy * cy;
    }
#pragma unroll
    for (int m = 1; m < 64; m <<= 1) ss += __shfl_xor(ss, m, 64);
    float inv = 1.0f / fmaxf(sqrtf(ss), 1e-12f);
    if (sub == 0) {
        float a, b;
        a = ux * inv; a = (a >= 0.f) ? a : 0.1f * a;
        b = uy * inv; b = (b >= 0.f) ? b : 0.1f * b;
        *(float2*)&out[n * 96 + (fp << 1)] = make_float2(a, b);
        a = vx * inv; a = (a >= 0.f) ? a : 0.1f * a;
        b = vy * inv; b = (b >= 0.f) ? b : 0.1f * b;
        *(float2*)&out[n * 96 + 32 + (fp << 1)] = make_float2(a, b);
        a = cx * inv; a = (a >= 0.f) ? a : 0.1f * a;
        b = cy * inv; b = (b >= 0.f) ? b : 0.1f * b;
        *(float2*)&out[n * 96 + 64 + (fp << 1)] = make_float2(a, b);
    }
}

// ================================================================ specialized linear, din=96, dout=3x32 fused, bf16 out
// 64 nodes/block, 2 nodes/thread (node, node+32) x 12 outputs: weight LDS reads
// amortized over 2 nodes (was the LDS-BW bottleneck at 1 node/thread).
__global__ void k_lin96(const float* __restrict__ xin, long N,
                        const void* __restrict__ wu, const void* __restrict__ wd,
                        const void* __restrict__ wb, int wfi,
                        const int* __restrict__ flags,
                        ushort_t* __restrict__ Su, ushort_t* __restrict__ Sd,
                        ushort_t* __restrict__ Sb) {
    __shared__ float xs[64 * 100];   // 25.6 KB (reused as bf16 staging after compute)
    __shared__ float wt[96 * 96];    // 36.9 KB ; total 62.5 KB -> 2 blocks/CU
    int tid = threadIdx.x;
    int ubf = flags[wfi], dbf = flags[wfi + 1], bbf = flags[wfi + 2];
    for (int j = tid; j < 96 * 96; j += 256) {
        int o3 = j % 96, i = j / 96;
        float v;
        if (o3 < 32)      v = ldf(wu, (long)o3 * 96 + i, ubf);
        else if (o3 < 64) v = ldf(wd, (long)(o3 - 32) * 96 + i, dbf);
        else              v = ldf(wb, (long)(o3 - 64) * 96 + i, bbf);
        wt[j] = v;
    }
    long nb = (long)blockIdx.x * 64;
    for (int j = tid; j < 64 * 24; j += 256) {   // 1536 float4, coalesced
        int node = j / 24, c = j % 24;
        long gn = nb + node;
        float4 v = make_float4(0.f, 0.f, 0.f, 0.f);
        if (gn < N) v = ((const float4*)(xin + gn * 96))[c];
        *(float4*)&xs[node * 100 + c * 4] = v;
    }
    __syncthreads();
    int node0 = tid >> 3;            // 0..31
    int node1 = node0 + 32;          // 32..63
    int o0 = (tid & 7) * 12;
    float acc0[12], acc1[12];
#pragma unroll
    for (int s = 0; s < 12; s++) { acc0[s] = 0.f; acc1[s] = 0.f; }
    const float* xrow0 = &xs[node0 * 100];
    const float* xrow1 = &xs[node1 * 100];
#pragma unroll 4
    for (int c = 0; c < 24; c++) {
        float4 xv0 = *(const float4*)&xrow0[c * 4];
        float4 xv1 = *(const float4*)&xrow1[c * 4];
        const float* w0 = &wt[(c * 4) * 96 + o0];
#pragma unroll
        for (int k = 0; k < 4; k++) {
            float xk0 = (k == 0) ? xv0.x : (k == 1) ? xv0.y : (k == 2) ? xv0.z : xv0.w;
            float xk1 = (k == 0) ? xv1.x : (k == 1) ? xv1.y : (k == 2) ? xv1.z : xv1.w;
            const float* wr = w0 + k * 96;
            float4 wa = *(const float4*)(wr);
            float4 wb4 = *(const float4*)(wr + 4);
            float4 wc = *(const float4*)(wr + 8);
            acc0[0] += xk0 * wa.x;  acc0[1] += xk0 * wa.y;  acc0[2]  += xk0 * wa.z;  acc0[3]  += xk0 * wa.w;
            acc0[4] += xk0 * wb4.x; acc0[5] += xk0 * wb4.y; acc0[6]  += xk0 * wb4.z; acc0[7]  += xk0 * wb4.w;
            acc0[8] += xk0 * wc.x;  acc0[9] += xk0 * wc.y;  acc0[10] += xk0 * wc.z;  acc0[11] += xk0 * wc.w;
            acc1[0] += xk1 * wa.x;  acc1[1] += xk1 * wa.y;  acc1[2]  += xk1 * wa.z;  acc1[3]  += xk1 * wa.w;
            acc1[4] += xk1 * wb4.x; acc1[5] += xk1 * wb4.y; acc1[6]  += xk1 * wb4.z; acc1[7]  += xk1 * wb4.w;
            acc1[8] += xk1 * wc.x;  acc1[9] += xk1 * wc.y;  acc1[10] += xk1 * wc.z;  acc1[11] += xk1 * wc.w;
        }
    }
    __syncthreads();                       // everyone done reading xs
    ushort_t* sbuf = (ushort_t*)xs;        // 64*96 ushorts = 12 KB staging
#pragma unroll
    for (int s = 0; s < 12; s++) {
        sbuf[node0 * 96 + o0 + s] = f2u(acc0[s]);
        sbuf[node1 * 96 + o0 + s] = f2u(acc1[s]);
    }
    __syncthreads();
    for (int j = tid; j < 64 * 96; j += 256) {
        int nd = j / 96, o3 = j % 96;
        long gn = nb + nd;
        if (gn < N) {
            int blk = o3 >> 5, fo = o3 & 31;
            ushort_t v = sbuf[j];
            (blk == 0 ? Su : blk == 1 ? Sd : Sb)[gn * 32 + fo] = v;
        }
    }
}

// ================================================================ generic linear -> bf16 S arrays (layer 1)
__global__ void k_linear_b16(const void* __restrict__ xin, int xfi, int din, int dout, long N,
                             const void* __restrict__ wu, const void* __restrict__ wd,
                             const void* __restrict__ wb, int wfi,
                             const int* __restrict__ flags, int uselds,
                             ushort_t* __restrict__ Su, ushort_t* __restrict__ Sd,
                             ushort_t* __restrict__ Sb) {
    __shared__ float smem[12288];
    int xbf = (xfi >= 0) ? flags[xfi] : 0;
    int ubf = flags[wfi], dbf = flags[wfi + 1], bbf = flags[wfi + 2];
    float* su = smem;
    float* sd = smem + (long)din * dout;
    float* sb = smem + 2l * din * dout;
    if (uselds) {
        for (int j = threadIdx.x; j < din * dout; j += 256) {
            int o = j % dout, i = j / dout;
            su[j] = ldf(wu, (long)o * din + i, ubf);
            sd[j] = ldf(wd, (long)o * din + i, dbf);
            sb[j] = ldf(wb, (long)o * din + i, bbf);
        }
        __syncthreads();
    }
    long idx = (long)blockIdx.x * blockDim.x + threadIdx.x;
    long node = idx / dout;
    int o = (int)(idx % dout);
    if (node >= N) return;
    float au = 0.f, ad = 0.f, ab = 0.f;
    long xb = node * din;
    if (uselds) {
        for (int i = 0; i < din; i++) {
            float xv = ldf(xin, xb + i, xbf);
            au += xv * su[i * dout + o];
            ad += xv * sd[i * dout + o];
            ab += xv * sb[i * dout + o];
        }
    } else {
        for (int i = 0; i < din; i++) {
            float xv = ldf(xin, xb + i, xbf);
            au += xv * ldf(wu, (long)o * din + i, ubf);
            ad += xv * ldf(wd, (long)o * din + i, dbf);
            ab += xv * ldf(wb, (long)o * din + i, bbf);
        }
    }
    Su[node * dout + o] = f2u(au);
    Sd[node * dout + o] = f2u(ad);
    Sb[node * dout + o] = f2u(ab);
}

// ================================================================ fallback (round-4 proven) kernels
__global__ void k_linear(const void* __restrict__ xin, int xfi, int din, int dout, int rs, long N,
                         const void* __restrict__ wu, const void* __restrict__ wd,
                         const void* __restrict__ wb, int wfi,
                         const int* __restrict__ flags, int uselds,
                         float* __restrict__ A, float* __restrict__ B, float* __restrict__ C) {
    __shared__ float smem[12288];
    int xbf = (xfi >= 0) ? flags[xfi] : 0;
    int ubf = flags[wfi], dbf = flags[wfi + 1], bbf = flags[wfi + 2];
    float* su = smem;
    float* sd = smem + (long)din * dout;
    float* sb = smem + 2l * din * dout;
    if (uselds) {
        for (int j = threadIdx.x; j < din * dout; j += 256) {
            int o = j % dout, i = j / dout;
            su[j] = ldf(wu, (long)o * din + i, ubf);
            sd[j] = ldf(wd, (long)o * din + i, dbf);
            sb[j] = ldf(wb, (long)o * din + i, bbf);
        }
        __syncthreads();
    }
    long idx = (long)blockIdx.x * blockDim.x + threadIdx.x;
    long node = idx / dout;
    int o = (int)(idx % dout);
    if (node >= N) return;
    float au = 0.f, ad = 0.f, ab = 0.f;
    long xb = node * din;
    if (uselds) {
        for (int i = 0; i < din; i++) {
            float xv = ldf(xin, xb + i, xbf);
            au += xv * su[i * dout + o];
            ad += xv * sd[i * dout + o];
            ab += xv * sb[i * dout + o];
        }
    } else {
        for (int i = 0; i < din; i++) {
            float xv = ldf(xin, xb + i, xbf);
            au += xv * ldf(wu, (long)o * din + i, ubf);
            ad += xv * ldf(wd, (long)o * din + i, dbf);
            ab += xv * ldf(wb, (long)o * din + i, bbf);
        }
    }
    A[node * rs + o] = au;
    B[node * rs + o] = ad;
    C[node * rs + o] = ab;
}

__global__ void k_deg(const int* __restrict__ ei, long E, const int* __restrict__ flags,
                      float* __restrict__ degc, float* __restrict__ degr) {
    long e = (long)blockIdx.x * blockDim.x + threadIdx.x;
    if (e < E) {
        int is64 = flags[16];
        atomicAdd(&degc[lde(ei, 1, e, E, is64)], 1.0f);
        atomicAdd(&degr[lde(ei, 0, e, E, is64)], 1.0f);
    }
}

__global__ void k_inv(float* __restrict__ a, long n) {
    long i = (long)blockIdx.x * blockDim.x + threadIdx.x;
    if (i < n) { float v = a[i]; a[i] = (v > 0.0f) ? 1.0f / v : 0.0f; }
}

__global__ void k_scatter(const int* __restrict__ ei, long E, int F,
                          const void* __restrict__ ewu, const void* __restrict__ ewd,
                          int fu, int fd, const int* __restrict__ flags,
                          const float* __restrict__ degci, const float* __restrict__ degri,
                          const float* __restrict__ A, const float* __restrict__ B,
                          float* __restrict__ U, float* __restrict__ D) {
    long idx = (long)blockIdx.x * blockDim.x + threadIdx.x;
    long tot = E * 2 * F;
    if (idx >= tot) return;
    int is64 = flags[16];
    long e = idx / (2 * F);
    int rem = (int)(idx - e * 2 * F);
    int dir = rem >= F;
    int f = rem - dir * F;
    int r = lde(ei, 0, e, E, is64), c = lde(ei, 1, e, E, is64);
    if (!dir) {
        float w = degci[c] * ldf(ewu, e, flags[fu]);
        atomicAdd(&U[(long)c * F + f], w * A[(long)r * F + f]);
    } else {
        float w = degri[r] * ldf(ewd, e, flags[fd]);
        atomicAdd(&D[(long)r * F + f], w * B[(long)c * F + f]);
    }
}

__global__ void k_finalize(const float* __restrict__ U, const float* __restrict__ D,
                           const float* __restrict__ C, int F, long N,
                           float* __restrict__ out) {
    long t = (long)blockIdx.x * blockDim.x + threadIdx.x;
    long n = t >> 6;
    if (n >= N) return;
    int lane = (int)(t & 63);
    int cat = 3 * F;
    float ss = 0.f;
    for (int j = lane; j < cat; j += 64) {
        float v = (j < F) ? U[n * F + j] : (j < 2 * F) ? D[n * F + j - F] : C[n * F + j - 2 * F];
        ss += v * v;
    }
#pragma unroll
    for (int m = 1; m < 64; m <<= 1) ss += __shfl_xor(ss, m, 64);
    float inv = 1.0f / fmaxf(sqrtf(ss), 1e-12f);
    for (int j = lane; j < cat; j += 64) {
        float v = (j < F) ? U[n * F + j] : (j < 2 * F) ? D[n * F + j - F] : C[n * F + j - 2 * F];
        float a = v * inv;
        a = (a >= 0.0f) ? a : 0.1f * a;
        out[n * cat + j] = a;
    }
}

__global__ void k_mean(const void* e1u, const void* e2u, const void* e3u,
                       const void* e1d, const void* e2d, const void* e3d,
                       const int* __restrict__ flags, long E,
                       float* __restrict__ mu, float* __restrict__ md) {
    long e = (long)blockIdx.x * blockDim.x + threadIdx.x;
    if (e >= E) return;
    float su = ldf(e1u, e, flags[4]) + ldf(e2u, e, flags[9]) + ldf(e3u, e, flags[14]);
    float sd = ldf(e1d, e, flags[5]) + ldf(e2d, e, flags[10]) + ldf(e3d, e, flags[15]);
    mu[e] = su / 3.0f;
    md[e] = sd / 3.0f;
}

extern "C" void kernel_launch(void* const* d_in, const int* in_sizes, int n_in,
                              void* d_out, int out_size, void* d_ws, size_t ws_size,
                              hipStream_t stream) {
    const int* ei = (const int*)d_in[1];
    const void* w_up[3]   = {d_in[2], d_in[7],  d_in[12]};
    const void* w_down[3] = {d_in[3], d_in[8],  d_in[13]};
    const void* w_bias[3] = {d_in[4], d_in[9],  d_in[14]};
    const void* ew_up[3]  = {d_in[5], d_in[10], d_in[15]};
    const void* ew_down[3]= {d_in[6], d_in[11], d_in[16]};

    // ---- derive true sizes from in_sizes
    long E = in_sizes[5];
    if (E <= 0) E = 1600000;
    int HID = (int)(sqrt((double)in_sizes[7] / 3.0) + 0.5);
    if (HID <= 0 || (long)3 * HID * HID != (long)in_sizes[7]) HID = 32;
    int DIN = in_sizes[2] / HID;
    if (DIN <= 0) DIN = 8;
    long N = (long)in_sizes[0] / DIN;
    if (N <= 0) N = 50000;
    int EMB = in_sizes[12] / (3 * HID);
    if (EMB <= 0) EMB = 32;
    int Fm = HID > EMB ? HID : EMB;
    int NB = (int)((N + 255) >> BSH);

    // ---- outputs: fp32, concatenated (h, mean_up, mean_down)
    float* out_h  = (float*)d_out;
    float* out_mu = out_h + N * 3l * EMB;
    float* out_md = out_mu + E;

    const int TB = 256;
    int lds1  = (3l * DIN * HID <= 12288) ? 1 : 0;
    int lds12 = (3l * (3 * HID) * HID <= 12288) ? 1 : 0;
    int lds3  = (3l * (3 * HID) * EMB <= 12288) ? 1 : 0;
    dim3 linG1((unsigned)((N * HID + TB - 1) / TB));
    dim3 linG3((unsigned)((N * EMB + TB - 1) / TB));
    dim3 lin96G((unsigned)((N + 63) / 64));
    dim3 finG((unsigned)((N * 64 + TB - 1) / TB));
    dim3 edgeG((unsigned)((E + TB - 1) / TB));
    dim3 edgeG6((unsigned)((E + TB - 1) / TB), 6);
    dim3 chunkG1((unsigned)((E + CH - 1) / CH));
    dim3 chunkG2((unsigned)((E + CH - 1) / CH), 2);

    // ---- fast-path workspace layout
    int* flags = (int*)d_ws;                       // 64
    int* bc    = flags + 64;                       // 2*NBMAX
    int* bb    = bc + 2 * NBMAX;                   // 2*(NBMAX+1)
    int* gcur  = bb + 2 * (NBMAX + 1);             // 2*NBMAX
    int* off_c = gcur + 2 * NBMAX;                 // N+1
    int* off_r = off_c + (N + 1);                  // N+1
    long li = (long)(off_r + (N + 1) - (int*)d_ws);
    li = (li + 3) & ~3l;
    int* list_c = (int*)d_ws + li;                 // E (src only - gather hot path)
    int* list_r = list_c + E;                      // E
    int* eidx_c = list_r + E;                      // E (eids - wcsr only)
    int* eidx_r = eidx_c + E;                      // E
    int* R = eidx_r + E;
    // phase 1 (bucket build): bse 2E int2 = 4E ints (record: src|local<<24, eid)
    int2* bse = (int2*)R;
    // phase 2+: wc6 persists; ebc6 transient; S/U overlay ebc6
    ushort_t* wc6  = (ushort_t*)R;                 // 6E ushorts = 3E ints
    ushort_t* ebc6 = (ushort_t*)(R + 3 * E);       // 6E ushorts = 3E ints
    ushort_t* Su = ebc6;                           // N*Fm (after wcsr, ebc6 dead)
    ushort_t* Sd = Su + N * Fm;
    ushort_t* Sb = Sd + N * Fm;
    float* U = (float*)(Sb + N * Fm);              // N*Fm fp32 (int-aligned: 3*N*Fm even)
    long zInts = (3l * N * Fm + 1) / 2 + N * Fm;   // S arrays + U
    long Rints = 4l * E;                           // phase 1
    long p2 = 3l * E + ((zInts > 3l * E) ? zInts : 3l * E);
    if (p2 > Rints) Rints = p2;
    size_t need = (size_t)((li + 4l * E + Rints) * 4l + 256);

    bool fast = (HID == 32 && EMB == 32) && (NB <= NBMAX) &&
                (ws_size == 0 || ws_size >= need);

    // ---- dtype detection (both paths)
    DetectArgs da;
    da.p[0] = d_in[0]; da.n[0] = in_sizes[0];
    for (int L = 0; L < 3; L++) {
        da.p[1 + 5 * L] = w_up[L];    da.n[1 + 5 * L] = in_sizes[2 + 5 * L];
        da.p[2 + 5 * L] = w_down[L];  da.n[2 + 5 * L] = in_sizes[3 + 5 * L];
        da.p[3 + 5 * L] = w_bias[L];  da.n[3 + 5 * L] = in_sizes[4 + 5 * L];
        da.p[4 + 5 * L] = ew_up[L];   da.n[4 + 5 * L] = in_sizes[5 + 5 * L];
        da.p[5 + 5 * L] = ew_down[L]; da.n[5 + 5 * L] = in_sizes[6 + 5 * L];
    }
    da.ei = ei; da.E = E; da.flags = flags;
    k_detect<<<17, TB, 0, stream>>>(da);

    if (fast) {
        // ---- bucketed CSR build (once; reused 3 layers x 2 directions)
        hipMemsetAsync(bc, 0, 2 * NBMAX * sizeof(int), stream);
        kb_count<<<chunkG1, TB, 0, stream>>>(ei, E, flags, NB, bc);
        kb_scan<<<1, 512, 0, stream>>>(bc, bb, gcur, NB);
        kb_fill<<<chunkG2, TB, 0, stream>>>(ei, E, flags, NB, gcur, bse);
        kb_csr<<<dim3((unsigned)NB, 2), TB, 0, stream>>>(bb, bse, E, NB, N,
                                                         off_c, off_r, list_c, list_r,
                                                         eidx_c, eidx_r);

        // ---- cast all 6 ew arrays + write mean outputs, one pass
        k_ewcast6<<<edgeG, TB, 0, stream>>>(ew_up[0], ew_up[1], ew_up[2],
                                            ew_down[0], ew_down[1], ew_down[2],
                                            flags, E, ebc6, out_mu, out_md);
        // ---- CSR-ordered bf16 weights, all 6 tables in one launch
        k_wcsr6<<<edgeG6, TB, 0, stream>>>(eidx_c, eidx_r, E, ebc6, wc6);

        float* H = (float*)d_out;   // intermediate 96-wide activations live in d_out

        // ---- layer 1 (din=DIN, generic, bf16 S output)
        k_linear_b16<<<linG1, TB, 0, stream>>>(d_in[0], 0, DIN, HID, N,
                                               w_up[0], w_down[0], w_bias[0], 1, flags, lds1,
                                               Su, Sd, Sb);
        k_gather_up<<<finG, TB, 0, stream>>>(off_c, list_c, wc6, Su, N, U);
        k_gather_downfin<<<finG, TB, 0, stream>>>(off_r, list_r, wc6 + E, Sd, Sb, U, N, H);
        // ---- layer 2 (din=96 specialized)
        k_lin96<<<lin96G, TB, 0, stream>>>(H, N, w_up[1], w_down[1], w_bias[1], 6, flags,
                                           Su, Sd, Sb);
        k_gather_up<<<finG, TB, 0, stream>>>(off_c, list_c, wc6 + 2l * E, Su, N, U);
        k_gather_downfin<<<finG, TB, 0, stream>>>(off_r, list_r, wc6 + 3l * E, Sd, Sb, U, N, H);
        // ---- layer 3 -> final fp32 output
        k_lin96<<<lin96G, TB, 0, stream>>>(H, N, w_up[2], w_down[2], w_bias[2], 11, flags,
                                           Su, Sd, Sb);
        k_gather_up<<<finG, TB, 0, stream>>>(off_c, list_c, wc6 + 4l * E, Su, N, U);
        k_gather_downfin<<<finG, TB, 0, stream>>>(off_r, list_r, wc6 + 5l * E, Sd, Sb, U, N, out_h);
    } else {
        // ---- fallback: round-4 proven atomic-scatter path
        float* degci = (float*)(flags + 64);
        float* degri = degci + N;
        float* fA = degri + N;
        float* fB = fA + N * Fm;
        float* fC = fB + N * Fm;
        float* fU = fC + N * Fm;
        float* fD = fU + N * Fm;
        float* fH = fD + N * Fm;
        dim3 scatG12((unsigned)((E * 2 * HID + TB - 1) / TB));
        dim3 scatG3((unsigned)((E * 2 * EMB + TB - 1) / TB));

        hipMemsetAsync(degci, 0, 2 * N * sizeof(float), stream);
        k_deg<<<edgeG, TB, 0, stream>>>(ei, E, flags, degci, degri);
        k_inv<<<dim3((unsigned)((2 * N + TB - 1) / TB)), TB, 0, stream>>>(degci, 2 * N);

        k_linear<<<linG1, TB, 0, stream>>>(d_in[0], 0, DIN, HID, HID, N,
                                           w_up[0], w_down[0], w_bias[0], 1, flags, lds1, fA, fB, fC);
        hipMemsetAsync(fU, 0, 2l * N * Fm * sizeof(float), stream);
        k_scatter<<<scatG12, TB, 0, stream>>>(ei, E, HID, ew_up[0], ew_down[0], 4, 5, flags,
                                              degci, degri, fA, fB, fU, fD);
        k_finalize<<<finG, TB, 0, stream>>>(fU, fD, fC, HID, N, fH);

        k_linear<<<linG1, TB, 0, stream>>>(fH, -1, 3 * HID, HID, HID, N,
                                           w_up[1], w_down[1], w_bias[1], 6, flags, lds12, fA, fB, fC);
        hipMemsetAsync(fU, 0, 2l * N * Fm * sizeof(float), stream);
        k_scatter<<<scatG12, TB, 0, stream>>>(ei, E, HID, ew_up[1], ew_down[1], 9, 10, flags,
                                              degci, degri, fA, fB, fU, fD);
        k_finalize<<<finG, TB, 0, stream>>>(fU, fD, fC, HID, N, fH);

        k_linear<<<linG3, TB, 0, stream>>>(fH, -1, 3 * HID, EMB, EMB, N,
                                           w_up[2], w_down[2], w_bias[2], 11, flags, lds3, fA, fB, fC);
        hipMemsetAsync(fU, 0, 2l * N * Fm * sizeof(float), stream);
        k_scatter<<<scatG3, TB, 0, stream>>>(ei, E, EMB, ew_up[2], ew_down[2], 14, 15, flags,
                                             degci, degri, fA, fB, fU, fD);
        k_finalize<<<finG, TB, 0, stream>>>(fU, fD, fC, EMB, N, out_h);

        k_mean<<<edgeG, TB, 0, stream>>>(ew_up[0], ew_up[1], ew_up[2],
                                         ew_down[0], ew_down[1], ew_down[2],
                                         flags, E, out_mu, out_md);
    }
}